// Round 1
// baseline (4604.119 us; speedup 1.0000x reference)
//
#include <hip/hip_runtime.h>
#include <cstdint>

#define H 128
static const int NG = 50000, NS = 20000, NP = 30000;

static inline int nblk(long long n) { return (int)((n + 255) / 256); }

// ---------------- degree / count ----------------
__global__ void k_count(const int* __restrict__ col, int E, float* deg) {
  int e = blockIdx.x * blockDim.x + threadIdx.x;
  if (e < E) atomicAdd(&deg[col[e]], 1.0f);
}

__global__ void k_count_rel(const int* __restrict__ col, const int* __restrict__ et,
                            int E, float* cnt, int n) {
  int e = blockIdx.x * blockDim.x + threadIdx.x;
  if (e < E) atomicAdd(&cnt[et[e] * n + col[e]], 1.0f);
}

__global__ void k_dinv(float* deg, int n, float addself) {
  int i = blockIdx.x * blockDim.x + threadIdx.x;
  if (i < n) {
    float d = deg[i] + addself;
    deg[i] = (d > 0.f) ? rsqrtf(d) : 0.f;
  }
}

// ---------------- scatters ----------------
__global__ void k_scatter_norm7(const float* __restrict__ src, const int* __restrict__ row,
                                const int* __restrict__ col, const float* __restrict__ dinv,
                                int E, float* dst) {
  long long t = (long long)blockIdx.x * blockDim.x + threadIdx.x;
  int e = (int)(t >> 3), f = (int)(t & 7);
  if (e < E && f < 7) {
    int r = row[e], c = col[e];
    atomicAdd(&dst[c * 7 + f], dinv[r] * dinv[c] * src[r * 7 + f]);
  }
}

__global__ void k_scatter_norm128(const float* __restrict__ src, const int* __restrict__ row,
                                  const int* __restrict__ col, const float* __restrict__ dinv,
                                  int E, float* dst) {
  long long t = (long long)blockIdx.x * blockDim.x + threadIdx.x;
  int e = (int)(t >> 7), h = (int)(t & 127);
  if (e < E) {
    int r = row[e], c = col[e];
    atomicAdd(&dst[c * H + h], dinv[r] * dinv[c] * src[r * H + h]);
  }
}

__global__ void k_scatter_add128(const float* __restrict__ src, const int* __restrict__ row,
                                 const int* __restrict__ col, int E, float* dst, float* cnt) {
  long long t = (long long)blockIdx.x * blockDim.x + threadIdx.x;
  int e = (int)(t >> 7), h = (int)(t & 127);
  if (e < E) {
    int r = row[e], c = col[e];
    atomicAdd(&dst[c * H + h], src[r * H + h]);
    if (h == 0 && cnt) atomicAdd(&cnt[c], 1.0f);
  }
}

__global__ void k_scatter_rel128(const float* __restrict__ src, const int* __restrict__ row,
                                 const int* __restrict__ col, const int* __restrict__ et,
                                 int E, float* agg, long long plane) {
  long long t = (long long)blockIdx.x * blockDim.x + threadIdx.x;
  int e = (int)(t >> 7), h = (int)(t & 127);
  if (e < E) {
    atomicAdd(&agg[(long long)et[e] * plane + (long long)col[e] * H + h], src[row[e] * H + h]);
  }
}

// ---------------- elementwise / epilogues ----------------
__global__ void k_init_bias128(float* out, const float* __restrict__ b, int M) {
  long long t = (long long)blockIdx.x * blockDim.x + threadIdx.x;
  if (t < (long long)M * H) out[t] = b[t & 127];
}

__global__ void k_relu(float* p, long long n) {
  long long t = (long long)blockIdx.x * blockDim.x + threadIdx.x;
  if (t < n) p[t] = fmaxf(p[t], 0.f);
}

__global__ void k_gcn_epi(float* p, const float* __restrict__ xW, const float* __restrict__ dinv,
                          const float* __restrict__ b, int M) {
  long long t = (long long)blockIdx.x * blockDim.x + threadIdx.x;
  int i = (int)(t >> 7), h = (int)(t & 127);
  if (i < M) {
    float dv = dinv[i];
    p[t] = fmaxf(p[t] + dv * dv * xW[t] + b[h], 0.f);
  }
}

__global__ void k_rg_epi(float* s, const float* __restrict__ x6, const float* __restrict__ Wsk,
                         const float* __restrict__ b, int M) {
  long long t = (long long)blockIdx.x * blockDim.x + threadIdx.x;
  int i = (int)(t >> 7), h = (int)(t & 127);
  if (i < M) {
    float acc = s[t] + b[h];
#pragma unroll
    for (int f = 0; f < 6; f++) acc = fmaf(x6[i * 6 + f], Wsk[f * H + h], acc);
    s[t] = fmaxf(acc, 0.f);
  }
}

// ---------------- GEMMs ----------------
__global__ void k_gemm128(const float* __restrict__ X, const float* __restrict__ W,
                          const float* __restrict__ b, float* out, int M, int K, int act) {
  long long t = (long long)blockIdx.x * blockDim.x + threadIdx.x;
  if (t >= (long long)M * H) return;
  int i = (int)(t >> 7), h = (int)(t & 127);
  float acc = b ? b[h] : 0.f;
  const float* x = X + (long long)i * K;
  for (int k = 0; k < K; k++) acc = fmaf(x[k], W[k * H + h], acc);
  if (act) acc = fmaxf(acc, 0.f);
  out[t] = acc;
}

__global__ void k_gemm_acc128(const float* __restrict__ X, const float* __restrict__ W,
                              float* out, int M, int K, const float* __restrict__ cnt) {
  long long t = (long long)blockIdx.x * blockDim.x + threadIdx.x;
  if (t >= (long long)M * H) return;
  int i = (int)(t >> 7), h = (int)(t & 127);
  float acc = 0.f;
  const float* x = X + (long long)i * K;
  for (int k = 0; k < K; k++) acc = fmaf(x[k], W[k * H + h], acc);
  float sc = cnt ? 1.f / fmaxf(cnt[i], 1.f) : 1.f;
  out[t] += sc * acc;
}

__global__ void k_gemmN(const float* __restrict__ X, const float* __restrict__ W,
                        const float* __restrict__ b, float* out, int M, int K, int N, int act) {
  long long t = (long long)blockIdx.x * blockDim.x + threadIdx.x;
  if (t >= (long long)M * N) return;
  int i = (int)(t / N), h = (int)(t % N);
  float acc = b ? b[h] : 0.f;
  const float* x = X + (long long)i * K;
  for (int k = 0; k < K; k++) acc = fmaf(x[k], W[k * N + h], acc);
  if (act) acc = fmaxf(acc, 0.f);
  out[t] = acc;
}

// ---------------- ResGated edge kernel ----------------
__global__ void k_resgated_edge(const float* __restrict__ kk, const float* __restrict__ q,
                                const float* __restrict__ v, const float* __restrict__ ea,
                                const float* __restrict__ We, const int* __restrict__ rh,
                                const int* __restrict__ ch, int E, float* sacc) {
  long long t = (long long)blockIdx.x * blockDim.x + threadIdx.x;
  int e = (int)(t >> 7), h = (int)(t & 127);
  if (e < E) {
    int r = rh[e], c = ch[e];
    float ew = ea[2 * e] * We[h] + ea[2 * e + 1] * We[H + h];
    float x = kk[c * H + h] + q[r * H + h] + ew;
    float eta = 1.f / (1.f + __expf(-x));
    atomicAdd(&sacc[c * H + h], eta * v[r * H + h]);
  }
}

// ---------------- fused SAGE (GEMM + L2 row norm + relu) ----------------
__global__ void k_sage(const float* __restrict__ mraw, const float* __restrict__ cnt,
                       const float* __restrict__ xd, const float* __restrict__ lw,
                       const float* __restrict__ lb, const float* __restrict__ rw,
                       float* out, int M) {
  int i = blockIdx.x;
  int h = threadIdx.x;  // 128 threads
  __shared__ float xs[H], xdl[H], red[H];
  float invc = 1.f / fmaxf(cnt[i], 1.f);
  xs[h] = mraw[i * H + h] * invc;
  xdl[h] = xd[i * H + h];
  __syncthreads();
  float acc = lb[h];
  for (int k = 0; k < H; k++) {
    acc = fmaf(xs[k], lw[k * H + h], acc);
    acc = fmaf(xdl[k], rw[k * H + h], acc);
  }
  red[h] = acc * acc;
  __syncthreads();
  for (int s = 64; s > 0; s >>= 1) {
    if (h < s) red[h] += red[h + s];
    __syncthreads();
  }
  float nrm = fmaxf(sqrtf(red[0]), 1e-12f);
  out[i * H + h] = fmaxf(acc / nrm, 0.f);
}

// ---------------- log_softmax over axis 0 (single column) ----------------
__global__ void k_logsoftmax(const float* __restrict__ z, float* __restrict__ out, int n) {
  __shared__ float red[256];
  int tid = threadIdx.x;
  float m = -1e30f;
  for (int i = tid; i < n; i += 256) m = fmaxf(m, z[i]);
  red[tid] = m;
  __syncthreads();
  for (int s = 128; s > 0; s >>= 1) {
    if (tid < s) red[tid] = fmaxf(red[tid], red[tid + s]);
    __syncthreads();
  }
  float mx = red[0];
  __syncthreads();
  float sum = 0.f;
  for (int i = tid; i < n; i += 256) sum += __expf(z[i] - mx);
  red[tid] = sum;
  __syncthreads();
  for (int s = 128; s > 0; s >>= 1) {
    if (tid < s) red[tid] += red[tid + s];
    __syncthreads();
  }
  float lse = mx + logf(red[0]);
  for (int i = tid; i < n; i += 256) out[i] = z[i] - lse;
}

extern "C" void kernel_launch(void* const* d_in, const int* in_sizes, int n_in,
                              void* d_out, int out_size, void* d_ws, size_t ws_size,
                              hipStream_t stream) {
  const float* game_x = (const float*)d_in[0];
  const float* state_x = (const float*)d_in[1];
  const float* pc_x = (const float*)d_in[2];
  const int* ei_vv = (const int*)d_in[3];
  const int* et_vv = (const int*)d_in[4];
  const int* ei_hist = (const int*)d_in[5];
  const float* ea_hist = (const float*)d_in[6];
  const int* ei_in = (const int*)d_in[7];
  const int* ei_ss = (const int*)d_in[8];
  const int* ei_pp = (const int*)d_in[9];
  const int* ei_ps = (const int*)d_in[10];
  // d_in[11] edge_index_state_pc: unused by reference
  const float* tag10_w = (const float*)d_in[12];
  const float* tag10_b = (const float*)d_in[13];
  const float* rgcn_w = (const float*)d_in[14];
  const float* rgcn_root = (const float*)d_in[15];
  const float* rgcn_b = (const float*)d_in[16];
  const float* gcn1_w = (const float*)d_in[17];
  const float* gcn1_b = (const float*)d_in[18];
  const float* gcn2_w = (const float*)d_in[19];
  const float* gcn2_b = (const float*)d_in[20];
  const float* rg_key_w = (const float*)d_in[21];
  const float* rg_key_b = (const float*)d_in[22];
  const float* rg_query_w = (const float*)d_in[23];
  const float* rg_query_b = (const float*)d_in[24];
  const float* rg_value_w = (const float*)d_in[25];
  const float* rg_value_b = (const float*)d_in[26];
  const float* rg_edge_w = (const float*)d_in[27];
  const float* rg_skip_w = (const float*)d_in[28];
  const float* rg_b = (const float*)d_in[29];
  const float* sage32_lw = (const float*)d_in[30];
  const float* sage32_lb = (const float*)d_in[31];
  const float* sage32_rw = (const float*)d_in[32];
  const float* sage4_lw = (const float*)d_in[33];
  const float* sage4_lb = (const float*)d_in[34];
  const float* sage4_rw = (const float*)d_in[35];
  const float* sage42_lw = (const float*)d_in[36];
  const float* sage42_lb = (const float*)d_in[37];
  const float* sage42_rw = (const float*)d_in[38];
  const float* pcs_lw = (const float*)d_in[39];
  const float* pcs_lb = (const float*)d_in[40];
  const float* pcs_rw = (const float*)d_in[41];
  const float* tag2_w = (const float*)d_in[42];
  const float* tag2_b = (const float*)d_in[43];
  const float* sage5_lw = (const float*)d_in[44];
  const float* sage5_lb = (const float*)d_in[45];
  const float* sage5_rw = (const float*)d_in[46];
  const float* lin_w = (const float*)d_in[47];
  const float* lin_b = (const float*)d_in[48];
  const float* linl_w = (const float*)d_in[49];
  const float* linl_b = (const float*)d_in[50];

  const int Evv = in_sizes[3] / 2, Eh = in_sizes[5] / 2, Ein = in_sizes[7] / 2,
            Ess = in_sizes[8] / 2, Epp = in_sizes[9] / 2, Eps = in_sizes[10] / 2;
  const int* rvv = ei_vv;      const int* cvv = ei_vv + Evv;
  const int* rh = ei_hist;     const int* ch = ei_hist + Eh;
  const int* ri = ei_in;       const int* ci = ei_in + Ein;
  const int* rs = ei_ss;       const int* cs = ei_ss + Ess;
  const int* rp = ei_pp;       const int* cp = ei_pp + Epp;
  const int* rps = ei_ps;      const int* cps = ei_ps + Eps;

  // ---- workspace layout (floats). Peak ~136 MB. ----
  float* ws = (float*)d_ws;
  const size_t NGH = (size_t)NG * H, NPH = (size_t)NP * H, NSH = (size_t)NS * H;
  float* g_tag = ws;            // [0, NGH): tag10 output; later q; later tag2 h1/h2
  float* g = ws + NGH;          // [NGH, 2NGH): rgcn output (long-lived)
  float* big = ws + 2 * NGH;    // [2NGH, 5NGH): 3*NGH multipurpose arena
  float* small = ws + 5 * NGH;  // misc
  float* dinvG = small;
  float* dinvP = small + 50000;
  float* dinvS = small + 80000;
  float* cnt3 = small + 100000;   // 3*NG
  float* cntS = small + 250000;   // NS
  float* h7a = small + 270000;    // NG*7
  float* h7b = small + 620000;
  float* h7c = small + 970000;
  float* t32 = small + 1320000;   // NS*32
  float* z = small + 1960000;     // NS
  // arena aliases (sequenced so lifetimes don't overlap):
  float* agg = big;                       // rgcn: 3 planes of NGH
  float* xW = big;                        // pc: NPH
  float* p1 = big + NPH;                  // pc: NPH
  float* p2 = big + 2 * NPH;              // pc final p (lives until pcs sage)
  float* q = g_tag;                       // NGH (g_tag dead after rgcn)
  float* v = big;                         // NGH (fits in [0, 2*NPH))
  float* kk = big + 3 * NPH;              // NSH
  float* S_a = big + 3 * NPH + NSH;       // NSH
  float* S_b = big + 3 * NPH + 2 * NSH;   // NSH (3*NPH+3*NSH == 3*NGH exactly)
  float* m_buf = big + 3 * NPH;           // NSH (kk dead after edge kernel)
  float* h1 = g_tag;                      // NSH
  float* h2 = g_tag + NSH;                // NSH

  // ================= game graph =================
  // TAGConv(game_x, 3 hops, 7-dim propagation)
  hipMemsetAsync(dinvG, 0, NG * 4, stream);
  k_count<<<nblk(Evv), 256, 0, stream>>>(cvv, Evv, dinvG);
  k_dinv<<<nblk(NG), 256, 0, stream>>>(dinvG, NG, 0.f);

  hipMemsetAsync(h7a, 0, NG * 7 * 4, stream);
  k_scatter_norm7<<<nblk((long long)Evv * 8), 256, 0, stream>>>(game_x, rvv, cvv, dinvG, Evv, h7a);
  hipMemsetAsync(h7b, 0, NG * 7 * 4, stream);
  k_scatter_norm7<<<nblk((long long)Evv * 8), 256, 0, stream>>>(h7a, rvv, cvv, dinvG, Evv, h7b);
  hipMemsetAsync(h7c, 0, NG * 7 * 4, stream);
  k_scatter_norm7<<<nblk((long long)Evv * 8), 256, 0, stream>>>(h7b, rvv, cvv, dinvG, Evv, h7c);

  k_init_bias128<<<nblk(NGH), 256, 0, stream>>>(g_tag, tag10_b, NG);
  k_gemm_acc128<<<nblk(NGH), 256, 0, stream>>>(game_x, tag10_w, g_tag, NG, 7, nullptr);
  k_gemm_acc128<<<nblk(NGH), 256, 0, stream>>>(h7a, tag10_w + 7 * H, g_tag, NG, 7, nullptr);
  k_gemm_acc128<<<nblk(NGH), 256, 0, stream>>>(h7b, tag10_w + 14 * H, g_tag, NG, 7, nullptr);
  k_gemm_acc128<<<nblk(NGH), 256, 0, stream>>>(h7c, tag10_w + 21 * H, g_tag, NG, 7, nullptr);
  k_relu<<<nblk(NGH), 256, 0, stream>>>(g_tag, NGH);

  // RGCN (aggregate-first: per-relation mean, then GEMM)
  hipMemsetAsync(cnt3, 0, 3 * NG * 4, stream);
  k_count_rel<<<nblk(Evv), 256, 0, stream>>>(cvv, et_vv, Evv, cnt3, NG);
  hipMemsetAsync(agg, 0, 3 * NGH * 4, stream);
  k_scatter_rel128<<<nblk((long long)Evv * 128), 256, 0, stream>>>(g_tag, rvv, cvv, et_vv, Evv, agg, (long long)NGH);
  k_init_bias128<<<nblk(NGH), 256, 0, stream>>>(g, rgcn_b, NG);
  for (int r = 0; r < 3; r++)
    k_gemm_acc128<<<nblk(NGH), 256, 0, stream>>>(agg + (size_t)r * NGH, rgcn_w + r * H * H, g, NG, H, cnt3 + r * NG);
  k_gemm_acc128<<<nblk(NGH), 256, 0, stream>>>(g_tag, rgcn_root, g, NG, H, nullptr);
  k_relu<<<nblk(NGH), 256, 0, stream>>>(g, NGH);

  // ================= pc graph (2x GCN) =================
  hipMemsetAsync(dinvP, 0, NP * 4, stream);
  k_count<<<nblk(Epp), 256, 0, stream>>>(cp, Epp, dinvP);
  k_dinv<<<nblk(NP), 256, 0, stream>>>(dinvP, NP, 1.f);

  k_gemm128<<<nblk(NPH), 256, 0, stream>>>(pc_x, gcn1_w, nullptr, xW, NP, 5, 0);
  hipMemsetAsync(p1, 0, NPH * 4, stream);
  k_scatter_norm128<<<nblk((long long)Epp * 128), 256, 0, stream>>>(xW, rp, cp, dinvP, Epp, p1);
  k_gcn_epi<<<nblk(NPH), 256, 0, stream>>>(p1, xW, dinvP, gcn1_b, NP);

  k_gemm128<<<nblk(NPH), 256, 0, stream>>>(p1, gcn2_w, nullptr, xW, NP, H, 0);
  hipMemsetAsync(p2, 0, NPH * 4, stream);
  k_scatter_norm128<<<nblk((long long)Epp * 128), 256, 0, stream>>>(xW, rp, cp, dinvP, Epp, p2);
  k_gcn_epi<<<nblk(NPH), 256, 0, stream>>>(p2, xW, dinvP, gcn2_b, NP);

  // ================= ResGated (game -> state) =================
  k_gemm128<<<nblk(NSH), 256, 0, stream>>>(state_x, rg_key_w, rg_key_b, kk, NS, 6, 0);
  k_gemm128<<<nblk(NGH), 256, 0, stream>>>(g, rg_query_w, rg_query_b, q, NG, H, 0);
  k_gemm128<<<nblk(NGH), 256, 0, stream>>>(g, rg_value_w, rg_value_b, v, NG, H, 0);
  hipMemsetAsync(S_a, 0, NSH * 4, stream);
  k_resgated_edge<<<nblk((long long)Eh * 128), 256, 0, stream>>>(kk, q, v, ea_hist, rg_edge_w, rh, ch, Eh, S_a);
  k_rg_epi<<<nblk(NSH), 256, 0, stream>>>(S_a, state_x, rg_skip_w, rg_b, NS);

  // ================= sage32 (hist edges, xs=g) =================
  hipMemsetAsync(m_buf, 0, NSH * 4, stream);
  hipMemsetAsync(cntS, 0, NS * 4, stream);
  k_scatter_add128<<<nblk((long long)Eh * 128), 256, 0, stream>>>(g, rh, ch, Eh, m_buf, cntS);
  k_sage<<<NS, 128, 0, stream>>>(m_buf, cntS, S_a, sage32_lw, sage32_lb, sage32_rw, S_b, NS);

  // ================= sage4 + sage42 (in edges, xs=g; shared mean) =================
  hipMemsetAsync(m_buf, 0, NSH * 4, stream);
  hipMemsetAsync(cntS, 0, NS * 4, stream);
  k_scatter_add128<<<nblk((long long)Ein * 128), 256, 0, stream>>>(g, ri, ci, Ein, m_buf, cntS);
  k_sage<<<NS, 128, 0, stream>>>(m_buf, cntS, S_b, sage4_lw, sage4_lb, sage4_rw, S_a, NS);
  k_sage<<<NS, 128, 0, stream>>>(m_buf, cntS, S_a, sage42_lw, sage42_lb, sage42_rw, S_b, NS);

  // ================= pcs sage (pc->state, xs=p) =================
  hipMemsetAsync(m_buf, 0, NSH * 4, stream);
  hipMemsetAsync(cntS, 0, NS * 4, stream);
  k_scatter_add128<<<nblk((long long)Eps * 128), 256, 0, stream>>>(p2, rps, cps, Eps, m_buf, cntS);
  k_sage<<<NS, 128, 0, stream>>>(m_buf, cntS, S_b, pcs_lw, pcs_lb, pcs_rw, S_a, NS);

  // ================= tag2 (state graph, 2 hops, 128-dim) =================
  hipMemsetAsync(dinvS, 0, NS * 4, stream);
  k_count<<<nblk(Ess), 256, 0, stream>>>(cs, Ess, dinvS);
  k_dinv<<<nblk(NS), 256, 0, stream>>>(dinvS, NS, 0.f);
  hipMemsetAsync(h1, 0, NSH * 4, stream);
  k_scatter_norm128<<<nblk((long long)Ess * 128), 256, 0, stream>>>(S_a, rs, cs, dinvS, Ess, h1);
  hipMemsetAsync(h2, 0, NSH * 4, stream);
  k_scatter_norm128<<<nblk((long long)Ess * 128), 256, 0, stream>>>(h1, rs, cs, dinvS, Ess, h2);
  k_init_bias128<<<nblk(NSH), 256, 0, stream>>>(S_b, tag2_b, NS);
  k_gemm_acc128<<<nblk(NSH), 256, 0, stream>>>(S_a, tag2_w, S_b, NS, H, nullptr);
  k_gemm_acc128<<<nblk(NSH), 256, 0, stream>>>(h1, tag2_w + H * H, S_b, NS, H, nullptr);
  k_gemm_acc128<<<nblk(NSH), 256, 0, stream>>>(h2, tag2_w + 2 * H * H, S_b, NS, H, nullptr);
  k_relu<<<nblk(NSH), 256, 0, stream>>>(S_b, NSH);

  // ================= sage5 (state graph, xs=s) =================
  hipMemsetAsync(m_buf, 0, NSH * 4, stream);
  hipMemsetAsync(cntS, 0, NS * 4, stream);
  k_scatter_add128<<<nblk((long long)Ess * 128), 256, 0, stream>>>(S_b, rs, cs, Ess, m_buf, cntS);
  k_sage<<<NS, 128, 0, stream>>>(m_buf, cntS, S_b, sage5_lw, sage5_lb, sage5_rw, S_a, NS);

  // ================= head =================
  k_gemmN<<<nblk((long long)NS * 32), 256, 0, stream>>>(S_a, lin_w, lin_b, t32, NS, H, 32, 1);
  k_gemmN<<<nblk(NS), 256, 0, stream>>>(t32, linl_w, linl_b, z, NS, 32, 1, 0);
  k_logsoftmax<<<1, 256, 0, stream>>>(z, (float*)d_out, NS);
}

// Round 2
// 2413.278 us; speedup vs baseline: 1.9078x; 1.9078x over previous
//
#include <hip/hip_runtime.h>
#include <cstdint>

#define H 128
static const int NG = 50000, NS = 20000, NP = 30000;

static inline int nblk(long long n) { return (int)((n + 255) / 256); }

// ---------------- degree / count ----------------
__global__ void k_count(const int* __restrict__ col, int E, float* deg) {
  int e = blockIdx.x * blockDim.x + threadIdx.x;
  if (e < E) atomicAdd(&deg[col[e]], 1.0f);
}

__global__ void k_count_rel(const int* __restrict__ col, const int* __restrict__ et,
                            int E, float* cnt, int n) {
  int e = blockIdx.x * blockDim.x + threadIdx.x;
  if (e < E) atomicAdd(&cnt[et[e] * n + col[e]], 1.0f);
}

__global__ void k_dinv(float* deg, int n, float addself) {
  int i = blockIdx.x * blockDim.x + threadIdx.x;
  if (i < n) {
    float d = deg[i] + addself;
    deg[i] = (d > 0.f) ? rsqrtf(d) : 0.f;
  }
}

__global__ void k_invcnt(float* p, int n) {
  int i = blockIdx.x * blockDim.x + threadIdx.x;
  if (i < n) p[i] = 1.f / fmaxf(p[i], 1.f);
}

// ---------------- scatters ----------------
__global__ void k_scatter_norm7(const float* __restrict__ src, const int* __restrict__ row,
                                const int* __restrict__ col, const float* __restrict__ dinv,
                                int E, float* dst) {
  long long t = (long long)blockIdx.x * blockDim.x + threadIdx.x;
  int e = (int)(t >> 3), f = (int)(t & 7);
  if (e < E && f < 7) {
    int r = row[e], c = col[e];
    atomicAdd(&dst[c * 7 + f], dinv[r] * dinv[c] * src[r * 7 + f]);
  }
}

__global__ void k_scatter_norm128(const float* __restrict__ src, const int* __restrict__ row,
                                  const int* __restrict__ col, const float* __restrict__ dinv,
                                  int E, float* dst) {
  long long t = (long long)blockIdx.x * blockDim.x + threadIdx.x;
  int e = (int)(t >> 7), h = (int)(t & 127);
  if (e < E) {
    int r = row[e], c = col[e];
    atomicAdd(&dst[c * H + h], dinv[r] * dinv[c] * src[r * H + h]);
  }
}

__global__ void k_scatter_add128(const float* __restrict__ src, const int* __restrict__ row,
                                 const int* __restrict__ col, int E, float* dst, float* cnt) {
  long long t = (long long)blockIdx.x * blockDim.x + threadIdx.x;
  int e = (int)(t >> 7), h = (int)(t & 127);
  if (e < E) {
    int r = row[e], c = col[e];
    atomicAdd(&dst[c * H + h], src[r * H + h]);
    if (h == 0 && cnt) atomicAdd(&cnt[c], 1.0f);
  }
}

__global__ void k_scatter_rel128(const float* __restrict__ src, const int* __restrict__ row,
                                 const int* __restrict__ col, const int* __restrict__ et,
                                 int E, float* agg, long long plane) {
  long long t = (long long)blockIdx.x * blockDim.x + threadIdx.x;
  int e = (int)(t >> 7), h = (int)(t & 127);
  if (e < E) {
    atomicAdd(&agg[(long long)et[e] * plane + (long long)col[e] * H + h], src[row[e] * H + h]);
  }
}

// ---------------- elementwise / epilogues ----------------
__global__ void k_init_bias128(float* out, const float* __restrict__ b, int M) {
  long long t = (long long)blockIdx.x * blockDim.x + threadIdx.x;
  if (t < (long long)M * H) out[t] = b[t & 127];
}

__global__ void k_relu(float* p, long long n) {
  long long t = (long long)blockIdx.x * blockDim.x + threadIdx.x;
  if (t < n) p[t] = fmaxf(p[t], 0.f);
}

__global__ void k_gcn_epi(float* p, const float* __restrict__ xW, const float* __restrict__ dinv,
                          const float* __restrict__ b, int M) {
  long long t = (long long)blockIdx.x * blockDim.x + threadIdx.x;
  int i = (int)(t >> 7), h = (int)(t & 127);
  if (i < M) {
    float dv = dinv[i];
    p[t] = fmaxf(p[t] + dv * dv * xW[t] + b[h], 0.f);
  }
}

__global__ void k_rg_epi(float* s, const float* __restrict__ x6, const float* __restrict__ Wsk,
                         const float* __restrict__ b, int M) {
  long long t = (long long)blockIdx.x * blockDim.x + threadIdx.x;
  int i = (int)(t >> 7), h = (int)(t & 127);
  if (i < M) {
    float acc = s[t] + b[h];
#pragma unroll
    for (int f = 0; f < 6; f++) acc = fmaf(x6[i * 6 + f], Wsk[f * H + h], acc);
    s[t] = fmaxf(acc, 0.f);
  }
}

// L2 row-normalize + relu (SAGE epilogue)
__global__ void k_norm_relu(const float* __restrict__ in, float* __restrict__ out) {
  int i = blockIdx.x;
  int h = threadIdx.x;  // 128
  __shared__ float red[H];
  float v = in[i * H + h];
  red[h] = v * v;
  __syncthreads();
  for (int s = 64; s > 0; s >>= 1) {
    if (h < s) red[h] += red[h + s];
    __syncthreads();
  }
  float nrm = fmaxf(sqrtf(red[0]), 1e-12f);
  out[i * H + h] = fmaxf(v / nrm, 0.f);
}

// ---------------- naive GEMMs (tiny K only) ----------------
__global__ void k_gemm128(const float* __restrict__ X, const float* __restrict__ W,
                          const float* __restrict__ b, float* out, int M, int K, int act) {
  long long t = (long long)blockIdx.x * blockDim.x + threadIdx.x;
  if (t >= (long long)M * H) return;
  int i = (int)(t >> 7), h = (int)(t & 127);
  float acc = b ? b[h] : 0.f;
  const float* x = X + (long long)i * K;
  for (int k = 0; k < K; k++) acc = fmaf(x[k], W[k * H + h], acc);
  if (act) acc = fmaxf(acc, 0.f);
  out[t] = acc;
}

__global__ void k_gemm_acc128(const float* __restrict__ X, const float* __restrict__ W,
                              float* out, int M, int K) {
  long long t = (long long)blockIdx.x * blockDim.x + threadIdx.x;
  if (t >= (long long)M * H) return;
  int i = (int)(t >> 7), h = (int)(t & 127);
  float acc = 0.f;
  const float* x = X + (long long)i * K;
  for (int k = 0; k < K; k++) acc = fmaf(x[k], W[k * H + h], acc);
  out[t] += acc;
}

__global__ void k_gemmN(const float* __restrict__ X, const float* __restrict__ W,
                        const float* __restrict__ b, float* out, int M, int K, int N, int act) {
  long long t = (long long)blockIdx.x * blockDim.x + threadIdx.x;
  if (t >= (long long)M * N) return;
  int i = (int)(t / N), h = (int)(t % N);
  float acc = b ? b[h] : 0.f;
  const float* x = X + (long long)i * K;
  for (int k = 0; k < K; k++) acc = fmaf(x[k], W[k * N + h], acc);
  if (act) acc = fmaxf(acc, 0.f);
  out[t] = acc;
}

// ---------------- tiled SGEMM ----------------
// C[M x N] (N%64==0, K%16==0, K%16 stage uses float4 so K%4==0 and BK=16 needs K>=16)
// flags: bit0 = accumulate into C, bit1 = relu
// rs: optional per-row scale applied to X rows at staging (mean aggregation)
#define BM 64
#define BN 64
#define BK 16
__global__ __launch_bounds__(256) void k_tgemm(const float* __restrict__ X,
                                               const float* __restrict__ W,
                                               const float* __restrict__ bias,
                                               const float* __restrict__ rs,
                                               float* __restrict__ C,
                                               int M, int K, int N, int flags) {
  __shared__ float Xs[BK][BM + 4];  // [k][m], 68-stride keeps 16B align + 2-way-max conflicts
  __shared__ float Ws[BK][BN + 4];  // [k][n]
  int tid = threadIdx.x;
  int tx = tid & 15, ty = tid >> 4;
  int rowBase = blockIdx.x * BM, colBase = blockIdx.y * BN;
  int lr = tid >> 2;         // X staging: row in tile (0..63)
  int lk = (tid & 3) * 4;    // X staging: k offset (0,4,8,12)
  int wk = tid >> 4;         // W staging: k row (0..15)
  int wc = (tid & 15) * 4;   // W staging: col offset
  int xrow = rowBase + lr;
  float rscale = 1.f;
  if (rs && xrow < M) rscale = rs[xrow];
  float acc[4][4] = {};
  for (int k0 = 0; k0 < K; k0 += BK) {
    float4 xv = make_float4(0.f, 0.f, 0.f, 0.f);
    if (xrow < M) xv = *(const float4*)(X + (long long)xrow * K + k0 + lk);
    float4 wv = *(const float4*)(W + (long long)(k0 + wk) * N + colBase + wc);
    __syncthreads();
    Xs[lk + 0][lr] = xv.x * rscale;
    Xs[lk + 1][lr] = xv.y * rscale;
    Xs[lk + 2][lr] = xv.z * rscale;
    Xs[lk + 3][lr] = xv.w * rscale;
    *(float4*)&Ws[wk][wc] = wv;
    __syncthreads();
#pragma unroll
    for (int kk = 0; kk < BK; kk++) {
      float4 xf = *(const float4*)&Xs[kk][ty * 4];
      float4 wf = *(const float4*)&Ws[kk][tx * 4];
      acc[0][0] = fmaf(xf.x, wf.x, acc[0][0]);
      acc[0][1] = fmaf(xf.x, wf.y, acc[0][1]);
      acc[0][2] = fmaf(xf.x, wf.z, acc[0][2]);
      acc[0][3] = fmaf(xf.x, wf.w, acc[0][3]);
      acc[1][0] = fmaf(xf.y, wf.x, acc[1][0]);
      acc[1][1] = fmaf(xf.y, wf.y, acc[1][1]);
      acc[1][2] = fmaf(xf.y, wf.z, acc[1][2]);
      acc[1][3] = fmaf(xf.y, wf.w, acc[1][3]);
      acc[2][0] = fmaf(xf.z, wf.x, acc[2][0]);
      acc[2][1] = fmaf(xf.z, wf.y, acc[2][1]);
      acc[2][2] = fmaf(xf.z, wf.z, acc[2][2]);
      acc[2][3] = fmaf(xf.z, wf.w, acc[2][3]);
      acc[3][0] = fmaf(xf.w, wf.x, acc[3][0]);
      acc[3][1] = fmaf(xf.w, wf.y, acc[3][1]);
      acc[3][2] = fmaf(xf.w, wf.z, acc[3][2]);
      acc[3][3] = fmaf(xf.w, wf.w, acc[3][3]);
    }
  }
  float4 bv = make_float4(0.f, 0.f, 0.f, 0.f);
  if (bias) bv = *(const float4*)(bias + colBase + tx * 4);
#pragma unroll
  for (int j = 0; j < 4; j++) {
    int row = rowBase + ty * 4 + j;
    if (row >= M) break;
    float* cp = C + (long long)row * N + colBase + tx * 4;
    float4 o;
    o.x = acc[j][0] + bv.x;
    o.y = acc[j][1] + bv.y;
    o.z = acc[j][2] + bv.z;
    o.w = acc[j][3] + bv.w;
    if (flags & 1) {
      float4 prev = *(const float4*)cp;
      o.x += prev.x; o.y += prev.y; o.z += prev.z; o.w += prev.w;
    }
    if (flags & 2) {
      o.x = fmaxf(o.x, 0.f); o.y = fmaxf(o.y, 0.f);
      o.z = fmaxf(o.z, 0.f); o.w = fmaxf(o.w, 0.f);
    }
    *(float4*)cp = o;
  }
}

static inline dim3 tg_grid(int M) { return dim3((M + BM - 1) / BM, H / BN); }

// ---------------- ResGated edge kernel ----------------
__global__ void k_resgated_edge(const float* __restrict__ kk, const float* __restrict__ q,
                                const float* __restrict__ v, const float* __restrict__ ea,
                                const float* __restrict__ We, const int* __restrict__ rh,
                                const int* __restrict__ ch, int E, float* sacc) {
  long long t = (long long)blockIdx.x * blockDim.x + threadIdx.x;
  int e = (int)(t >> 7), h = (int)(t & 127);
  if (e < E) {
    int r = rh[e], c = ch[e];
    float ew = ea[2 * e] * We[h] + ea[2 * e + 1] * We[H + h];
    float x = kk[c * H + h] + q[r * H + h] + ew;
    float eta = 1.f / (1.f + __expf(-x));
    atomicAdd(&sacc[c * H + h], eta * v[r * H + h]);
  }
}

// ---------------- log_softmax over axis 0 (single column) ----------------
__global__ void k_logsoftmax(const float* __restrict__ z, float* __restrict__ out, int n) {
  __shared__ float red[256];
  int tid = threadIdx.x;
  float m = -1e30f;
  for (int i = tid; i < n; i += 256) m = fmaxf(m, z[i]);
  red[tid] = m;
  __syncthreads();
  for (int s = 128; s > 0; s >>= 1) {
    if (tid < s) red[tid] = fmaxf(red[tid], red[tid + s]);
    __syncthreads();
  }
  float mx = red[0];
  __syncthreads();
  float sum = 0.f;
  for (int i = tid; i < n; i += 256) sum += __expf(z[i] - mx);
  red[tid] = sum;
  __syncthreads();
  for (int s = 128; s > 0; s >>= 1) {
    if (tid < s) red[tid] += red[tid + s];
    __syncthreads();
  }
  float lse = mx + logf(red[0]);
  for (int i = tid; i < n; i += 256) out[i] = z[i] - lse;
}

extern "C" void kernel_launch(void* const* d_in, const int* in_sizes, int n_in,
                              void* d_out, int out_size, void* d_ws, size_t ws_size,
                              hipStream_t stream) {
  const float* game_x = (const float*)d_in[0];
  const float* state_x = (const float*)d_in[1];
  const float* pc_x = (const float*)d_in[2];
  const int* ei_vv = (const int*)d_in[3];
  const int* et_vv = (const int*)d_in[4];
  const int* ei_hist = (const int*)d_in[5];
  const float* ea_hist = (const float*)d_in[6];
  const int* ei_in = (const int*)d_in[7];
  const int* ei_ss = (const int*)d_in[8];
  const int* ei_pp = (const int*)d_in[9];
  const int* ei_ps = (const int*)d_in[10];
  const float* tag10_w = (const float*)d_in[12];
  const float* tag10_b = (const float*)d_in[13];
  const float* rgcn_w = (const float*)d_in[14];
  const float* rgcn_root = (const float*)d_in[15];
  const float* rgcn_b = (const float*)d_in[16];
  const float* gcn1_w = (const float*)d_in[17];
  const float* gcn1_b = (const float*)d_in[18];
  const float* gcn2_w = (const float*)d_in[19];
  const float* gcn2_b = (const float*)d_in[20];
  const float* rg_key_w = (const float*)d_in[21];
  const float* rg_key_b = (const float*)d_in[22];
  const float* rg_query_w = (const float*)d_in[23];
  const float* rg_query_b = (const float*)d_in[24];
  const float* rg_value_w = (const float*)d_in[25];
  const float* rg_value_b = (const float*)d_in[26];
  const float* rg_edge_w = (const float*)d_in[27];
  const float* rg_skip_w = (const float*)d_in[28];
  const float* rg_b = (const float*)d_in[29];
  const float* sage32_lw = (const float*)d_in[30];
  const float* sage32_lb = (const float*)d_in[31];
  const float* sage32_rw = (const float*)d_in[32];
  const float* sage4_lw = (const float*)d_in[33];
  const float* sage4_lb = (const float*)d_in[34];
  const float* sage4_rw = (const float*)d_in[35];
  const float* sage42_lw = (const float*)d_in[36];
  const float* sage42_lb = (const float*)d_in[37];
  const float* sage42_rw = (const float*)d_in[38];
  const float* pcs_lw = (const float*)d_in[39];
  const float* pcs_lb = (const float*)d_in[40];
  const float* pcs_rw = (const float*)d_in[41];
  const float* tag2_w = (const float*)d_in[42];
  const float* tag2_b = (const float*)d_in[43];
  const float* sage5_lw = (const float*)d_in[44];
  const float* sage5_lb = (const float*)d_in[45];
  const float* sage5_rw = (const float*)d_in[46];
  const float* lin_w = (const float*)d_in[47];
  const float* lin_b = (const float*)d_in[48];
  const float* linl_w = (const float*)d_in[49];
  const float* linl_b = (const float*)d_in[50];

  const int Evv = in_sizes[3] / 2, Eh = in_sizes[5] / 2, Ein = in_sizes[7] / 2,
            Ess = in_sizes[8] / 2, Epp = in_sizes[9] / 2, Eps = in_sizes[10] / 2;
  const int* rvv = ei_vv;      const int* cvv = ei_vv + Evv;
  const int* rh = ei_hist;     const int* ch = ei_hist + Eh;
  const int* ri = ei_in;       const int* ci = ei_in + Ein;
  const int* rs = ei_ss;       const int* cs = ei_ss + Ess;
  const int* rp = ei_pp;       const int* cp = ei_pp + Epp;
  const int* rps = ei_ps;      const int* cps = ei_ps + Eps;

  // ---- workspace layout (floats). Peak ~136 MB, same as R1. ----
  float* ws = (float*)d_ws;
  const size_t NGH = (size_t)NG * H, NPH = (size_t)NP * H, NSH = (size_t)NS * H;
  float* g_tag = ws;            // tag10 out; later q; later tag2 h1/h2
  float* g = ws + NGH;          // rgcn out (long-lived)
  float* big = ws + 2 * NGH;    // 3*NGH arena
  float* small = ws + 5 * NGH;
  float* dinvG = small;
  float* dinvP = small + 50000;
  float* dinvS = small + 80000;
  float* cnt3 = small + 100000;   // 3*NG (becomes inv-counts)
  float* cntS = small + 250000;   // NS (becomes inv-counts)
  float* h7a = small + 270000;
  float* h7b = small + 620000;
  float* h7c = small + 970000;
  float* t32 = small + 1320000;   // NS*32
  float* z = small + 1960000;     // NS
  // arena aliases:
  float* agg = big;                       // rgcn: 3 planes NGH
  float* xW = big;                        // pc: NPH
  float* p1 = big + NPH;                  // pc: NPH
  float* p2 = big + 2 * NPH;              // pc final (lives until pcs sage)
  float* q = g_tag;                       // NGH
  float* v = big;                         // NGH (dead after resgated edge)
  float* kk = big + 3 * NPH;              // NSH
  float* S_a = big + 3 * NPH + NSH;       // NSH
  float* S_b = big + 3 * NPH + 2 * NSH;   // NSH
  float* m_buf = big + 3 * NPH;           // NSH (kk dead after edge kernel)
  float* tmp = big;                       // NSH sage scratch (v/xW dead; < p2)
  float* h1 = g_tag;                      // NSH
  float* h2 = g_tag + NSH;                // NSH

  // ================= game graph =================
  // TAGConv(game_x, 3 hops, 7-dim propagation)
  hipMemsetAsync(dinvG, 0, NG * 4, stream);
  k_count<<<nblk(Evv), 256, 0, stream>>>(cvv, Evv, dinvG);
  k_dinv<<<nblk(NG), 256, 0, stream>>>(dinvG, NG, 0.f);

  hipMemsetAsync(h7a, 0, NG * 7 * 4, stream);
  k_scatter_norm7<<<nblk((long long)Evv * 8), 256, 0, stream>>>(game_x, rvv, cvv, dinvG, Evv, h7a);
  hipMemsetAsync(h7b, 0, NG * 7 * 4, stream);
  k_scatter_norm7<<<nblk((long long)Evv * 8), 256, 0, stream>>>(h7a, rvv, cvv, dinvG, Evv, h7b);
  hipMemsetAsync(h7c, 0, NG * 7 * 4, stream);
  k_scatter_norm7<<<nblk((long long)Evv * 8), 256, 0, stream>>>(h7b, rvv, cvv, dinvG, Evv, h7c);

  k_init_bias128<<<nblk(NGH), 256, 0, stream>>>(g_tag, tag10_b, NG);
  k_gemm_acc128<<<nblk(NGH), 256, 0, stream>>>(game_x, tag10_w, g_tag, NG, 7);
  k_gemm_acc128<<<nblk(NGH), 256, 0, stream>>>(h7a, tag10_w + 7 * H, g_tag, NG, 7);
  k_gemm_acc128<<<nblk(NGH), 256, 0, stream>>>(h7b, tag10_w + 14 * H, g_tag, NG, 7);
  k_gemm_acc128<<<nblk(NGH), 256, 0, stream>>>(h7c, tag10_w + 21 * H, g_tag, NG, 7);
  k_relu<<<nblk(NGH), 256, 0, stream>>>(g_tag, NGH);

  // RGCN: per-relation sum + count, then (agg/cnt)@W_r accumulated via tgemm rowscale
  hipMemsetAsync(cnt3, 0, 3 * NG * 4, stream);
  k_count_rel<<<nblk(Evv), 256, 0, stream>>>(cvv, et_vv, Evv, cnt3, NG);
  k_invcnt<<<nblk(3 * NG), 256, 0, stream>>>(cnt3, 3 * NG);
  hipMemsetAsync(agg, 0, 3 * NGH * 4, stream);
  k_scatter_rel128<<<nblk((long long)Evv * 128), 256, 0, stream>>>(g_tag, rvv, cvv, et_vv, Evv, agg, (long long)NGH);
  k_tgemm<<<tg_grid(NG), 256, 0, stream>>>(agg, rgcn_w, rgcn_b, cnt3, g, NG, H, H, 0);
  k_tgemm<<<tg_grid(NG), 256, 0, stream>>>(agg + NGH, rgcn_w + H * H, nullptr, cnt3 + NG, g, NG, H, H, 1);
  k_tgemm<<<tg_grid(NG), 256, 0, stream>>>(agg + 2 * NGH, rgcn_w + 2 * H * H, nullptr, cnt3 + 2 * NG, g, NG, H, H, 1);
  k_tgemm<<<tg_grid(NG), 256, 0, stream>>>(g_tag, rgcn_root, nullptr, nullptr, g, NG, H, H, 3);  // accum+relu

  // ================= pc graph (2x GCN) =================
  hipMemsetAsync(dinvP, 0, NP * 4, stream);
  k_count<<<nblk(Epp), 256, 0, stream>>>(cp, Epp, dinvP);
  k_dinv<<<nblk(NP), 256, 0, stream>>>(dinvP, NP, 1.f);

  k_gemm128<<<nblk(NPH), 256, 0, stream>>>(pc_x, gcn1_w, nullptr, xW, NP, 5, 0);
  hipMemsetAsync(p1, 0, NPH * 4, stream);
  k_scatter_norm128<<<nblk((long long)Epp * 128), 256, 0, stream>>>(xW, rp, cp, dinvP, Epp, p1);
  k_gcn_epi<<<nblk(NPH), 256, 0, stream>>>(p1, xW, dinvP, gcn1_b, NP);

  k_tgemm<<<tg_grid(NP), 256, 0, stream>>>(p1, gcn2_w, nullptr, nullptr, xW, NP, H, H, 0);
  hipMemsetAsync(p2, 0, NPH * 4, stream);
  k_scatter_norm128<<<nblk((long long)Epp * 128), 256, 0, stream>>>(xW, rp, cp, dinvP, Epp, p2);
  k_gcn_epi<<<nblk(NPH), 256, 0, stream>>>(p2, xW, dinvP, gcn2_b, NP);

  // ================= ResGated (game -> state) =================
  k_gemm128<<<nblk(NSH), 256, 0, stream>>>(state_x, rg_key_w, rg_key_b, kk, NS, 6, 0);
  k_tgemm<<<tg_grid(NG), 256, 0, stream>>>(g, rg_query_w, rg_query_b, nullptr, q, NG, H, H, 0);
  k_tgemm<<<tg_grid(NG), 256, 0, stream>>>(g, rg_value_w, rg_value_b, nullptr, v, NG, H, H, 0);
  hipMemsetAsync(S_a, 0, NSH * 4, stream);
  k_resgated_edge<<<nblk((long long)Eh * 128), 256, 0, stream>>>(kk, q, v, ea_hist, rg_edge_w, rh, ch, Eh, S_a);
  k_rg_epi<<<nblk(NSH), 256, 0, stream>>>(S_a, state_x, rg_skip_w, rg_b, NS);

  // ================= sage32 (hist edges, xs=g) =================
  hipMemsetAsync(m_buf, 0, NSH * 4, stream);
  hipMemsetAsync(cntS, 0, NS * 4, stream);
  k_scatter_add128<<<nblk((long long)Eh * 128), 256, 0, stream>>>(g, rh, ch, Eh, m_buf, cntS);
  k_invcnt<<<nblk(NS), 256, 0, stream>>>(cntS, NS);
  k_tgemm<<<tg_grid(NS), 256, 0, stream>>>(m_buf, sage32_lw, sage32_lb, cntS, tmp, NS, H, H, 0);
  k_tgemm<<<tg_grid(NS), 256, 0, stream>>>(S_a, sage32_rw, nullptr, nullptr, tmp, NS, H, H, 1);
  k_norm_relu<<<NS, 128, 0, stream>>>(tmp, S_b);

  // ================= sage4 + sage42 (in edges, xs=g; shared mean) =================
  hipMemsetAsync(m_buf, 0, NSH * 4, stream);
  hipMemsetAsync(cntS, 0, NS * 4, stream);
  k_scatter_add128<<<nblk((long long)Ein * 128), 256, 0, stream>>>(g, ri, ci, Ein, m_buf, cntS);
  k_invcnt<<<nblk(NS), 256, 0, stream>>>(cntS, NS);
  k_tgemm<<<tg_grid(NS), 256, 0, stream>>>(m_buf, sage4_lw, sage4_lb, cntS, tmp, NS, H, H, 0);
  k_tgemm<<<tg_grid(NS), 256, 0, stream>>>(S_b, sage4_rw, nullptr, nullptr, tmp, NS, H, H, 1);
  k_norm_relu<<<NS, 128, 0, stream>>>(tmp, S_a);
  k_tgemm<<<tg_grid(NS), 256, 0, stream>>>(m_buf, sage42_lw, sage42_lb, cntS, tmp, NS, H, H, 0);
  k_tgemm<<<tg_grid(NS), 256, 0, stream>>>(S_a, sage42_rw, nullptr, nullptr, tmp, NS, H, H, 1);
  k_norm_relu<<<NS, 128, 0, stream>>>(tmp, S_b);

  // ================= pcs sage (pc->state, xs=p) =================
  hipMemsetAsync(m_buf, 0, NSH * 4, stream);
  hipMemsetAsync(cntS, 0, NS * 4, stream);
  k_scatter_add128<<<nblk((long long)Eps * 128), 256, 0, stream>>>(p2, rps, cps, Eps, m_buf, cntS);
  k_invcnt<<<nblk(NS), 256, 0, stream>>>(cntS, NS);
  k_tgemm<<<tg_grid(NS), 256, 0, stream>>>(m_buf, pcs_lw, pcs_lb, cntS, tmp, NS, H, H, 0);
  k_tgemm<<<tg_grid(NS), 256, 0, stream>>>(S_b, pcs_rw, nullptr, nullptr, tmp, NS, H, H, 1);
  k_norm_relu<<<NS, 128, 0, stream>>>(tmp, S_a);

  // ================= tag2 (state graph, 2 hops, 128-dim) =================
  hipMemsetAsync(dinvS, 0, NS * 4, stream);
  k_count<<<nblk(Ess), 256, 0, stream>>>(cs, Ess, dinvS);
  k_dinv<<<nblk(NS), 256, 0, stream>>>(dinvS, NS, 0.f);
  hipMemsetAsync(h1, 0, NSH * 4, stream);
  k_scatter_norm128<<<nblk((long long)Ess * 128), 256, 0, stream>>>(S_a, rs, cs, dinvS, Ess, h1);
  hipMemsetAsync(h2, 0, NSH * 4, stream);
  k_scatter_norm128<<<nblk((long long)Ess * 128), 256, 0, stream>>>(h1, rs, cs, dinvS, Ess, h2);
  k_tgemm<<<tg_grid(NS), 256, 0, stream>>>(S_a, tag2_w, tag2_b, nullptr, S_b, NS, H, H, 0);
  k_tgemm<<<tg_grid(NS), 256, 0, stream>>>(h1, tag2_w + H * H, nullptr, nullptr, S_b, NS, H, H, 1);
  k_tgemm<<<tg_grid(NS), 256, 0, stream>>>(h2, tag2_w + 2 * H * H, nullptr, nullptr, S_b, NS, H, H, 3);

  // ================= sage5 (state graph, xs=s) =================
  hipMemsetAsync(m_buf, 0, NSH * 4, stream);
  hipMemsetAsync(cntS, 0, NS * 4, stream);
  k_scatter_add128<<<nblk((long long)Ess * 128), 256, 0, stream>>>(S_b, rs, cs, Ess, m_buf, cntS);
  k_invcnt<<<nblk(NS), 256, 0, stream>>>(cntS, NS);
  k_tgemm<<<tg_grid(NS), 256, 0, stream>>>(m_buf, sage5_lw, sage5_lb, cntS, tmp, NS, H, H, 0);
  k_tgemm<<<tg_grid(NS), 256, 0, stream>>>(S_b, sage5_rw, nullptr, nullptr, tmp, NS, H, H, 1);
  k_norm_relu<<<NS, 128, 0, stream>>>(tmp, S_a);

  // ================= head =================
  k_gemmN<<<nblk((long long)NS * 32), 256, 0, stream>>>(S_a, lin_w, lin_b, t32, NS, H, 32, 1);
  k_gemmN<<<nblk(NS), 256, 0, stream>>>(t32, linl_w, linl_b, z, NS, 32, 1, 0);
  k_logsoftmax<<<1, 256, 0, stream>>>(z, (float*)d_out, NS);
}

// Round 3
// 1507.180 us; speedup vs baseline: 3.0548x; 1.6012x over previous
//
#include <hip/hip_runtime.h>
#include <cstdint>

#define H 128
static const int NG = 50000, NS = 20000, NP = 30000;

#define TG_ACC 1
#define TG_RELU 2
#define TG_NORM 4

static inline int nblk(long long n) { return (int)((n + 255) / 256); }

// ================= CSR build =================
__global__ void k_count_int(const int* __restrict__ col, int E, int* cnt) {
  int e = blockIdx.x * blockDim.x + threadIdx.x;
  if (e < E) atomicAdd(&cnt[col[e]], 1);
}

// per-512 block exclusive scan; bsum[b] = block total
__global__ void k_scan1(const int* __restrict__ cnt, int n, int* __restrict__ part,
                        int* __restrict__ bsum) {
  __shared__ int s[256];
  int b = blockIdx.x, t = threadIdx.x;
  int i0 = b * 512 + 2 * t;
  int a = (i0 < n) ? cnt[i0] : 0;
  int bb = (i0 + 1 < n) ? cnt[i0 + 1] : 0;
  s[t] = a + bb;
  __syncthreads();
  for (int off = 1; off < 256; off <<= 1) {
    int v = s[t];
    int u = (t >= off) ? s[t - off] : 0;
    __syncthreads();
    s[t] = v + u;
    __syncthreads();
  }
  int excl = (t > 0) ? s[t - 1] : 0;
  if (i0 < n) part[i0] = excl;
  if (i0 + 1 < n) part[i0 + 1] = excl + a;
  if (t == 255) bsum[b] = s[255];
}

__global__ void k_scan2(int* bsum, int nb) {
  if (threadIdx.x == 0) {
    int run = 0;
    for (int b = 0; b < nb; b++) { int t = bsum[b]; bsum[b] = run; run += t; }
  }
}

__global__ void k_scan3(int* rowptr, int* cursor, const int* __restrict__ bsum, int n, int E) {
  int i = blockIdx.x * blockDim.x + threadIdx.x;
  if (i < n) {
    int v = rowptr[i] + bsum[i >> 9];
    rowptr[i] = v;
    cursor[i] = v;
  }
  if (i == n) rowptr[n] = E;
}

// mode: 0 = store row, 1 = store row|(et<<16), 2 = store edge id
__global__ void k_fill(const int* __restrict__ row, const int* __restrict__ col,
                       const int* __restrict__ et, int E, int* cursor, int* eidx, int mode) {
  int e = blockIdx.x * blockDim.x + threadIdx.x;
  if (e < E) {
    int pos = atomicAdd(&cursor[col[e]], 1);
    int pay;
    if (mode == 2) pay = e;
    else if (mode == 1) pay = row[e] | (et[e] << 16);
    else pay = row[e];
    eidx[pos] = pay;
  }
}

__global__ void k_dinv_i(const int* __restrict__ cnt, int n, float addself, float* dinv) {
  int i = blockIdx.x * blockDim.x + threadIdx.x;
  if (i < n) {
    float d = (float)cnt[i] + addself;
    dinv[i] = (d > 0.f) ? rsqrtf(d) : 0.f;
  }
}

// ================= gathers =================
// mean over CSR segment; remap (nullable): si = remap[eidx[j]]
__global__ void k_gather_mean(const float* __restrict__ src, const int* __restrict__ eidx,
                              const int* __restrict__ rowptr, const int* __restrict__ remap,
                              float* __restrict__ out) {
  int c = blockIdx.x, h = threadIdx.x;
  int beg = rowptr[c], end = rowptr[c + 1];
  __shared__ int si[128];
  float acc = 0.f;
  for (int j0 = beg; j0 < end; j0 += 128) {
    int nn = min(128, end - j0);
    __syncthreads();
    if (h < nn) {
      int e = eidx[j0 + h];
      si[h] = remap ? remap[e] : e;
    }
    __syncthreads();
    int t = 0;
    for (; t + 4 <= nn; t += 4) {
      float a0 = src[(size_t)si[t] * H + h];
      float a1 = src[(size_t)si[t + 1] * H + h];
      float a2 = src[(size_t)si[t + 2] * H + h];
      float a3 = src[(size_t)si[t + 3] * H + h];
      acc += (a0 + a1) + (a2 + a3);
    }
    for (; t < nn; t++) acc += src[(size_t)si[t] * H + h];
  }
  int cnt = end - beg;
  out[(size_t)c * H + h] = acc * (1.f / (float)(cnt > 0 ? cnt : 1));
}

// per-relation mean (payload = r | et<<16), writes plane for relation relSel
__global__ void k_gather_rel1(const float* __restrict__ src, const int* __restrict__ eidx,
                              const int* __restrict__ rowptr, int relSel, float* __restrict__ out) {
  int c = blockIdx.x, h = threadIdx.x;
  int beg = rowptr[c], end = rowptr[c + 1];
  __shared__ int si[128];
  float acc = 0.f;
  int cnt = 0;
  for (int j0 = beg; j0 < end; j0 += 128) {
    int nn = min(128, end - j0);
    __syncthreads();
    if (h < nn) si[h] = eidx[j0 + h];
    __syncthreads();
    for (int t = 0; t < nn; t++) {
      int pk = si[t];
      if ((pk >> 16) == relSel) {
        acc += src[(size_t)(pk & 0xFFFF) * H + h];
        cnt++;
      }
    }
  }
  out[(size_t)c * H + h] = acc * (1.f / (float)(cnt > 0 ? cnt : 1));
}

// symmetric-normalized gather: acc = sum dinv[r]*src[r,:]; o = acc*dinv[c] (+ self + bias + relu)
__global__ void k_gather_norm(const float* __restrict__ src, int ldS, int offS,
                              const int* __restrict__ eidx, const int* __restrict__ rowptr,
                              const float* __restrict__ dinv, const float* __restrict__ selfX,
                              const float* __restrict__ bias, float* __restrict__ out,
                              int ldD, int offD, int relu) {
  int c = blockIdx.x, h = threadIdx.x;
  int beg = rowptr[c], end = rowptr[c + 1];
  __shared__ int si[128];
  __shared__ float sw[128];
  float acc = 0.f;
  for (int j0 = beg; j0 < end; j0 += 128) {
    int nn = min(128, end - j0);
    __syncthreads();
    if (h < nn) {
      int r = eidx[j0 + h];
      si[h] = r;
      sw[h] = dinv[r];
    }
    __syncthreads();
    int t = 0;
    for (; t + 4 <= nn; t += 4) {
      float a0 = sw[t] * src[(size_t)si[t] * ldS + offS + h];
      float a1 = sw[t + 1] * src[(size_t)si[t + 1] * ldS + offS + h];
      float a2 = sw[t + 2] * src[(size_t)si[t + 2] * ldS + offS + h];
      float a3 = sw[t + 3] * src[(size_t)si[t + 3] * ldS + offS + h];
      acc += (a0 + a1) + (a2 + a3);
    }
    for (; t < nn; t++) acc += sw[t] * src[(size_t)si[t] * ldS + offS + h];
  }
  float dc = dinv[c];
  float o = acc * dc;
  if (selfX) o += dc * dc * selfX[(size_t)c * H + h];
  if (bias) o += bias[h];
  if (relu) o = fmaxf(o, 0.f);
  out[(size_t)c * ldD + offD + h] = o;
}

// ResGated gather + skip(K=6) + bias + relu, fully fused
__global__ void k_resgated_gather(const float* __restrict__ kk, const float* __restrict__ q,
                                  const float* __restrict__ v, const float* __restrict__ ea,
                                  const float* __restrict__ We, const int* __restrict__ rh,
                                  const int* __restrict__ eidx, const int* __restrict__ rowptr,
                                  const float* __restrict__ sx, const float* __restrict__ Wsk,
                                  const float* __restrict__ rgb, float* __restrict__ out) {
  int c = blockIdx.x, h = threadIdx.x;
  int beg = rowptr[c], end = rowptr[c + 1];
  __shared__ int sr[64];
  __shared__ float se0[64], se1[64];
  float kload = kk[(size_t)c * H + h];
  float we0 = We[h], we1 = We[H + h];
  float acc = 0.f;
  for (int j0 = beg; j0 < end; j0 += 64) {
    int nn = min(64, end - j0);
    __syncthreads();
    if (h < nn) {
      int e = eidx[j0 + h];
      sr[h] = rh[e];
      se0[h] = ea[2 * e];
      se1[h] = ea[2 * e + 1];
    }
    __syncthreads();
    for (int t = 0; t < nn; t++) {
      int r = sr[t];
      float x = kload + q[(size_t)r * H + h] + se0[t] * we0 + se1[t] * we1;
      float eta = 1.f / (1.f + __expf(-x));
      acc += eta * v[(size_t)r * H + h];
    }
  }
  float skip = rgb[h];
#pragma unroll
  for (int f = 0; f < 6; f++) skip = fmaf(sx[c * 6 + f], Wsk[f * H + h], skip);
  out[(size_t)c * H + h] = fmaxf(acc + skip, 0.f);
}

// 7-dim normalized atomic scatter (tag10 hops) with strided src/dst
__global__ void k_scatter_norm7(const float* __restrict__ src, int ldS, int offS,
                                const int* __restrict__ row, const int* __restrict__ col,
                                const float* __restrict__ dinv, int E,
                                float* __restrict__ dst, int ldD, int offD) {
  long long t = (long long)blockIdx.x * blockDim.x + threadIdx.x;
  int e = (int)(t >> 3), f = (int)(t & 7);
  if (e < E && f < 7) {
    int r = row[e], c = col[e];
    atomicAdd(&dst[(size_t)c * ldD + offD + f], dinv[r] * dinv[c] * src[(size_t)r * ldS + offS + f]);
  }
}

// ================= small utility kernels =================
__global__ void k_copy7(const float* __restrict__ src, float* __restrict__ dst, int n) {
  long long t = (long long)blockIdx.x * blockDim.x + threadIdx.x;
  int i = (int)(t >> 3), f = (int)(t & 7);
  if (i < n && f < 7) dst[(size_t)i * 32 + f] = src[(size_t)i * 7 + f];
}

__global__ void k_copy_str(const float* __restrict__ src, float* __restrict__ dst, int n) {
  long long t = (long long)blockIdx.x * blockDim.x + threadIdx.x;
  int i = (int)(t >> 7), h = (int)(t & 127);
  if (i < n) dst[(size_t)i * 384 + h] = src[(size_t)i * H + h];
}

__global__ void k_buildW32(const float* __restrict__ w, float* __restrict__ W32) {
  int t = blockIdx.x * blockDim.x + threadIdx.x;  // 4096
  int k = t >> 7, h = t & 127;
  W32[t] = (k < 28) ? w[(size_t)k * H + h] : 0.f;
}

__global__ void k_gemm128(const float* __restrict__ X, const float* __restrict__ W,
                          const float* __restrict__ b, float* out, int M, int K, int act) {
  long long t = (long long)blockIdx.x * blockDim.x + threadIdx.x;
  if (t >= (long long)M * H) return;
  int i = (int)(t >> 7), h = (int)(t & 127);
  float acc = b ? b[h] : 0.f;
  const float* x = X + (long long)i * K;
  for (int k = 0; k < K; k++) acc = fmaf(x[k], W[k * H + h], acc);
  if (act) acc = fmaxf(acc, 0.f);
  out[t] = acc;
}

__global__ void k_gemmN(const float* __restrict__ X, const float* __restrict__ W,
                        const float* __restrict__ b, float* out, int M, int K, int N, int act) {
  long long t = (long long)blockIdx.x * blockDim.x + threadIdx.x;
  if (t >= (long long)M * N) return;
  int i = (int)(t / N), h = (int)(t % N);
  float acc = b ? b[h] : 0.f;
  const float* x = X + (long long)i * K;
  for (int k = 0; k < K; k++) acc = fmaf(x[k], W[k * N + h], acc);
  if (act) acc = fmaxf(acc, 0.f);
  out[t] = acc;
}

// ================= tiled SGEMM, N=128 fixed, BM=64 =================
// flags: TG_ACC (o += Cin[row]), TG_RELU, TG_NORM (row L2-normalize then relu)
__global__ __launch_bounds__(256) void k_tgemm(const float* __restrict__ X,
                                               const float* __restrict__ W,
                                               const float* __restrict__ bias,
                                               const float* __restrict__ Cin,
                                               float* __restrict__ Cout,
                                               int M, int K, int flags) {
  __shared__ float Xs[16][68];
  __shared__ float Ws[16][132];
  __shared__ float rsum[64];
  int tid = threadIdx.x;
  int tx = tid & 15, ty = tid >> 4;
  int rowBase = blockIdx.x * 64;
  int lr = tid >> 2, lk = (tid & 3) * 4;
  int xrow = rowBase + lr;
  int p1 = tid + 256;
  float acc[4][8] = {};
  for (int k0 = 0; k0 < K; k0 += 16) {
    float4 xv = make_float4(0.f, 0.f, 0.f, 0.f);
    if (xrow < M) xv = *(const float4*)(X + (size_t)xrow * K + k0 + lk);
    float4 w0 = *(const float4*)(W + (size_t)(k0 + (tid >> 5)) * H + (tid & 31) * 4);
    float4 w1 = *(const float4*)(W + (size_t)(k0 + (p1 >> 5)) * H + (p1 & 31) * 4);
    __syncthreads();
    Xs[lk + 0][lr] = xv.x;
    Xs[lk + 1][lr] = xv.y;
    Xs[lk + 2][lr] = xv.z;
    Xs[lk + 3][lr] = xv.w;
    *(float4*)&Ws[tid >> 5][(tid & 31) * 4] = w0;
    *(float4*)&Ws[p1 >> 5][(p1 & 31) * 4] = w1;
    __syncthreads();
#pragma unroll
    for (int kk = 0; kk < 16; kk++) {
      float4 xf = *(const float4*)&Xs[kk][ty * 4];
      float4 wa = *(const float4*)&Ws[kk][tx * 8];
      float4 wb = *(const float4*)&Ws[kk][tx * 8 + 4];
      float xr[4] = {xf.x, xf.y, xf.z, xf.w};
      float wc[8] = {wa.x, wa.y, wa.z, wa.w, wb.x, wb.y, wb.z, wb.w};
#pragma unroll
      for (int j = 0; j < 4; j++)
#pragma unroll
        for (int i = 0; i < 8; i++) acc[j][i] = fmaf(xr[j], wc[i], acc[j][i]);
    }
  }
  float bcol[8] = {};
  if (bias) {
    float4 ba = *(const float4*)(bias + tx * 8);
    float4 bb = *(const float4*)(bias + tx * 8 + 4);
    bcol[0] = ba.x; bcol[1] = ba.y; bcol[2] = ba.z; bcol[3] = ba.w;
    bcol[4] = bb.x; bcol[5] = bb.y; bcol[6] = bb.z; bcol[7] = bb.w;
  }
  float o[4][8];
#pragma unroll
  for (int j = 0; j < 4; j++) {
    int row = rowBase + ty * 4 + j;
#pragma unroll
    for (int i = 0; i < 8; i++) o[j][i] = acc[j][i] + bcol[i];
    if ((flags & TG_ACC) && row < M) {
      float4 pa = *(const float4*)(Cin + (size_t)row * H + tx * 8);
      float4 pb = *(const float4*)(Cin + (size_t)row * H + tx * 8 + 4);
      o[j][0] += pa.x; o[j][1] += pa.y; o[j][2] += pa.z; o[j][3] += pa.w;
      o[j][4] += pb.x; o[j][5] += pb.y; o[j][6] += pb.z; o[j][7] += pb.w;
    }
  }
  if (flags & TG_NORM) {
    if (tid < 64) rsum[tid] = 0.f;
    __syncthreads();
#pragma unroll
    for (int j = 0; j < 4; j++) {
      int row = rowBase + ty * 4 + j;
      if (row < M) {
        float s = 0.f;
#pragma unroll
        for (int i = 0; i < 8; i++) s = fmaf(o[j][i], o[j][i], s);
        atomicAdd(&rsum[ty * 4 + j], s);
      }
    }
    __syncthreads();
#pragma unroll
    for (int j = 0; j < 4; j++) {
      float f = 1.f / fmaxf(sqrtf(rsum[ty * 4 + j]), 1e-12f);
#pragma unroll
      for (int i = 0; i < 8; i++) o[j][i] = fmaxf(o[j][i] * f, 0.f);
    }
  } else if (flags & TG_RELU) {
#pragma unroll
    for (int j = 0; j < 4; j++)
#pragma unroll
      for (int i = 0; i < 8; i++) o[j][i] = fmaxf(o[j][i], 0.f);
  }
#pragma unroll
  for (int j = 0; j < 4; j++) {
    int row = rowBase + ty * 4 + j;
    if (row < M) {
      *(float4*)(Cout + (size_t)row * H + tx * 8) = make_float4(o[j][0], o[j][1], o[j][2], o[j][3]);
      *(float4*)(Cout + (size_t)row * H + tx * 8 + 4) = make_float4(o[j][4], o[j][5], o[j][6], o[j][7]);
    }
  }
}

static inline int tgb(int M) { return (M + 63) / 64; }

// ================= log_softmax over axis 0 =================
__global__ void k_logsoftmax(const float* __restrict__ z, float* __restrict__ out, int n) {
  __shared__ float red[256];
  int tid = threadIdx.x;
  float m = -1e30f;
  for (int i = tid; i < n; i += 256) m = fmaxf(m, z[i]);
  red[tid] = m;
  __syncthreads();
  for (int s = 128; s > 0; s >>= 1) {
    if (tid < s) red[tid] = fmaxf(red[tid], red[tid + s]);
    __syncthreads();
  }
  float mx = red[0];
  __syncthreads();
  float sum = 0.f;
  for (int i = tid; i < n; i += 256) sum += __expf(z[i] - mx);
  red[tid] = sum;
  __syncthreads();
  for (int s = 128; s > 0; s >>= 1) {
    if (tid < s) red[tid] += red[tid + s];
    __syncthreads();
  }
  float lse = mx + logf(red[0]);
  for (int i = tid; i < n; i += 256) out[i] = z[i] - lse;
}

extern "C" void kernel_launch(void* const* d_in, const int* in_sizes, int n_in,
                              void* d_out, int out_size, void* d_ws, size_t ws_size,
                              hipStream_t stream) {
  const float* game_x = (const float*)d_in[0];
  const float* state_x = (const float*)d_in[1];
  const float* pc_x = (const float*)d_in[2];
  const int* ei_vv = (const int*)d_in[3];
  const int* et_vv = (const int*)d_in[4];
  const int* ei_hist = (const int*)d_in[5];
  const float* ea_hist = (const float*)d_in[6];
  const int* ei_in = (const int*)d_in[7];
  const int* ei_ss = (const int*)d_in[8];
  const int* ei_pp = (const int*)d_in[9];
  const int* ei_ps = (const int*)d_in[10];
  const float* tag10_w = (const float*)d_in[12];
  const float* tag10_b = (const float*)d_in[13];
  const float* rgcn_w = (const float*)d_in[14];
  const float* rgcn_root = (const float*)d_in[15];
  const float* rgcn_b = (const float*)d_in[16];
  const float* gcn1_w = (const float*)d_in[17];
  const float* gcn1_b = (const float*)d_in[18];
  const float* gcn2_w = (const float*)d_in[19];
  const float* gcn2_b = (const float*)d_in[20];
  const float* rg_key_w = (const float*)d_in[21];
  const float* rg_key_b = (const float*)d_in[22];
  const float* rg_query_w = (const float*)d_in[23];
  const float* rg_query_b = (const float*)d_in[24];
  const float* rg_value_w = (const float*)d_in[25];
  const float* rg_value_b = (const float*)d_in[26];
  const float* rg_edge_w = (const float*)d_in[27];
  const float* rg_skip_w = (const float*)d_in[28];
  const float* rg_b = (const float*)d_in[29];
  const float* sage32_lw = (const float*)d_in[30];
  const float* sage32_lb = (const float*)d_in[31];
  const float* sage32_rw = (const float*)d_in[32];
  const float* sage4_lw = (const float*)d_in[33];
  const float* sage4_lb = (const float*)d_in[34];
  const float* sage4_rw = (const float*)d_in[35];
  const float* sage42_lw = (const float*)d_in[36];
  const float* sage42_lb = (const float*)d_in[37];
  const float* sage42_rw = (const float*)d_in[38];
  const float* pcs_lw = (const float*)d_in[39];
  const float* pcs_lb = (const float*)d_in[40];
  const float* pcs_rw = (const float*)d_in[41];
  const float* tag2_w = (const float*)d_in[42];
  const float* tag2_b = (const float*)d_in[43];
  const float* sage5_lw = (const float*)d_in[44];
  const float* sage5_lb = (const float*)d_in[45];
  const float* sage5_rw = (const float*)d_in[46];
  const float* lin_w = (const float*)d_in[47];
  const float* lin_b = (const float*)d_in[48];
  const float* linl_w = (const float*)d_in[49];
  const float* linl_b = (const float*)d_in[50];

  const int Evv = in_sizes[3] / 2, Eh = in_sizes[5] / 2, Ein = in_sizes[7] / 2,
            Ess = in_sizes[8] / 2, Epp = in_sizes[9] / 2, Eps = in_sizes[10] / 2;
  const int* rvv = ei_vv;       const int* cvv = ei_vv + Evv;
  const int* rh = ei_hist;      const int* ch = ei_hist + Eh;
  const int* ri = ei_in;        const int* ci = ei_in + Ein;
  const int* rs = ei_ss;        const int* cs = ei_ss + Ess;
  const int* rp_pc = ei_pp;     const int* cp_pc = ei_pp + Epp;
  const int* rps = ei_ps;       const int* cps = ei_ps + Eps;

  // ---- workspace layout (floats). Peak ~150 MB. ----
  float* ws = (float*)d_ws;
  const size_t NGH = (size_t)NG * H, NPH = (size_t)NP * H, NSH = (size_t)NS * H;
  float* g_tag = ws;                 // 6.4M: tag10 out; later q
  float* g = ws + NGH;               // 6.4M: rgcn out (long-lived)
  float* C0 = ws + 2 * NGH;          // 11.52M arena
  float* S_a = C0 + 3 * NPH;
  float* S_b = S_a + NSH;
  float* m_buf = S_b + NSH;
  float* tmp = m_buf + NSH;          // also kk
  int* ip = (int*)(tmp + NSH);
  // CSR region
  int* vv_rp = ip; ip += NG + 1;  int* vv_cur = ip; ip += NG;  int* vv_ei = ip; ip += Evv;
  int* pp_rp = ip; ip += NP + 1;  int* pp_cur = ip; ip += NP;  int* pp_ei = ip; ip += Epp;
  int* hh_rp = ip; ip += NS + 1;  int* hh_cur = ip; ip += NS;  int* hh_ei = ip; ip += Eh;
  int* in_rp = ip; ip += NS + 1;  int* in_cur = ip; ip += NS;  int* in_ei = ip; ip += Ein;
  int* ps_rp = ip; ip += NS + 1;  int* ps_cur = ip; ip += NS;  int* ps_ei = ip; ip += Eps;
  int* ss_rp = ip; ip += NS + 1;  int* ss_cur = ip; ip += NS;  int* ss_ei = ip; ip += Ess;
  int* cntI = ip; ip += NG;       // count scratch (max n)
  int* bsum = ip; ip += 256;
  float* fp = (float*)ip;
  float* dinvG = fp; fp += NG;
  float* dinvP = fp; fp += NP;
  float* dinvS = fp; fp += NS;
  float* t32 = fp; fp += (size_t)NS * 32;
  float* z = fp; fp += NS;
  float* W32 = fp; fp += 32 * H;
  // arena aliases (sequential lifetimes):
  float* P_tag10 = C0;               // NG*32 (phase 1)
  float* plane = C0;                 // NGH (phase 2)
  float* xW = C0;                    // NPH (phase 3)
  float* p1b = C0 + NPH;             // NPH
  float* p2b = C0 + 2 * NPH;         // NPH (lives to pcs sage)
  float* v = C0;                     // NGH (phase 4; xW/p1b dead, fits before p2b? 6.4M < 7.68M OK)
  float* q = g_tag;                  // NGH (after rgcn root)
  float* kk = tmp;
  float* P_tag2 = C0;                // NS*384 = 7.68M (phase 8; p2b dead)

  // ---- CSR builds (+ dinv from counts) ----
  auto build = [&](const int* col, int n, int E, const int* row, const int* et, int mode,
                   int* rp, int* cur, int* ei, float* dinv, float addself) {
    hipMemsetAsync(cntI, 0, (size_t)n * 4, stream);
    k_count_int<<<nblk(E), 256, 0, stream>>>(col, E, cntI);
    if (dinv) k_dinv_i<<<nblk(n), 256, 0, stream>>>(cntI, n, addself, dinv);
    int nb = (n + 511) / 512;
    k_scan1<<<nb, 256, 0, stream>>>(cntI, n, rp, bsum);
    k_scan2<<<1, 64, 0, stream>>>(bsum, nb);
    k_scan3<<<nblk(n + 1), 256, 0, stream>>>(rp, cur, bsum, n, E);
    k_fill<<<nblk(E), 256, 0, stream>>>(row, col, et, E, cur, ei, mode);
  };
  build(cvv, NG, Evv, rvv, et_vv, 1, vv_rp, vv_cur, vv_ei, dinvG, 0.f);
  build(cp_pc, NP, Epp, rp_pc, nullptr, 0, pp_rp, pp_cur, pp_ei, dinvP, 1.f);
  build(ch, NS, Eh, rh, nullptr, 2, hh_rp, hh_cur, hh_ei, nullptr, 0.f);
  build(ci, NS, Ein, ri, nullptr, 0, in_rp, in_cur, in_ei, nullptr, 0.f);
  build(cps, NS, Eps, rps, nullptr, 0, ps_rp, ps_cur, ps_ei, nullptr, 0.f);
  build(cs, NS, Ess, rs, nullptr, 0, ss_rp, ss_cur, ss_ei, dinvS, 0.f);

  // ================= phase 1: TAGConv game (K packed to 32) =================
  hipMemsetAsync(P_tag10, 0, (size_t)NG * 32 * 4, stream);
  k_copy7<<<nblk((long long)NG * 8), 256, 0, stream>>>(game_x, P_tag10, NG);
  k_scatter_norm7<<<nblk((long long)Evv * 8), 256, 0, stream>>>(game_x, 7, 0, rvv, cvv, dinvG, Evv, P_tag10, 32, 7);
  k_scatter_norm7<<<nblk((long long)Evv * 8), 256, 0, stream>>>(P_tag10, 32, 7, rvv, cvv, dinvG, Evv, P_tag10, 32, 14);
  k_scatter_norm7<<<nblk((long long)Evv * 8), 256, 0, stream>>>(P_tag10, 32, 14, rvv, cvv, dinvG, Evv, P_tag10, 32, 21);
  k_buildW32<<<16, 256, 0, stream>>>(tag10_w, W32);
  k_tgemm<<<tgb(NG), 256, 0, stream>>>(P_tag10, W32, tag10_b, nullptr, g_tag, NG, 32, TG_RELU);

  // ================= phase 2: RGCN (per-relation mean gather + GEMM) =================
  for (int r = 0; r < 3; r++) {
    k_gather_rel1<<<NG, 128, 0, stream>>>(g_tag, vv_ei, vv_rp, r, plane);
    k_tgemm<<<tgb(NG), 256, 0, stream>>>(plane, rgcn_w + (size_t)r * H * H,
                                         r == 0 ? rgcn_b : nullptr,
                                         r == 0 ? nullptr : g, g, NG, H,
                                         r == 0 ? 0 : TG_ACC);
  }
  k_tgemm<<<tgb(NG), 256, 0, stream>>>(g_tag, rgcn_root, nullptr, g, g, NG, H, TG_ACC | TG_RELU);

  // ================= phase 3: pc graph (2x GCN, gather + fused epilogue) =================
  k_gemm128<<<nblk((long long)NPH), 256, 0, stream>>>(pc_x, gcn1_w, nullptr, xW, NP, 5, 0);
  k_gather_norm<<<NP, 128, 0, stream>>>(xW, H, 0, pp_ei, pp_rp, dinvP, xW, gcn1_b, p1b, H, 0, 1);
  k_tgemm<<<tgb(NP), 256, 0, stream>>>(p1b, gcn2_w, nullptr, nullptr, xW, NP, H, 0);
  k_gather_norm<<<NP, 128, 0, stream>>>(xW, H, 0, pp_ei, pp_rp, dinvP, xW, gcn2_b, p2b, H, 0, 1);

  // ================= phase 4: ResGated (game -> state) =================
  k_gemm128<<<nblk((long long)NSH), 256, 0, stream>>>(state_x, rg_key_w, rg_key_b, kk, NS, 6, 0);
  k_tgemm<<<tgb(NG), 256, 0, stream>>>(g, rg_query_w, rg_query_b, nullptr, q, NG, H, 0);
  k_tgemm<<<tgb(NG), 256, 0, stream>>>(g, rg_value_w, rg_value_b, nullptr, v, NG, H, 0);
  k_resgated_gather<<<NS, 128, 0, stream>>>(kk, q, v, ea_hist, rg_edge_w, rh, hh_ei, hh_rp,
                                            state_x, rg_skip_w, rg_b, S_a);

  // ================= phase 5: sage32 (hist, xs=g) =================
  k_gather_mean<<<NS, 128, 0, stream>>>(g, hh_ei, hh_rp, rh, m_buf);
  k_tgemm<<<tgb(NS), 256, 0, stream>>>(m_buf, sage32_lw, sage32_lb, nullptr, tmp, NS, H, 0);
  k_tgemm<<<tgb(NS), 256, 0, stream>>>(S_a, sage32_rw, nullptr, tmp, S_b, NS, H, TG_ACC | TG_NORM);

  // ================= phase 6: sage4 + sage42 (in, xs=g; shared mean) =================
  k_gather_mean<<<NS, 128, 0, stream>>>(g, in_ei, in_rp, nullptr, m_buf);
  k_tgemm<<<tgb(NS), 256, 0, stream>>>(m_buf, sage4_lw, sage4_lb, nullptr, tmp, NS, H, 0);
  k_tgemm<<<tgb(NS), 256, 0, stream>>>(S_b, sage4_rw, nullptr, tmp, S_a, NS, H, TG_ACC | TG_NORM);
  k_tgemm<<<tgb(NS), 256, 0, stream>>>(m_buf, sage42_lw, sage42_lb, nullptr, tmp, NS, H, 0);
  k_tgemm<<<tgb(NS), 256, 0, stream>>>(S_a, sage42_rw, nullptr, tmp, S_b, NS, H, TG_ACC | TG_NORM);

  // ================= phase 7: pcs sage (pc->state) =================
  k_gather_mean<<<NS, 128, 0, stream>>>(p2b, ps_ei, ps_rp, nullptr, m_buf);
  k_tgemm<<<tgb(NS), 256, 0, stream>>>(m_buf, pcs_lw, pcs_lb, nullptr, tmp, NS, H, 0);
  k_tgemm<<<tgb(NS), 256, 0, stream>>>(S_b, pcs_rw, nullptr, tmp, S_a, NS, H, TG_ACC | TG_NORM);

  // ================= phase 8: tag2 (state graph, K packed to 384) =================
  k_copy_str<<<nblk((long long)NSH), 256, 0, stream>>>(S_a, P_tag2, NS);
  k_gather_norm<<<NS, 128, 0, stream>>>(S_a, H, 0, ss_ei, ss_rp, dinvS, nullptr, nullptr, P_tag2, 384, 128, 0);
  k_gather_norm<<<NS, 128, 0, stream>>>(P_tag2, 384, 128, ss_ei, ss_rp, dinvS, nullptr, nullptr, P_tag2, 384, 256, 0);
  k_tgemm<<<tgb(NS), 256, 0, stream>>>(P_tag2, tag2_w, tag2_b, nullptr, S_b, NS, 384, TG_RELU);

  // ================= phase 9: sage5 (state graph, xs=xd=s) =================
  k_gather_mean<<<NS, 128, 0, stream>>>(S_b, ss_ei, ss_rp, nullptr, m_buf);
  k_tgemm<<<tgb(NS), 256, 0, stream>>>(m_buf, sage5_lw, sage5_lb, nullptr, tmp, NS, H, 0);
  k_tgemm<<<tgb(NS), 256, 0, stream>>>(S_b, sage5_rw, nullptr, tmp, S_a, NS, H, TG_ACC | TG_NORM);

  // ================= head =================
  k_gemmN<<<nblk((long long)NS * 32), 256, 0, stream>>>(S_a, lin_w, lin_b, t32, NS, H, 32, 1);
  k_gemmN<<<nblk(NS), 256, 0, stream>>>(t32, linl_w, linl_b, z, NS, 32, 1, 0);
  k_logsoftmax<<<1, 256, 0, stream>>>(z, (float*)d_out, NS);
}

// Round 4
// 1268.661 us; speedup vs baseline: 3.6291x; 1.1880x over previous
//
#include <hip/hip_runtime.h>
#include <cstdint>

#define H 128
static const int NG = 50000, NS = 20000, NP = 30000;

#define TG_ACC 1
#define TG_RELU 2

static inline int nblk(long long n) { return (int)((n + 255) / 256); }

// ================= batched CSR build =================
struct Seg6 {
  const int* col[6];
  const int* row[6];
  const int* et0;      // etype for graph 0 only
  int nodeoff[7];
  int edgeoff[7];
  int mode[6];         // 0=row, 1=row|(et<<16), 2=edge id (local)
  float addself[6];
  int hasdinv[6];
};

__global__ void k_count_all(Seg6 sg, int EE, int* __restrict__ cnt) {
  int e = blockIdx.x * blockDim.x + threadIdx.x;
  if (e >= EE) return;
  int gi = 0;
  while (e >= sg.edgeoff[gi + 1]) gi++;
  int le = e - sg.edgeoff[gi];
  atomicAdd(&cnt[sg.nodeoff[gi] + sg.col[gi][le]], 1);
}

__global__ void k_dinv_all(Seg6 sg, int NN, const int* __restrict__ cnt, float* __restrict__ dinv) {
  int i = blockIdx.x * blockDim.x + threadIdx.x;
  if (i >= NN) return;
  int gi = 0;
  while (i >= sg.nodeoff[gi + 1]) gi++;
  if (!sg.hasdinv[gi]) return;
  float d = (float)cnt[i] + sg.addself[gi];
  dinv[i] = (d > 0.f) ? rsqrtf(d) : 0.f;
}

__global__ void k_scan1(const int* __restrict__ cnt, int n, int* __restrict__ part,
                        int* __restrict__ bsum) {
  __shared__ int s[256];
  int b = blockIdx.x, t = threadIdx.x;
  int i0 = b * 512 + 2 * t;
  int a = (i0 < n) ? cnt[i0] : 0;
  int bb = (i0 + 1 < n) ? cnt[i0 + 1] : 0;
  s[t] = a + bb;
  __syncthreads();
  for (int off = 1; off < 256; off <<= 1) {
    int v = s[t];
    int u = (t >= off) ? s[t - off] : 0;
    __syncthreads();
    s[t] = v + u;
    __syncthreads();
  }
  int excl = (t > 0) ? s[t - 1] : 0;
  if (i0 < n) part[i0] = excl;
  if (i0 + 1 < n) part[i0 + 1] = excl + a;
  if (t == 255) bsum[b] = s[255];
}

__global__ void k_scan2(int* bsum, int nb) {
  if (threadIdx.x == 0) {
    int run = 0;
    for (int b = 0; b < nb; b++) { int t = bsum[b]; bsum[b] = run; run += t; }
  }
}

__global__ void k_scan3(int* rowptr, int* cursor, const int* __restrict__ bsum, int n, int E) {
  int i = blockIdx.x * blockDim.x + threadIdx.x;
  if (i < n) {
    int v = rowptr[i] + bsum[i >> 9];
    rowptr[i] = v;
    cursor[i] = v;
  }
  if (i == n) rowptr[n] = E;
}

__global__ void k_fill_all(Seg6 sg, int EE, int* cursor, int* __restrict__ eidx) {
  int e = blockIdx.x * blockDim.x + threadIdx.x;
  if (e >= EE) return;
  int gi = 0;
  while (e >= sg.edgeoff[gi + 1]) gi++;
  int le = e - sg.edgeoff[gi];
  int c = sg.col[gi][le];
  int pos = atomicAdd(&cursor[sg.nodeoff[gi] + c], 1);
  int m = sg.mode[gi];
  int pay;
  if (m == 2) pay = le;
  else {
    pay = sg.row[gi][le];
    if (m == 1) pay |= sg.et0[le] << 16;
  }
  eidx[pos] = pay;
}

// ================= gathers =================
__global__ void k_gather_mean(const float* __restrict__ src, const int* __restrict__ eidx,
                              const int* __restrict__ rowptr, const int* __restrict__ remap,
                              float* __restrict__ out) {
  int c = blockIdx.x, h = threadIdx.x;
  int beg = rowptr[c], end = rowptr[c + 1];
  __shared__ int si[128];
  float acc = 0.f;
  for (int j0 = beg; j0 < end; j0 += 128) {
    int nn = min(128, end - j0);
    __syncthreads();
    if (h < nn) {
      int e = eidx[j0 + h];
      si[h] = remap ? remap[e] : e;
    }
    __syncthreads();
    int t = 0;
    for (; t + 4 <= nn; t += 4) {
      float a0 = src[(size_t)si[t] * H + h];
      float a1 = src[(size_t)si[t + 1] * H + h];
      float a2 = src[(size_t)si[t + 2] * H + h];
      float a3 = src[(size_t)si[t + 3] * H + h];
      acc += (a0 + a1) + (a2 + a3);
    }
    for (; t < nn; t++) acc += src[(size_t)si[t] * H + h];
  }
  int cnt = end - beg;
  out[(size_t)c * H + h] = acc * (1.f / (float)(cnt > 0 ? cnt : 1));
}

// single-pass 3-relation mean; writes concatenated [rel0|rel1|rel2] row of width 384
__global__ void k_gather_rel3(const float* __restrict__ src, const int* __restrict__ eidx,
                              const int* __restrict__ rowptr, float* __restrict__ G3) {
  int c = blockIdx.x, h = threadIdx.x;
  int beg = rowptr[c], end = rowptr[c + 1];
  __shared__ int si[128];
  float a0 = 0.f, a1 = 0.f, a2 = 0.f;
  int c0 = 0, c1 = 0, c2 = 0;
  for (int j0 = beg; j0 < end; j0 += 128) {
    int nn = min(128, end - j0);
    __syncthreads();
    if (h < nn) si[h] = eidx[j0 + h];
    __syncthreads();
    for (int t = 0; t < nn; t++) {
      int pk = si[t];
      int rel = pk >> 16;
      float val = src[(size_t)(pk & 0xFFFF) * H + h];
      if (rel == 0) { a0 += val; c0++; }
      else if (rel == 1) { a1 += val; c1++; }
      else { a2 += val; c2++; }
    }
  }
  size_t base = (size_t)c * 384;
  G3[base + h] = a0 * (1.f / (float)(c0 > 0 ? c0 : 1));
  G3[base + 128 + h] = a1 * (1.f / (float)(c1 > 0 ? c1 : 1));
  G3[base + 256 + h] = a2 * (1.f / (float)(c2 > 0 ? c2 : 1));
}

// symmetric-normalized gather (+ optional self + bias + relu), strided src/dst
__global__ void k_gather_norm(const float* __restrict__ src, int ldS, int offS,
                              const int* __restrict__ eidx, const int* __restrict__ rowptr,
                              const float* __restrict__ dinv, const float* __restrict__ selfX,
                              const float* __restrict__ bias, float* __restrict__ out,
                              int ldD, int offD, int relu) {
  int c = blockIdx.x, h = threadIdx.x;
  int beg = rowptr[c], end = rowptr[c + 1];
  __shared__ int si[128];
  __shared__ float sw[128];
  float acc = 0.f;
  for (int j0 = beg; j0 < end; j0 += 128) {
    int nn = min(128, end - j0);
    __syncthreads();
    if (h < nn) {
      int r = eidx[j0 + h];
      si[h] = r;
      sw[h] = dinv[r];
    }
    __syncthreads();
    int t = 0;
    for (; t + 4 <= nn; t += 4) {
      float a0 = sw[t] * src[(size_t)si[t] * ldS + offS + h];
      float a1 = sw[t + 1] * src[(size_t)si[t + 1] * ldS + offS + h];
      float a2 = sw[t + 2] * src[(size_t)si[t + 2] * ldS + offS + h];
      float a3 = sw[t + 3] * src[(size_t)si[t + 3] * ldS + offS + h];
      acc += (a0 + a1) + (a2 + a3);
    }
    for (; t < nn; t++) acc += sw[t] * src[(size_t)si[t] * ldS + offS + h];
  }
  float dc = dinv[c];
  float o = acc * dc;
  if (selfX) o += dc * dc * selfX[(size_t)c * H + h];
  if (bias) o += bias[h];
  if (relu) o = fmaxf(o, 0.f);
  out[(size_t)c * ldD + offD + h] = o;
}

// 7-dim symmetric-normalized gather (payload may carry et in high bits -> masked)
__global__ void k_gather_norm7(const float* __restrict__ src, int ldS, int offS,
                               const int* __restrict__ eidx, const int* __restrict__ rowptr,
                               const float* __restrict__ dinv, float* __restrict__ dst,
                               int ldD, int offD) {
  int c = blockIdx.x;
  int t = threadIdx.x;  // 64
  int f = t & 7, j = t >> 3;
  int beg = rowptr[c], end = rowptr[c + 1];
  __shared__ int si[64];
  __shared__ float sw[64];
  __shared__ float red[8][8];
  float acc = 0.f;
  for (int j0 = beg; j0 < end; j0 += 64) {
    int nn = min(64, end - j0);
    __syncthreads();
    if (t < nn) {
      int r = eidx[j0 + t] & 0xFFFF;
      si[t] = r;
      sw[t] = dinv[r];
    }
    __syncthreads();
    if (f < 7)
      for (int u = j; u < nn; u += 8) acc += sw[u] * src[(size_t)si[u] * ldS + offS + f];
  }
  red[j][f] = acc;
  __syncthreads();
  if (j == 0 && f < 7) {
    float s = 0.f;
    for (int u = 0; u < 8; u++) s += red[u][f];
    dst[(size_t)c * ldD + offD + f] = s * dinv[c];
  }
}

// ResGated gather + skip(K=6) + bias + relu
__global__ void k_resgated_gather(const float* __restrict__ kk, const float* __restrict__ q,
                                  const float* __restrict__ v, const float* __restrict__ ea,
                                  const float* __restrict__ We, const int* __restrict__ rh,
                                  const int* __restrict__ eidx, const int* __restrict__ rowptr,
                                  const float* __restrict__ sx, const float* __restrict__ Wsk,
                                  const float* __restrict__ rgb, float* __restrict__ out) {
  int c = blockIdx.x, h = threadIdx.x;
  int beg = rowptr[c], end = rowptr[c + 1];
  __shared__ int sr[64];
  __shared__ float se0[64], se1[64];
  float kload = kk[(size_t)c * H + h];
  float we0 = We[h], we1 = We[H + h];
  float acc = 0.f;
  for (int j0 = beg; j0 < end; j0 += 64) {
    int nn = min(64, end - j0);
    __syncthreads();
    if (h < nn) {
      int e = eidx[j0 + h];
      sr[h] = rh[e];
      se0[h] = ea[2 * e];
      se1[h] = ea[2 * e + 1];
    }
    __syncthreads();
    for (int t = 0; t < nn; t++) {
      int r = sr[t];
      float x = kload + q[(size_t)r * H + h] + se0[t] * we0 + se1[t] * we1;
      float eta = 1.f / (1.f + __expf(-x));
      acc += eta * v[(size_t)r * H + h];
    }
  }
  float skip = rgb[h];
#pragma unroll
  for (int f = 0; f < 6; f++) skip = fmaf(sx[c * 6 + f], Wsk[f * H + h], skip);
  out[(size_t)c * H + h] = fmaxf(acc + skip, 0.f);
}

// ================= small utilities =================
__global__ void k_copy7(const float* __restrict__ src, float* __restrict__ dst, int n) {
  long long t = (long long)blockIdx.x * blockDim.x + threadIdx.x;
  int i = (int)(t >> 3), f = (int)(t & 7);
  if (i < n && f < 7) dst[(size_t)i * 32 + f] = src[(size_t)i * 7 + f];
}

__global__ void k_buildW32(const float* __restrict__ w, float* __restrict__ W32) {
  int t = blockIdx.x * blockDim.x + threadIdx.x;  // 4096
  int k = t >> 7, h = t & 127;
  W32[t] = (k < 28) ? w[(size_t)k * H + h] : 0.f;
}

__global__ void k_gemm128(const float* __restrict__ X, const float* __restrict__ W,
                          const float* __restrict__ b, float* out, int M, int K, int act) {
  long long t = (long long)blockIdx.x * blockDim.x + threadIdx.x;
  if (t >= (long long)M * H) return;
  int i = (int)(t >> 7), h = (int)(t & 127);
  float acc = b ? b[h] : 0.f;
  const float* x = X + (long long)i * K;
  for (int k = 0; k < K; k++) acc = fmaf(x[k], W[k * H + h], acc);
  if (act) acc = fmaxf(acc, 0.f);
  out[t] = acc;
}

// ================= tiled SGEMM, N=128, BM=64 =================
__global__ __launch_bounds__(256) void k_tgemm(const float* __restrict__ X,
                                               const float* __restrict__ W,
                                               const float* __restrict__ bias,
                                               const float* __restrict__ Cin,
                                               float* __restrict__ Cout,
                                               int M, int K, int flags) {
  __shared__ float Xs[16][68];
  __shared__ float Ws[16][132];
  int tid = threadIdx.x;
  int tx = tid & 15, ty = tid >> 4;
  int rowBase = blockIdx.x * 64;
  int lr = tid >> 2, lk = (tid & 3) * 4;
  int xrow = rowBase + lr;
  int p1 = tid + 256;
  float acc[4][8] = {};
  for (int k0 = 0; k0 < K; k0 += 16) {
    float4 xv = make_float4(0.f, 0.f, 0.f, 0.f);
    if (xrow < M) xv = *(const float4*)(X + (size_t)xrow * K + k0 + lk);
    float4 w0 = *(const float4*)(W + (size_t)(k0 + (tid >> 5)) * H + (tid & 31) * 4);
    float4 w1 = *(const float4*)(W + (size_t)(k0 + (p1 >> 5)) * H + (p1 & 31) * 4);
    __syncthreads();
    Xs[lk + 0][lr] = xv.x;
    Xs[lk + 1][lr] = xv.y;
    Xs[lk + 2][lr] = xv.z;
    Xs[lk + 3][lr] = xv.w;
    *(float4*)&Ws[tid >> 5][(tid & 31) * 4] = w0;
    *(float4*)&Ws[p1 >> 5][(p1 & 31) * 4] = w1;
    __syncthreads();
#pragma unroll
    for (int kk = 0; kk < 16; kk++) {
      float4 xf = *(const float4*)&Xs[kk][ty * 4];
      float4 wa = *(const float4*)&Ws[kk][tx * 8];
      float4 wb = *(const float4*)&Ws[kk][tx * 8 + 4];
      float xr[4] = {xf.x, xf.y, xf.z, xf.w};
      float wc[8] = {wa.x, wa.y, wa.z, wa.w, wb.x, wb.y, wb.z, wb.w};
#pragma unroll
      for (int j = 0; j < 4; j++)
#pragma unroll
        for (int i = 0; i < 8; i++) acc[j][i] = fmaf(xr[j], wc[i], acc[j][i]);
    }
  }
  float bcol[8] = {};
  if (bias) {
    float4 ba = *(const float4*)(bias + tx * 8);
    float4 bb = *(const float4*)(bias + tx * 8 + 4);
    bcol[0] = ba.x; bcol[1] = ba.y; bcol[2] = ba.z; bcol[3] = ba.w;
    bcol[4] = bb.x; bcol[5] = bb.y; bcol[6] = bb.z; bcol[7] = bb.w;
  }
#pragma unroll
  for (int j = 0; j < 4; j++) {
    int row = rowBase + ty * 4 + j;
    if (row >= M) break;
    float o[8];
#pragma unroll
    for (int i = 0; i < 8; i++) o[i] = acc[j][i] + bcol[i];
    if (flags & TG_ACC) {
      float4 pa = *(const float4*)(Cin + (size_t)row * H + tx * 8);
      float4 pb = *(const float4*)(Cin + (size_t)row * H + tx * 8 + 4);
      o[0] += pa.x; o[1] += pa.y; o[2] += pa.z; o[3] += pa.w;
      o[4] += pb.x; o[5] += pb.y; o[6] += pb.z; o[7] += pb.w;
    }
    if (flags & TG_RELU)
#pragma unroll
      for (int i = 0; i < 8; i++) o[i] = fmaxf(o[i], 0.f);
    *(float4*)(Cout + (size_t)row * H + tx * 8) = make_float4(o[0], o[1], o[2], o[3]);
    *(float4*)(Cout + (size_t)row * H + tx * 8 + 4) = make_float4(o[4], o[5], o[6], o[7]);
  }
}

static inline int tgb(int M) { return (M + 63) / 64; }

// ================= fused SAGE: out = relu(l2norm(Xm@lw + lb + Xd@rw)), out ldC =================
__global__ __launch_bounds__(256) void k_sage2(const float* __restrict__ Xm,
                                               const float* __restrict__ Xd,
                                               const float* __restrict__ lw,
                                               const float* __restrict__ rw,
                                               const float* __restrict__ lb,
                                               float* __restrict__ Cout, long ldC, int M) {
  __shared__ float Xms[16][68];
  __shared__ float Xds[16][68];
  __shared__ float Wls[16][132];
  __shared__ float Wrs[16][132];
  __shared__ float rsum[64];
  int tid = threadIdx.x;
  int tx = tid & 15, ty = tid >> 4;
  int rowBase = blockIdx.x * 64;
  int lr = tid >> 2, lk = (tid & 3) * 4;
  int xrow = rowBase + lr;
  int p1 = tid + 256;
  float acc[4][8] = {};
  for (int k0 = 0; k0 < H; k0 += 16) {
    float4 xm = make_float4(0.f, 0.f, 0.f, 0.f), xd = xm;
    if (xrow < M) {
      xm = *(const float4*)(Xm + (size_t)xrow * H + k0 + lk);
      xd = *(const float4*)(Xd + (size_t)xrow * H + k0 + lk);
    }
    float4 wl0 = *(const float4*)(lw + (size_t)(k0 + (tid >> 5)) * H + (tid & 31) * 4);
    float4 wl1 = *(const float4*)(lw + (size_t)(k0 + (p1 >> 5)) * H + (p1 & 31) * 4);
    float4 wr0 = *(const float4*)(rw + (size_t)(k0 + (tid >> 5)) * H + (tid & 31) * 4);
    float4 wr1 = *(const float4*)(rw + (size_t)(k0 + (p1 >> 5)) * H + (p1 & 31) * 4);
    __syncthreads();
    Xms[lk + 0][lr] = xm.x; Xms[lk + 1][lr] = xm.y;
    Xms[lk + 2][lr] = xm.z; Xms[lk + 3][lr] = xm.w;
    Xds[lk + 0][lr] = xd.x; Xds[lk + 1][lr] = xd.y;
    Xds[lk + 2][lr] = xd.z; Xds[lk + 3][lr] = xd.w;
    *(float4*)&Wls[tid >> 5][(tid & 31) * 4] = wl0;
    *(float4*)&Wls[p1 >> 5][(p1 & 31) * 4] = wl1;
    *(float4*)&Wrs[tid >> 5][(tid & 31) * 4] = wr0;
    *(float4*)&Wrs[p1 >> 5][(p1 & 31) * 4] = wr1;
    __syncthreads();
#pragma unroll
    for (int kk = 0; kk < 16; kk++) {
      float4 xf = *(const float4*)&Xms[kk][ty * 4];
      float4 yf = *(const float4*)&Xds[kk][ty * 4];
      float4 wa = *(const float4*)&Wls[kk][tx * 8];
      float4 wb = *(const float4*)&Wls[kk][tx * 8 + 4];
      float4 va = *(const float4*)&Wrs[kk][tx * 8];
      float4 vb = *(const float4*)&Wrs[kk][tx * 8 + 4];
      float xr[4] = {xf.x, xf.y, xf.z, xf.w};
      float yr[4] = {yf.x, yf.y, yf.z, yf.w};
      float wc[8] = {wa.x, wa.y, wa.z, wa.w, wb.x, wb.y, wb.z, wb.w};
      float vc[8] = {va.x, va.y, va.z, va.w, vb.x, vb.y, vb.z, vb.w};
#pragma unroll
      for (int j = 0; j < 4; j++)
#pragma unroll
        for (int i = 0; i < 8; i++)
          acc[j][i] = fmaf(yr[j], vc[i], fmaf(xr[j], wc[i], acc[j][i]));
    }
  }
  float bcol[8];
  {
    float4 ba = *(const float4*)(lb + tx * 8);
    float4 bb = *(const float4*)(lb + tx * 8 + 4);
    bcol[0] = ba.x; bcol[1] = ba.y; bcol[2] = ba.z; bcol[3] = ba.w;
    bcol[4] = bb.x; bcol[5] = bb.y; bcol[6] = bb.z; bcol[7] = bb.w;
  }
  float o[4][8];
  if (tid < 64) rsum[tid] = 0.f;
  __syncthreads();
#pragma unroll
  for (int j = 0; j < 4; j++) {
    int row = rowBase + ty * 4 + j;
    float s = 0.f;
#pragma unroll
    for (int i = 0; i < 8; i++) {
      o[j][i] = acc[j][i] + bcol[i];
      s = fmaf(o[j][i], o[j][i], s);
    }
    if (row < M) atomicAdd(&rsum[ty * 4 + j], s);
  }
  __syncthreads();
#pragma unroll
  for (int j = 0; j < 4; j++) {
    int row = rowBase + ty * 4 + j;
    if (row >= M) break;
    float f = 1.f / fmaxf(sqrtf(rsum[ty * 4 + j]), 1e-12f);
    float4 oa = make_float4(fmaxf(o[j][0] * f, 0.f), fmaxf(o[j][1] * f, 0.f),
                            fmaxf(o[j][2] * f, 0.f), fmaxf(o[j][3] * f, 0.f));
    float4 ob = make_float4(fmaxf(o[j][4] * f, 0.f), fmaxf(o[j][5] * f, 0.f),
                            fmaxf(o[j][6] * f, 0.f), fmaxf(o[j][7] * f, 0.f));
    *(float4*)(Cout + (size_t)row * ldC + tx * 8) = oa;
    *(float4*)(Cout + (size_t)row * ldC + tx * 8 + 4) = ob;
  }
}

// ================= fused head: z = relu(X@lw + lb) @ lwl + lbl =================
__global__ __launch_bounds__(256) void k_head(const float* __restrict__ X,
                                              const float* __restrict__ lw,
                                              const float* __restrict__ lb,
                                              const float* __restrict__ lwl,
                                              const float* __restrict__ lbl,
                                              float* __restrict__ z, int M) {
  __shared__ float Wl[128 * 32];
  __shared__ float Xs[8][128];
  int tid = threadIdx.x;
  for (int i = tid * 4; i < 4096; i += 1024) *(float4*)&Wl[i] = *(const float4*)&lw[i];
  int rowBase = blockIdx.x * 8;
  {
    int idx = tid * 4;
    int xr = idx >> 7, xc = idx & 127;
    int grow = rowBase + xr;
    float4 v = make_float4(0.f, 0.f, 0.f, 0.f);
    if (grow < M) v = *(const float4*)(X + (size_t)grow * H + xc);
    *(float4*)&Xs[xr][xc] = v;
  }
  __syncthreads();
  int r = tid >> 5, o = tid & 31;
  float acc = lb[o];
  for (int k = 0; k < 128; k++) acc = fmaf(Xs[r][k], Wl[k * 32 + o], acc);
  acc = fmaxf(acc, 0.f) * lwl[o];
  for (int s = 16; s > 0; s >>= 1) acc += __shfl_down(acc, s, 32);
  int grow = rowBase + r;
  if (o == 0 && grow < M) z[grow] = acc + lbl[0];
}

// ================= log_softmax over axis 0 =================
__global__ void k_logsoftmax(const float* __restrict__ z, float* __restrict__ out, int n) {
  __shared__ float red[256];
  int tid = threadIdx.x;
  float m = -1e30f;
  for (int i = tid; i < n; i += 256) m = fmaxf(m, z[i]);
  red[tid] = m;
  __syncthreads();
  for (int s = 128; s > 0; s >>= 1) {
    if (tid < s) red[tid] = fmaxf(red[tid], red[tid + s]);
    __syncthreads();
  }
  float mx = red[0];
  __syncthreads();
  float sum = 0.f;
  for (int i = tid; i < n; i += 256) sum += __expf(z[i] - mx);
  red[tid] = sum;
  __syncthreads();
  for (int s = 128; s > 0; s >>= 1) {
    if (tid < s) red[tid] += red[tid + s];
    __syncthreads();
  }
  float lse = mx + logf(red[0]);
  for (int i = tid; i < n; i += 256) out[i] = z[i] - lse;
}

extern "C" void kernel_launch(void* const* d_in, const int* in_sizes, int n_in,
                              void* d_out, int out_size, void* d_ws, size_t ws_size,
                              hipStream_t stream) {
  const float* game_x = (const float*)d_in[0];
  const float* state_x = (const float*)d_in[1];
  const float* pc_x = (const float*)d_in[2];
  const int* ei_vv = (const int*)d_in[3];
  const int* et_vv = (const int*)d_in[4];
  const int* ei_hist = (const int*)d_in[5];
  const float* ea_hist = (const float*)d_in[6];
  const int* ei_in = (const int*)d_in[7];
  const int* ei_ss = (const int*)d_in[8];
  const int* ei_pp = (const int*)d_in[9];
  const int* ei_ps = (const int*)d_in[10];
  const float* tag10_w = (const float*)d_in[12];
  const float* tag10_b = (const float*)d_in[13];
  const float* rgcn_w = (const float*)d_in[14];
  const float* rgcn_root = (const float*)d_in[15];
  const float* rgcn_b = (const float*)d_in[16];
  const float* gcn1_w = (const float*)d_in[17];
  const float* gcn1_b = (const float*)d_in[18];
  const float* gcn2_w = (const float*)d_in[19];
  const float* gcn2_b = (const float*)d_in[20];
  const float* rg_key_w = (const float*)d_in[21];
  const float* rg_key_b = (const float*)d_in[22];
  const float* rg_query_w = (const float*)d_in[23];
  const float* rg_query_b = (const float*)d_in[24];
  const float* rg_value_w = (const float*)d_in[25];
  const float* rg_value_b = (const float*)d_in[26];
  const float* rg_edge_w = (const float*)d_in[27];
  const float* rg_skip_w = (const float*)d_in[28];
  const float* rg_b = (const float*)d_in[29];
  const float* sage32_lw = (const float*)d_in[30];
  const float* sage32_lb = (const float*)d_in[31];
  const float* sage32_rw = (const float*)d_in[32];
  const float* sage4_lw = (const float*)d_in[33];
  const float* sage4_lb = (const float*)d_in[34];
  const float* sage4_rw = (const float*)d_in[35];
  const float* sage42_lw = (const float*)d_in[36];
  const float* sage42_lb = (const float*)d_in[37];
  const float* sage42_rw = (const float*)d_in[38];
  const float* pcs_lw = (const float*)d_in[39];
  const float* pcs_lb = (const float*)d_in[40];
  const float* pcs_rw = (const float*)d_in[41];
  const float* tag2_w = (const float*)d_in[42];
  const float* tag2_b = (const float*)d_in[43];
  const float* sage5_lw = (const float*)d_in[44];
  const float* sage5_lb = (const float*)d_in[45];
  const float* sage5_rw = (const float*)d_in[46];
  const float* lin_w = (const float*)d_in[47];
  const float* lin_b = (const float*)d_in[48];
  const float* linl_w = (const float*)d_in[49];
  const float* linl_b = (const float*)d_in[50];

  const int Evv = in_sizes[3] / 2, Eh = in_sizes[5] / 2, Ein = in_sizes[7] / 2,
            Ess = in_sizes[8] / 2, Epp = in_sizes[9] / 2, Eps = in_sizes[10] / 2;
  const int EE = Evv + Epp + Eh + Ein + Eps + Ess;
  const int NN = NG + NP + 4 * NS;

  // ---- workspace layout (floats). Peak ~148 MB. ----
  float* ws = (float*)d_ws;
  const size_t NGH = (size_t)NG * H, NPH = (size_t)NP * H, NSH = (size_t)NS * H;
  float* g_tag = ws;                // NGH; later q
  float* g = ws + NGH;              // NGH (long-lived)
  float* C0 = ws + 2 * NGH;
  // arena aliases (sequential lifetimes):
  float* P_tag10 = C0;              // NG*32          (phase 1)
  float* G3 = C0;                   // NG*384 = 19.2M (phase 2; overlaps S region, S not live yet)
  float* xW = C0;                   // NPH            (phase 3)
  float* p1b = C0 + NPH;            // NPH
  float* p2b = C0 + 2 * NPH;        // NPH (lives to phase 7 gather)
  float* v = C0;                    // NGH            (phase 4; xW/p1b dead)
  float* q = g_tag;                 // NGH (g_tag dead after rgcn root)
  float* P_tag2 = C0;               // NS*384 = 7.68M (phase 7-8; ends exactly at p2b)
  float* S_a = C0 + 3 * NPH;        // NSH  (live phase >= 4; G3 overlap is temporal only)
  float* S_b = S_a + NSH;
  float* m_buf = S_b + NSH;
  float* kk = m_buf + NSH;
  int* ip = (int*)(kk + NSH);
  int* rp_all = ip; ip += NN + 1;
  int* cur_all = ip; ip += NN;
  int* cnt_all = ip; ip += NN;
  int* eidx_all = ip; ip += EE;
  int* bsum = ip; ip += 512;
  float* fp = (float*)ip;
  float* dinv_all = fp; fp += NN;
  float* z = fp; fp += NS;
  float* W32 = fp; fp += 32 * H;

  // graph order: 0=vv, 1=pp, 2=hh, 3=in, 4=ps, 5=ss
  Seg6 sg;
  sg.col[0] = ei_vv + Evv;  sg.row[0] = ei_vv;
  sg.col[1] = ei_pp + Epp;  sg.row[1] = ei_pp;
  sg.col[2] = ei_hist + Eh; sg.row[2] = ei_hist;
  sg.col[3] = ei_in + Ein;  sg.row[3] = ei_in;
  sg.col[4] = ei_ps + Eps;  sg.row[4] = ei_ps;
  sg.col[5] = ei_ss + Ess;  sg.row[5] = ei_ss;
  sg.et0 = et_vv;
  int no[7] = {0, NG, NG + NP, NG + NP + NS, NG + NP + 2 * NS, NG + NP + 3 * NS, NN};
  int eo[7] = {0, Evv, Evv + Epp, Evv + Epp + Eh, Evv + Epp + Eh + Ein,
               Evv + Epp + Eh + Ein + Eps, EE};
  for (int i = 0; i < 7; i++) { sg.nodeoff[i] = no[i]; sg.edgeoff[i] = eo[i]; }
  int md[6] = {1, 0, 2, 0, 0, 0};
  float as[6] = {0.f, 1.f, 0.f, 0.f, 0.f, 0.f};
  int hd[6] = {1, 1, 0, 0, 0, 1};
  for (int i = 0; i < 6; i++) { sg.mode[i] = md[i]; sg.addself[i] = as[i]; sg.hasdinv[i] = hd[i]; }

  const int* rp_vv = rp_all + no[0];
  const int* rp_pp = rp_all + no[1];
  const int* rp_hh = rp_all + no[2];
  const int* rp_in = rp_all + no[3];
  const int* rp_ps = rp_all + no[4];
  const int* rp_ss = rp_all + no[5];
  const float* dinvG = dinv_all + no[0];
  const float* dinvP = dinv_all + no[1];
  const float* dinvS = dinv_all + no[5];
  const int* rh = ei_hist;

  // ---- batched CSR build (7 dispatches) ----
  hipMemsetAsync(cnt_all, 0, (size_t)NN * 4, stream);
  k_count_all<<<nblk(EE), 256, 0, stream>>>(sg, EE, cnt_all);
  k_dinv_all<<<nblk(NN), 256, 0, stream>>>(sg, NN, cnt_all, dinv_all);
  int nb = (NN + 511) / 512;
  k_scan1<<<nb, 256, 0, stream>>>(cnt_all, NN, rp_all, bsum);
  k_scan2<<<1, 64, 0, stream>>>(bsum, nb);
  k_scan3<<<nblk(NN + 1), 256, 0, stream>>>(rp_all, cur_all, bsum, NN, EE);
  k_fill_all<<<nblk(EE), 256, 0, stream>>>(sg, EE, cur_all, eidx_all);

  // ================= phase 1: TAGConv game (7-dim hops, K packed to 32) =================
  hipMemsetAsync(P_tag10, 0, (size_t)NG * 32 * 4, stream);
  k_copy7<<<nblk((long long)NG * 8), 256, 0, stream>>>(game_x, P_tag10, NG);
  k_gather_norm7<<<NG, 64, 0, stream>>>(game_x, 7, 0, eidx_all, rp_vv, dinvG, P_tag10, 32, 7);
  k_gather_norm7<<<NG, 64, 0, stream>>>(P_tag10, 32, 7, eidx_all, rp_vv, dinvG, P_tag10, 32, 14);
  k_gather_norm7<<<NG, 64, 0, stream>>>(P_tag10, 32, 14, eidx_all, rp_vv, dinvG, P_tag10, 32, 21);
  k_buildW32<<<16, 256, 0, stream>>>(tag10_w, W32);
  k_tgemm<<<tgb(NG), 256, 0, stream>>>(P_tag10, W32, tag10_b, nullptr, g_tag, NG, 32, TG_RELU);

  // ================= phase 2: RGCN (single-pass rel gather, K=384 GEMM, root) =================
  k_gather_rel3<<<NG, 128, 0, stream>>>(g_tag, eidx_all, rp_vv, G3);
  k_tgemm<<<tgb(NG), 256, 0, stream>>>(G3, rgcn_w, rgcn_b, nullptr, g, NG, 384, 0);
  k_tgemm<<<tgb(NG), 256, 0, stream>>>(g_tag, rgcn_root, nullptr, g, g, NG, H, TG_ACC | TG_RELU);

  // ================= phase 3: pc graph (2x GCN) =================
  k_gemm128<<<nblk((long long)NPH), 256, 0, stream>>>(pc_x, gcn1_w, nullptr, xW, NP, 5, 0);
  k_gather_norm<<<NP, 128, 0, stream>>>(xW, H, 0, eidx_all, rp_pp, dinvP, xW, gcn1_b, p1b, H, 0, 1);
  k_tgemm<<<tgb(NP), 256, 0, stream>>>(p1b, gcn2_w, nullptr, nullptr, xW, NP, H, 0);
  k_gather_norm<<<NP, 128, 0, stream>>>(xW, H, 0, eidx_all, rp_pp, dinvP, xW, gcn2_b, p2b, H, 0, 1);

  // ================= phase 4: ResGated (game -> state) =================
  k_gemm128<<<nblk((long long)NSH), 256, 0, stream>>>(state_x, rg_key_w, rg_key_b, kk, NS, 6, 0);
  k_tgemm<<<tgb(NG), 256, 0, stream>>>(g, rg_query_w, rg_query_b, nullptr, q, NG, H, 0);
  k_tgemm<<<tgb(NG), 256, 0, stream>>>(g, rg_value_w, rg_value_b, nullptr, v, NG, H, 0);
  k_resgated_gather<<<NS, 128, 0, stream>>>(kk, q, v, ea_hist, rg_edge_w, rh, eidx_all, rp_hh,
                                            state_x, rg_skip_w, rg_b, S_a);

  // ================= phase 5: sage32 (hist, xs=g) =================
  k_gather_mean<<<NS, 128, 0, stream>>>(g, eidx_all, rp_hh, rh, m_buf);
  k_sage2<<<tgb(NS), 256, 0, stream>>>(m_buf, S_a, sage32_lw, sage32_rw, sage32_lb, S_b, H, NS);

  // ================= phase 6: sage4 + sage42 (in, xs=g; shared mean) =================
  k_gather_mean<<<NS, 128, 0, stream>>>(g, eidx_all, rp_in, nullptr, m_buf);
  k_sage2<<<tgb(NS), 256, 0, stream>>>(m_buf, S_b, sage4_lw, sage4_rw, sage4_lb, S_a, H, NS);
  k_sage2<<<tgb(NS), 256, 0, stream>>>(m_buf, S_a, sage42_lw, sage42_rw, sage42_lb, S_b, H, NS);

  // ================= phase 7: pcs sage (pc->state) — writes tag2 operand col 0 =================
  k_gather_mean<<<NS, 128, 0, stream>>>(p2b, eidx_all, rp_ps, nullptr, m_buf);
  k_sage2<<<tgb(NS), 256, 0, stream>>>(m_buf, S_b, pcs_lw, pcs_rw, pcs_lb, P_tag2, 384, NS);

  // ================= phase 8: tag2 (2 hops into cols 128/256, K=384 GEMM) =================
  k_gather_norm<<<NS, 128, 0, stream>>>(P_tag2, 384, 0, eidx_all, rp_ss, dinvS, nullptr, nullptr,
                                        P_tag2, 384, 128, 0);
  k_gather_norm<<<NS, 128, 0, stream>>>(P_tag2, 384, 128, eidx_all, rp_ss, dinvS, nullptr, nullptr,
                                        P_tag2, 384, 256, 0);
  k_tgemm<<<tgb(NS), 256, 0, stream>>>(P_tag2, tag2_w, tag2_b, nullptr, S_b, NS, 384, TG_RELU);

  // ================= phase 9: sage5 (state graph, xs=xd=s) =================
  k_gather_mean<<<NS, 128, 0, stream>>>(S_b, eidx_all, rp_ss, nullptr, m_buf);
  k_sage2<<<tgb(NS), 256, 0, stream>>>(m_buf, S_b, sage5_lw, sage5_rw, sage5_lb, S_a, H, NS);

  // ================= head =================
  k_head<<<(NS + 7) / 8, 256, 0, stream>>>(S_a, lin_w, lin_b, linl_w, linl_b, z, NS);
  k_logsoftmax<<<1, 256, 0, stream>>>(z, (float*)d_out, NS);
}

// Round 5
// 1130.580 us; speedup vs baseline: 4.0724x; 1.1221x over previous
//
#include <hip/hip_runtime.h>
#include <cstdint>

#define H 128
static const int NG = 50000, NS = 20000, NP = 30000;

#define TG_RELU 2
#define TG_NORM 4

typedef __attribute__((ext_vector_type(8))) short bf16x8;
typedef __attribute__((ext_vector_type(4))) float f32x4;

static inline int nblk(long long n) { return (int)((n + 255) / 256); }

__device__ inline unsigned short f2b(float f) {
  unsigned int u = __float_as_uint(f);
  u += 0x7FFFu + ((u >> 16) & 1u);
  return (unsigned short)(u >> 16);
}

// ================= batched CSR build =================
struct Seg6 {
  const int* col[6];
  const int* row[6];
  const int* et0;
  int nodeoff[7];
  int edgeoff[7];
  int mode[6];         // 0=row, 1=row|(et<<16), 2=edge id (local)
  float addself[6];
  int hasdinv[6];
};

__global__ void k_count_all(Seg6 sg, int EE, int* __restrict__ cnt) {
  int e = blockIdx.x * blockDim.x + threadIdx.x;
  if (e >= EE) return;
  int gi = 0;
  while (e >= sg.edgeoff[gi + 1]) gi++;
  int le = e - sg.edgeoff[gi];
  atomicAdd(&cnt[sg.nodeoff[gi] + sg.col[gi][le]], 1);
}

__global__ void k_dinv_all(Seg6 sg, int NN, const int* __restrict__ cnt, float* __restrict__ dinv) {
  int i = blockIdx.x * blockDim.x + threadIdx.x;
  if (i >= NN) return;
  int gi = 0;
  while (i >= sg.nodeoff[gi + 1]) gi++;
  if (!sg.hasdinv[gi]) return;
  float d = (float)cnt[i] + sg.addself[gi];
  dinv[i] = (d > 0.f) ? rsqrtf(d) : 0.f;
}

__global__ void k_scan1(const int* __restrict__ cnt, int n, int* __restrict__ part,
                        int* __restrict__ bsum) {
  __shared__ int s[256];
  int b = blockIdx.x, t = threadIdx.x;
  int i0 = b * 512 + 2 * t;
  int a = (i0 < n) ? cnt[i0] : 0;
  int bb = (i0 + 1 < n) ? cnt[i0 + 1] : 0;
  s[t] = a + bb;
  __syncthreads();
  for (int off = 1; off < 256; off <<= 1) {
    int v = s[t];
    int u = (t >= off) ? s[t - off] : 0;
    __syncthreads();
    s[t] = v + u;
    __syncthreads();
  }
  int excl = (t > 0) ? s[t - 1] : 0;
  if (i0 < n) part[i0] = excl;
  if (i0 + 1 < n) part[i0 + 1] = excl + a;
  if (t == 255) bsum[b] = s[255];
}

__global__ void k_scan2(int* bsum, int nb) {
  if (threadIdx.x == 0) {
    int run = 0;
    for (int b = 0; b < nb; b++) { int t = bsum[b]; bsum[b] = run; run += t; }
  }
}

__global__ void k_scan3(int* rowptr, int* cursor, const int* __restrict__ bsum, int n, int E) {
  int i = blockIdx.x * blockDim.x + threadIdx.x;
  if (i < n) {
    int v = rowptr[i] + bsum[i >> 9];
    rowptr[i] = v;
    cursor[i] = v;
  }
  if (i == n) rowptr[n] = E;
}

__global__ void k_fill_all(Seg6 sg, int EE, int* cursor, int* __restrict__ eidx) {
  int e = blockIdx.x * blockDim.x + threadIdx.x;
  if (e >= EE) return;
  int gi = 0;
  while (e >= sg.edgeoff[gi + 1]) gi++;
  int le = e - sg.edgeoff[gi];
  int c = sg.col[gi][le];
  int pos = atomicAdd(&cursor[sg.nodeoff[gi] + c], 1);
  int m = sg.mode[gi];
  int pay;
  if (m == 2) pay = le;
  else {
    pay = sg.row[gi][le];
    if (m == 1) pay |= sg.et0[le] << 16;
  }
  eidx[pos] = pay;
}

// ================= gathers =================
__global__ void k_gather_mean(const float* __restrict__ src, const int* __restrict__ eidx,
                              const int* __restrict__ rowptr, const int* __restrict__ remap,
                              float* __restrict__ out) {
  int c = blockIdx.x, h = threadIdx.x;
  int beg = rowptr[c], end = rowptr[c + 1];
  __shared__ int si[128];
  float acc = 0.f;
  for (int j0 = beg; j0 < end; j0 += 128) {
    int nn = min(128, end - j0);
    __syncthreads();
    if (h < nn) {
      int e = eidx[j0 + h];
      si[h] = remap ? remap[e] : e;
    }
    __syncthreads();
    int t = 0;
    for (; t + 4 <= nn; t += 4) {
      float a0 = src[(size_t)si[t] * H + h];
      float a1 = src[(size_t)si[t + 1] * H + h];
      float a2 = src[(size_t)si[t + 2] * H + h];
      float a3 = src[(size_t)si[t + 3] * H + h];
      acc += (a0 + a1) + (a2 + a3);
    }
    for (; t < nn; t++) acc += src[(size_t)si[t] * H + h];
  }
  int cnt = end - beg;
  out[(size_t)c * H + h] = acc * (1.f / (float)(cnt > 0 ? cnt : 1));
}

// single-pass 3-relation mean; writes concatenated [rel0|rel1|rel2] row of width 384
__global__ void k_gather_rel3(const float* __restrict__ src, const int* __restrict__ eidx,
                              const int* __restrict__ rowptr, float* __restrict__ G3) {
  int c = blockIdx.x, h = threadIdx.x;
  int beg = rowptr[c], end = rowptr[c + 1];
  __shared__ int si[128];
  float a0 = 0.f, a1 = 0.f, a2 = 0.f;
  int c0 = 0, c1 = 0, c2 = 0;
  for (int j0 = beg; j0 < end; j0 += 128) {
    int nn = min(128, end - j0);
    __syncthreads();
    if (h < nn) si[h] = eidx[j0 + h];
    __syncthreads();
    for (int t = 0; t < nn; t++) {
      int pk = si[t];
      int rel = pk >> 16;
      float val = src[(size_t)(pk & 0xFFFF) * H + h];
      if (rel == 0) { a0 += val; c0++; }
      else if (rel == 1) { a1 += val; c1++; }
      else { a2 += val; c2++; }
    }
  }
  size_t base = (size_t)c * 384;
  G3[base + h] = a0 * (1.f / (float)(c0 > 0 ? c0 : 1));
  G3[base + 128 + h] = a1 * (1.f / (float)(c1 > 0 ? c1 : 1));
  G3[base + 256 + h] = a2 * (1.f / (float)(c2 > 0 ? c2 : 1));
}

// symmetric-normalized gather (+ optional self + bias + relu), strided src/dst
__global__ void k_gather_norm(const float* __restrict__ src, int ldS, int offS,
                              const int* __restrict__ eidx, const int* __restrict__ rowptr,
                              const float* __restrict__ dinv, const float* __restrict__ selfX,
                              const float* __restrict__ bias, float* __restrict__ out,
                              int ldD, int offD, int relu) {
  int c = blockIdx.x, h = threadIdx.x;
  int beg = rowptr[c], end = rowptr[c + 1];
  __shared__ int si[128];
  __shared__ float sw[128];
  float acc = 0.f;
  for (int j0 = beg; j0 < end; j0 += 128) {
    int nn = min(128, end - j0);
    __syncthreads();
    if (h < nn) {
      int r = eidx[j0 + h];
      si[h] = r;
      sw[h] = dinv[r];
    }
    __syncthreads();
    int t = 0;
    for (; t + 4 <= nn; t += 4) {
      float a0 = sw[t] * src[(size_t)si[t] * ldS + offS + h];
      float a1 = sw[t + 1] * src[(size_t)si[t + 1] * ldS + offS + h];
      float a2 = sw[t + 2] * src[(size_t)si[t + 2] * ldS + offS + h];
      float a3 = sw[t + 3] * src[(size_t)si[t + 3] * ldS + offS + h];
      acc += (a0 + a1) + (a2 + a3);
    }
    for (; t < nn; t++) acc += sw[t] * src[(size_t)si[t] * ldS + offS + h];
  }
  float dc = dinv[c];
  float o = acc * dc;
  if (selfX) o += dc * dc * selfX[(size_t)c * H + h];
  if (bias) o += bias[h];
  if (relu) o = fmaxf(o, 0.f);
  out[(size_t)c * ldD + offD + h] = o;
}

// 7-dim symmetric-normalized gather (payload masked for etype bits)
__global__ void k_gather_norm7(const float* __restrict__ src, int ldS, int offS,
                               const int* __restrict__ eidx, const int* __restrict__ rowptr,
                               const float* __restrict__ dinv, float* __restrict__ dst,
                               int ldD, int offD) {
  int c = blockIdx.x;
  int t = threadIdx.x;  // 64
  int f = t & 7, j = t >> 3;
  int beg = rowptr[c], end = rowptr[c + 1];
  __shared__ int si[64];
  __shared__ float sw[64];
  __shared__ float red[8][8];
  float acc = 0.f;
  for (int j0 = beg; j0 < end; j0 += 64) {
    int nn = min(64, end - j0);
    __syncthreads();
    if (t < nn) {
      int r = eidx[j0 + t] & 0xFFFF;
      si[t] = r;
      sw[t] = dinv[r];
    }
    __syncthreads();
    if (f < 7)
      for (int u = j; u < nn; u += 8) acc += sw[u] * src[(size_t)si[u] * ldS + offS + f];
  }
  red[j][f] = acc;
  __syncthreads();
  if (j == 0 && f < 7) {
    float s = 0.f;
    for (int u = 0; u < 8; u++) s += red[u][f];
    dst[(size_t)c * ldD + offD + f] = s * dinv[c];
  }
}

// ResGated gather + skip(K=6) + bias + relu
__global__ void k_resgated_gather(const float* __restrict__ kk, const float* __restrict__ q,
                                  const float* __restrict__ v, const float* __restrict__ ea,
                                  const float* __restrict__ We, const int* __restrict__ rh,
                                  const int* __restrict__ eidx, const int* __restrict__ rowptr,
                                  const float* __restrict__ sx, const float* __restrict__ Wsk,
                                  const float* __restrict__ rgb, float* __restrict__ out) {
  int c = blockIdx.x, h = threadIdx.x;
  int beg = rowptr[c], end = rowptr[c + 1];
  __shared__ int sr[64];
  __shared__ float se0[64], se1[64];
  float kload = kk[(size_t)c * H + h];
  float we0 = We[h], we1 = We[H + h];
  float acc = 0.f;
  for (int j0 = beg; j0 < end; j0 += 64) {
    int nn = min(64, end - j0);
    __syncthreads();
    if (h < nn) {
      int e = eidx[j0 + h];
      sr[h] = rh[e];
      se0[h] = ea[2 * e];
      se1[h] = ea[2 * e + 1];
    }
    __syncthreads();
    for (int t = 0; t < nn; t++) {
      int r = sr[t];
      float x = kload + q[(size_t)r * H + h] + se0[t] * we0 + se1[t] * we1;
      float eta = 1.f / (1.f + __expf(-x));
      acc += eta * v[(size_t)r * H + h];
    }
  }
  float skip = rgb[h];
#pragma unroll
  for (int f = 0; f < 6; f++) skip = fmaf(sx[c * 6 + f], Wsk[f * H + h], skip);
  out[(size_t)c * H + h] = fmaxf(acc + skip, 0.f);
}

// ================= small utilities =================
__global__ void k_copy7(const float* __restrict__ src, float* __restrict__ dst, int n) {
  long long t = (long long)blockIdx.x * blockDim.x + threadIdx.x;
  int i = (int)(t >> 3), f = (int)(t & 7);
  if (i < n && f < 7) dst[(size_t)i * 32 + f] = src[(size_t)i * 7 + f];
}

__global__ void k_buildW32(const float* __restrict__ w, float* __restrict__ W32) {
  int t = blockIdx.x * blockDim.x + threadIdx.x;  // 4096
  int k = t >> 7, h = t & 127;
  W32[t] = (k < 28) ? w[(size_t)k * H + h] : 0.f;
}

__global__ void k_gemm128(const float* __restrict__ X, const float* __restrict__ W,
                          const float* __restrict__ b, float* out, int M, int K, int act) {
  long long t = (long long)blockIdx.x * blockDim.x + threadIdx.x;
  if (t >= (long long)M * H) return;
  int i = (int)(t >> 7), h = (int)(t & 127);
  float acc = b ? b[h] : 0.f;
  const float* x = X + (long long)i * K;
  for (int k = 0; k < K; k++) acc = fmaf(x[k], W[k * H + h], acc);
  if (act) acc = fmaxf(acc, 0.f);
  out[t] = acc;
}

// ================= MFMA bf16 GEMM: C[M x 128] = [X1|X2] @ [W1;W2] =================
// BM=64, 256 threads (4 waves): wave w -> rows (w&1)*32, cols (w>>1)*64.
// K1,K2 multiples of 32. Epilogue: bias, relu, row-L2-norm(+relu).
// LDS rows padded to 40 ushorts (80 B): 16B-aligned b128 reads, <=2-way conflicts.
__global__ __launch_bounds__(256) void k_mgemm(const float* __restrict__ X1, int ldX1, int K1,
                                               const float* __restrict__ W1,
                                               const float* __restrict__ X2, int ldX2, int K2,
                                               const float* __restrict__ W2,
                                               const float* __restrict__ bias,
                                               float* __restrict__ C, long ldC,
                                               int M, int flags) {
  __shared__ unsigned short Als[64 * 40];
  __shared__ unsigned short Bls[128 * 40];
  __shared__ float rs[2][64];
  int tid = threadIdx.x;
  int lane = tid & 63, wv = tid >> 6;
  int m = lane & 15, q = lane >> 4;
  int rbase = (wv & 1) * 32;
  int cbase = (wv >> 1) * 64;
  int blockRow = blockIdx.x * 64;
  // staging coords
  int sr0 = tid >> 3;              // X: rows 0..31 (t<256 -> fid=t: r=t>>3)
  int sc0 = (tid & 7) * 4;         // X: k offset
  f32x4 acc[2][4];
#pragma unroll
  for (int a = 0; a < 2; a++)
#pragma unroll
    for (int b = 0; b < 4; b++) acc[a][b] = (f32x4){0.f, 0.f, 0.f, 0.f};

  int Ktot = K1 + K2;
  for (int k0 = 0; k0 < Ktot; k0 += 32) {
    const float* Xs_;
    const float* Ws_;
    int kr, ldx;
    if (k0 < K1) { Xs_ = X1; Ws_ = W1; kr = k0; ldx = ldX1; }
    else { Xs_ = X2; Ws_ = W2; kr = k0 - K1; ldx = ldX2; }
    __syncthreads();
    // stage X tile: 64 rows x 32 k. fid = tid and tid+256.
    {
      int r1 = sr0, r2 = sr0 + 32;
      int gr1 = blockRow + r1, gr2 = blockRow + r2;
      float4 xv1 = make_float4(0.f, 0.f, 0.f, 0.f), xv2 = xv1;
      if (gr1 < M) xv1 = *(const float4*)(Xs_ + (size_t)gr1 * ldx + kr + sc0);
      if (gr2 < M) xv2 = *(const float4*)(Xs_ + (size_t)gr2 * ldx + kr + sc0);
      ushort4 u1 = {f2b(xv1.x), f2b(xv1.y), f2b(xv1.z), f2b(xv1.w)};
      ushort4 u2 = {f2b(xv2.x), f2b(xv2.y), f2b(xv2.z), f2b(xv2.w)};
      *(ushort4*)&Als[r1 * 40 + sc0] = u1;
      *(ushort4*)&Als[r2 * 40 + sc0] = u2;
    }
    // stage W tile transposed: Bls[n][k], 32 k x 128 n floats
#pragma unroll
    for (int it = 0; it < 4; it++) {
      int fid = it * 256 + tid;
      int kk = fid >> 5, nc = (fid & 31) * 4;
      float4 wval = *(const float4*)(Ws_ + (size_t)(kr + kk) * H + nc);
      Bls[(nc + 0) * 40 + kk] = f2b(wval.x);
      Bls[(nc + 1) * 40 + kk] = f2b(wval.y);
      Bls[(nc + 2) * 40 + kk] = f2b(wval.z);
      Bls[(nc + 3) * 40 + kk] = f2b(wval.w);
    }
    __syncthreads();
    bf16x8 a0 = *(const bf16x8*)&Als[(rbase + m) * 40 + q * 8];
    bf16x8 a1 = *(const bf16x8*)&Als[(rbase + 16 + m) * 40 + q * 8];
    bf16x8 b0 = *(const bf16x8*)&Bls[(cbase + m) * 40 + q * 8];
    bf16x8 b1 = *(const bf16x8*)&Bls[(cbase + 16 + m) * 40 + q * 8];
    bf16x8 b2 = *(const bf16x8*)&Bls[(cbase + 32 + m) * 40 + q * 8];
    bf16x8 b3 = *(const bf16x8*)&Bls[(cbase + 48 + m) * 40 + q * 8];
    acc[0][0] = __builtin_amdgcn_mfma_f32_16x16x32_bf16(a0, b0, acc[0][0], 0, 0, 0);
    acc[0][1] = __builtin_amdgcn_mfma_f32_16x16x32_bf16(a0, b1, acc[0][1], 0, 0, 0);
    acc[0][2] = __builtin_amdgcn_mfma_f32_16x16x32_bf16(a0, b2, acc[0][2], 0, 0, 0);
    acc[0][3] = __builtin_amdgcn_mfma_f32_16x16x32_bf16(a0, b3, acc[0][3], 0, 0, 0);
    acc[1][0] = __builtin_amdgcn_mfma_f32_16x16x32_bf16(a1, b0, acc[1][0], 0, 0, 0);
    acc[1][1] = __builtin_amdgcn_mfma_f32_16x16x32_bf16(a1, b1, acc[1][1], 0, 0, 0);
    acc[1][2] = __builtin_amdgcn_mfma_f32_16x16x32_bf16(a1, b2, acc[1][2], 0, 0, 0);
    acc[1][3] = __builtin_amdgcn_mfma_f32_16x16x32_bf16(a1, b3, acc[1][3], 0, 0, 0);
  }
  // epilogue
  float ov[2][4][4];
  float bcol[4] = {0.f, 0.f, 0.f, 0.f};
  if (bias) {
#pragma unroll
    for (int j = 0; j < 4; j++) bcol[j] = bias[cbase + j * 16 + m];
  }
#pragma unroll
  for (int a = 0; a < 2; a++)
#pragma unroll
    for (int j = 0; j < 4; j++)
#pragma unroll
      for (int i = 0; i < 4; i++) ov[a][j][i] = acc[a][j][i] + bcol[j];

  if (flags & TG_NORM) {
#pragma unroll
    for (int a = 0; a < 2; a++)
#pragma unroll
      for (int i = 0; i < 4; i++) {
        float p = 0.f;
#pragma unroll
        for (int j = 0; j < 4; j++) p = fmaf(ov[a][j][i], ov[a][j][i], p);
        p += __shfl_xor(p, 1);
        p += __shfl_xor(p, 2);
        p += __shfl_xor(p, 4);
        p += __shfl_xor(p, 8);
        if (m == 0) rs[wv >> 1][rbase + a * 16 + q * 4 + i] = p;
      }
    __syncthreads();
#pragma unroll
    for (int a = 0; a < 2; a++)
#pragma unroll
      for (int i = 0; i < 4; i++) {
        int ridx = rbase + a * 16 + q * 4 + i;
        float s = rs[0][ridx] + rs[1][ridx];
        float f = 1.f / fmaxf(sqrtf(s), 1e-12f);
#pragma unroll
        for (int j = 0; j < 4; j++) ov[a][j][i] = fmaxf(ov[a][j][i] * f, 0.f);
      }
  } else if (flags & TG_RELU) {
#pragma unroll
    for (int a = 0; a < 2; a++)
#pragma unroll
      for (int j = 0; j < 4; j++)
#pragma unroll
        for (int i = 0; i < 4; i++) ov[a][j][i] = fmaxf(ov[a][j][i], 0.f);
  }
#pragma unroll
  for (int a = 0; a < 2; a++)
#pragma unroll
    for (int i = 0; i < 4; i++) {
      int row = blockRow + rbase + a * 16 + q * 4 + i;
      if (row < M) {
#pragma unroll
        for (int j = 0; j < 4; j++) C[(size_t)row * ldC + cbase + j * 16 + m] = ov[a][j][i];
      }
    }
}

static inline int mgb(int M) { return (M + 63) / 64; }

// ================= fused head: z = relu(X@lw + lb) @ lwl + lbl =================
__global__ __launch_bounds__(256) void k_head(const float* __restrict__ X,
                                              const float* __restrict__ lw,
                                              const float* __restrict__ lb,
                                              const float* __restrict__ lwl,
                                              const float* __restrict__ lbl,
                                              float* __restrict__ z, int M) {
  __shared__ float Wl[128 * 32];
  __shared__ float Xs[8][128];
  int tid = threadIdx.x;
  for (int i = tid * 4; i < 4096; i += 1024) *(float4*)&Wl[i] = *(const float4*)&lw[i];
  int rowBase = blockIdx.x * 8;
  {
    int idx = tid * 4;
    int xr = idx >> 7, xc = idx & 127;
    int grow = rowBase + xr;
    float4 v = make_float4(0.f, 0.f, 0.f, 0.f);
    if (grow < M) v = *(const float4*)(X + (size_t)grow * H + xc);
    *(float4*)&Xs[xr][xc] = v;
  }
  __syncthreads();
  int r = tid >> 5, o = tid & 31;
  float acc = lb[o];
  for (int k = 0; k < 128; k++) acc = fmaf(Xs[r][k], Wl[k * 32 + o], acc);
  acc = fmaxf(acc, 0.f) * lwl[o];
  for (int s = 16; s > 0; s >>= 1) acc += __shfl_down(acc, s, 32);
  int grow = rowBase + r;
  if (o == 0 && grow < M) z[grow] = acc + lbl[0];
}

// ================= log_softmax over axis 0 =================
__global__ void k_logsoftmax(const float* __restrict__ z, float* __restrict__ out, int n) {
  __shared__ float red[256];
  int tid = threadIdx.x;
  float m = -1e30f;
  for (int i = tid; i < n; i += 256) m = fmaxf(m, z[i]);
  red[tid] = m;
  __syncthreads();
  for (int s = 128; s > 0; s >>= 1) {
    if (tid < s) red[tid] = fmaxf(red[tid], red[tid + s]);
    __syncthreads();
  }
  float mx = red[0];
  __syncthreads();
  float sum = 0.f;
  for (int i = tid; i < n; i += 256) sum += __expf(z[i] - mx);
  red[tid] = sum;
  __syncthreads();
  for (int s = 128; s > 0; s >>= 1) {
    if (tid < s) red[tid] += red[tid + s];
    __syncthreads();
  }
  float lse = mx + logf(red[0]);
  for (int i = tid; i < n; i += 256) out[i] = z[i] - lse;
}

extern "C" void kernel_launch(void* const* d_in, const int* in_sizes, int n_in,
                              void* d_out, int out_size, void* d_ws, size_t ws_size,
                              hipStream_t stream) {
  const float* game_x = (const float*)d_in[0];
  const float* state_x = (const float*)d_in[1];
  const float* pc_x = (const float*)d_in[2];
  const int* ei_vv = (const int*)d_in[3];
  const int* et_vv = (const int*)d_in[4];
  const int* ei_hist = (const int*)d_in[5];
  const float* ea_hist = (const float*)d_in[6];
  const int* ei_in = (const int*)d_in[7];
  const int* ei_ss = (const int*)d_in[8];
  const int* ei_pp = (const int*)d_in[9];
  const int* ei_ps = (const int*)d_in[10];
  const float* tag10_w = (const float*)d_in[12];
  const float* tag10_b = (const float*)d_in[13];
  const float* rgcn_w = (const float*)d_in[14];
  const float* rgcn_root = (const float*)d_in[15];
  const float* rgcn_b = (const float*)d_in[16];
  const float* gcn1_w = (const float*)d_in[17];
  const float* gcn1_b = (const float*)d_in[18];
  const float* gcn2_w = (const float*)d_in[19];
  const float* gcn2_b = (const float*)d_in[20];
  const float* rg_key_w = (const float*)d_in[21];
  const float* rg_key_b = (const float*)d_in[22];
  const float* rg_query_w = (const float*)d_in[23];
  const float* rg_query_b = (const float*)d_in[24];
  const float* rg_value_w = (const float*)d_in[25];
  const float* rg_value_b = (const float*)d_in[26];
  const float* rg_edge_w = (const float*)d_in[27];
  const float* rg_skip_w = (const float*)d_in[28];
  const float* rg_b = (const float*)d_in[29];
  const float* sage32_lw = (const float*)d_in[30];
  const float* sage32_lb = (const float*)d_in[31];
  const float* sage32_rw = (const float*)d_in[32];
  const float* sage4_lw = (const float*)d_in[33];
  const float* sage4_lb = (const float*)d_in[34];
  const float* sage4_rw = (const float*)d_in[35];
  const float* sage42_lw = (const float*)d_in[36];
  const float* sage42_lb = (const float*)d_in[37];
  const float* sage42_rw = (const float*)d_in[38];
  const float* pcs_lw = (const float*)d_in[39];
  const float* pcs_lb = (const float*)d_in[40];
  const float* pcs_rw = (const float*)d_in[41];
  const float* tag2_w = (const float*)d_in[42];
  const float* tag2_b = (const float*)d_in[43];
  const float* sage5_lw = (const float*)d_in[44];
  const float* sage5_lb = (const float*)d_in[45];
  const float* sage5_rw = (const float*)d_in[46];
  const float* lin_w = (const float*)d_in[47];
  const float* lin_b = (const float*)d_in[48];
  const float* linl_w = (const float*)d_in[49];
  const float* linl_b = (const float*)d_in[50];

  const int Evv = in_sizes[3] / 2, Eh = in_sizes[5] / 2, Ein = in_sizes[7] / 2,
            Ess = in_sizes[8] / 2, Epp = in_sizes[9] / 2, Eps = in_sizes[10] / 2;
  const int EE = Evv + Epp + Eh + Ein + Eps + Ess;
  const int NN = NG + NP + 4 * NS;

  // ---- workspace layout (floats). Peak ~148 MB. ----
  float* ws = (float*)d_ws;
  const size_t NGH = (size_t)NG * H, NPH = (size_t)NP * H, NSH = (size_t)NS * H;
  float* g_tag = ws;                // NGH; later q
  float* g = ws + NGH;              // NGH (long-lived)
  float* C0 = ws + 2 * NGH;
  // arena aliases (sequential lifetimes):
  float* P_tag10 = C0;              // NG*32          (phase 1)
  float* G3 = C0;                   // NG*384         (phase 2)
  float* xW = C0;                   // NPH            (phase 3)
  float* p1b = C0 + NPH;            // NPH
  float* p2b = C0 + 2 * NPH;        // NPH (lives to phase 7 gather)
  float* v = C0;                    // NGH            (phase 4)
  float* q = g_tag;                 // NGH
  float* P_tag2 = C0;               // NS*384 (phase 7-8; ends exactly at p2b)
  float* S_a = C0 + 3 * NPH;        // NSH
  float* S_b = S_a + NSH;
  float* m_buf = S_b + NSH;
  float* kk = m_buf + NSH;
  int* ip = (int*)(kk + NSH);
  int* rp_all = ip; ip += NN + 1;
  int* cur_all = ip; ip += NN;
  int* cnt_all = ip; ip += NN;
  int* eidx_all = ip; ip += EE;
  int* bsum = ip; ip += 512;
  float* fp = (float*)ip;
  float* dinv_all = fp; fp += NN;
  float* z = fp; fp += NS;
  float* W32 = fp; fp += 32 * H;

  // graph order: 0=vv, 1=pp, 2=hh, 3=in, 4=ps, 5=ss
  Seg6 sg;
  sg.col[0] = ei_vv + Evv;  sg.row[0] = ei_vv;
  sg.col[1] = ei_pp + Epp;  sg.row[1] = ei_pp;
  sg.col[2] = ei_hist + Eh; sg.row[2] = ei_hist;
  sg.col[3] = ei_in + Ein;  sg.row[3] = ei_in;
  sg.col[4] = ei_ps + Eps;  sg.row[4] = ei_ps;
  sg.col[5] = ei_ss + Ess;  sg.row[5] = ei_ss;
  sg.et0 = et_vv;
  int no[7] = {0, NG, NG + NP, NG + NP + NS, NG + NP + 2 * NS, NG + NP + 3 * NS, NN};
  int eo[7] = {0, Evv, Evv + Epp, Evv + Epp + Eh, Evv + Epp + Eh + Ein,
               Evv + Epp + Eh + Ein + Eps, EE};
  for (int i = 0; i < 7; i++) { sg.nodeoff[i] = no[i]; sg.edgeoff[i] = eo[i]; }
  int md[6] = {1, 0, 2, 0, 0, 0};
  float as[6] = {0.f, 1.f, 0.f, 0.f, 0.f, 0.f};
  int hd[6] = {1, 1, 0, 0, 0, 1};
  for (int i = 0; i < 6; i++) { sg.mode[i] = md[i]; sg.addself[i] = as[i]; sg.hasdinv[i] = hd[i]; }

  const int* rp_vv = rp_all + no[0];
  const int* rp_pp = rp_all + no[1];
  const int* rp_hh = rp_all + no[2];
  const int* rp_in = rp_all + no[3];
  const int* rp_ps = rp_all + no[4];
  const int* rp_ss = rp_all + no[5];
  const float* dinvG = dinv_all + no[0];
  const float* dinvP = dinv_all + no[1];
  const float* dinvS = dinv_all + no[5];
  const int* rh = ei_hist;

  // ---- batched CSR build (7 dispatches) ----
  hipMemsetAsync(cnt_all, 0, (size_t)NN * 4, stream);
  k_count_all<<<nblk(EE), 256, 0, stream>>>(sg, EE, cnt_all);
  k_dinv_all<<<nblk(NN), 256, 0, stream>>>(sg, NN, cnt_all, dinv_all);
  int nb = (NN + 511) / 512;
  k_scan1<<<nb, 256, 0, stream>>>(cnt_all, NN, rp_all, bsum);
  k_scan2<<<1, 64, 0, stream>>>(bsum, nb);
  k_scan3<<<nblk(NN + 1), 256, 0, stream>>>(rp_all, cur_all, bsum, NN, EE);
  k_fill_all<<<nblk(EE), 256, 0, stream>>>(sg, EE, cur_all, eidx_all);

  // ================= phase 1: TAGConv game (7-dim hops, K packed to 32) =================
  hipMemsetAsync(P_tag10, 0, (size_t)NG * 32 * 4, stream);
  k_copy7<<<nblk((long long)NG * 8), 256, 0, stream>>>(game_x, P_tag10, NG);
  k_gather_norm7<<<NG, 64, 0, stream>>>(game_x, 7, 0, eidx_all, rp_vv, dinvG, P_tag10, 32, 7);
  k_gather_norm7<<<NG, 64, 0, stream>>>(P_tag10, 32, 7, eidx_all, rp_vv, dinvG, P_tag10, 32, 14);
  k_gather_norm7<<<NG, 64, 0, stream>>>(P_tag10, 32, 14, eidx_all, rp_vv, dinvG, P_tag10, 32, 21);
  k_buildW32<<<16, 256, 0, stream>>>(tag10_w, W32);
  k_mgemm<<<mgb(NG), 256, 0, stream>>>(P_tag10, 32, 32, W32, nullptr, 0, 0, nullptr,
                                       tag10_b, g_tag, H, NG, TG_RELU);

  // ================= phase 2: RGCN — one dual-source GEMM (K=384 + root K=128) ========
  k_gather_rel3<<<NG, 128, 0, stream>>>(g_tag, eidx_all, rp_vv, G3);
  k_mgemm<<<mgb(NG), 256, 0, stream>>>(G3, 384, 384, rgcn_w, g_tag, H, H, rgcn_root,
                                       rgcn_b, g, H, NG, TG_RELU);

  // ================= phase 3: pc graph (2x GCN) =================
  k_gemm128<<<nblk((long long)NPH), 256, 0, stream>>>(pc_x, gcn1_w, nullptr, xW, NP, 5, 0);
  k_gather_norm<<<NP, 128, 0, stream>>>(xW, H, 0, eidx_all, rp_pp, dinvP, xW, gcn1_b, p1b, H, 0, 1);
  k_mgemm<<<mgb(NP), 256, 0, stream>>>(p1b, H, H, gcn2_w, nullptr, 0, 0, nullptr,
                                       nullptr, xW, H, NP, 0);
  k_gather_norm<<<NP, 128, 0, stream>>>(xW, H, 0, eidx_all, rp_pp, dinvP, xW, gcn2_b, p2b, H, 0, 1);

  // ================= phase 4: ResGated (game -> state) =================
  k_gemm128<<<nblk((long long)NSH), 256, 0, stream>>>(state_x, rg_key_w, rg_key_b, kk, NS, 6, 0);
  k_mgemm<<<mgb(NG), 256, 0, stream>>>(g, H, H, rg_query_w, nullptr, 0, 0, nullptr,
                                       rg_query_b, q, H, NG, 0);
  k_mgemm<<<mgb(NG), 256, 0, stream>>>(g, H, H, rg_value_w, nullptr, 0, 0, nullptr,
                                       rg_value_b, v, H, NG, 0);
  k_resgated_gather<<<NS, 128, 0, stream>>>(kk, q, v, ea_hist, rg_edge_w, rh, eidx_all, rp_hh,
                                            state_x, rg_skip_w, rg_b, S_a);

  // ================= phase 5: sage32 (hist, xs=g) =================
  k_gather_mean<<<NS, 128, 0, stream>>>(g, eidx_all, rp_hh, rh, m_buf);
  k_mgemm<<<mgb(NS), 256, 0, stream>>>(m_buf, H, H, sage32_lw, S_a, H, H, sage32_rw,
                                       sage32_lb, S_b, H, NS, TG_NORM);

  // ================= phase 6: sage4 + sage42 (in, xs=g; shared mean) =================
  k_gather_mean<<<NS, 128, 0, stream>>>(g, eidx_all, rp_in, nullptr, m_buf);
  k_mgemm<<<mgb(NS), 256, 0, stream>>>(m_buf, H, H, sage4_lw, S_b, H, H, sage4_rw,
                                       sage4_lb, S_a, H, NS, TG_NORM);
  k_mgemm<<<mgb(NS), 256, 0, stream>>>(m_buf, H, H, sage42_lw, S_a, H, H, sage42_rw,
                                       sage42_lb, S_b, H, NS, TG_NORM);

  // ================= phase 7: pcs sage (pc->state) — writes tag2 operand col 0 ========
  k_gather_mean<<<NS, 128, 0, stream>>>(p2b, eidx_all, rp_ps, nullptr, m_buf);
  k_mgemm<<<mgb(NS), 256, 0, stream>>>(m_buf, H, H, pcs_lw, S_b, H, H, pcs_rw,
                                       pcs_lb, P_tag2, 384, NS, TG_NORM);

  // ================= phase 8: tag2 (2 hops into cols 128/256, K=384 GEMM) =============
  k_gather_norm<<<NS, 128, 0, stream>>>(P_tag2, 384, 0, eidx_all, rp_ss, dinvS, nullptr, nullptr,
                                        P_tag2, 384, 128, 0);
  k_gather_norm<<<NS, 128, 0, stream>>>(P_tag2, 384, 128, eidx_all, rp_ss, dinvS, nullptr, nullptr,
                                        P_tag2, 384, 256, 0);
  k_mgemm<<<mgb(NS), 256, 0, stream>>>(P_tag2, 384, 384, tag2_w, nullptr, 0, 0, nullptr,
                                       tag2_b, S_b, H, NS, TG_RELU);

  // ================= phase 9: sage5 (state graph, xs=xd=s) =================
  k_gather_mean<<<NS, 128, 0, stream>>>(S_b, eidx_all, rp_ss, nullptr, m_buf);
  k_mgemm<<<mgb(NS), 256, 0, stream>>>(m_buf, H, H, sage5_lw, S_b, H, H, sage5_rw,
                                       sage5_lb, S_a, H, NS, TG_NORM);

  // ================= head =================
  k_head<<<(NS + 7) / 8, 256, 0, stream>>>(S_a, lin_w, lin_b, linl_w, linl_b, z, NS);
  k_logsoftmax<<<1, 256, 0, stream>>>(z, (float*)d_out, NS);
}

// Round 6
// 919.076 us; speedup vs baseline: 5.0095x; 1.2301x over previous
//
#include <hip/hip_runtime.h>
#include <cstdint>

#define H 128
static const int NG = 50000, NS = 20000, NP = 30000;

#define TG_RELU 2
#define TG_NORM 4
#define TG_OUTBF16 8

typedef __attribute__((ext_vector_type(8))) short bf16x8;
typedef __attribute__((ext_vector_type(4))) float f32x4;

static inline int nblk(long long n) { return (int)((n + 255) / 256); }

__device__ inline unsigned short f2b(float f) {
  unsigned int u = __float_as_uint(f);
  u += 0x7FFFu + ((u >> 16) & 1u);
  return (unsigned short)(u >> 16);
}
__device__ inline float b2f(unsigned short u) {
  return __uint_as_float(((unsigned int)u) << 16);
}

// ================= batched CSR build =================
struct Seg6 {
  const int* col[6];
  const int* row[6];
  const int* et0;
  int nodeoff[7];
  int edgeoff[7];
  int mode[6];         // 0=row, 1=row|(et<<16), 2=edge id (local)
  float addself[6];
  int hasdinv[6];
};

__global__ void k_count_all(Seg6 sg, int EE, int* __restrict__ cnt) {
  int e = blockIdx.x * blockDim.x + threadIdx.x;
  if (e >= EE) return;
  int gi = 0;
  while (e >= sg.edgeoff[gi + 1]) gi++;
  int le = e - sg.edgeoff[gi];
  atomicAdd(&cnt[sg.nodeoff[gi] + sg.col[gi][le]], 1);
}

__global__ void k_dinv_all(Seg6 sg, int NN, const int* __restrict__ cnt, float* __restrict__ dinv) {
  int i = blockIdx.x * blockDim.x + threadIdx.x;
  if (i >= NN) return;
  int gi = 0;
  while (i >= sg.nodeoff[gi + 1]) gi++;
  if (!sg.hasdinv[gi]) return;
  float d = (float)cnt[i] + sg.addself[gi];
  dinv[i] = (d > 0.f) ? rsqrtf(d) : 0.f;
}

__global__ void k_scan1(const int* __restrict__ cnt, int n, int* __restrict__ part,
                        int* __restrict__ bsum) {
  __shared__ int s[256];
  int b = blockIdx.x, t = threadIdx.x;
  int i0 = b * 512 + 2 * t;
  int a = (i0 < n) ? cnt[i0] : 0;
  int bb = (i0 + 1 < n) ? cnt[i0 + 1] : 0;
  s[t] = a + bb;
  __syncthreads();
  for (int off = 1; off < 256; off <<= 1) {
    int v = s[t];
    int u = (t >= off) ? s[t - off] : 0;
    __syncthreads();
    s[t] = v + u;
    __syncthreads();
  }
  int excl = (t > 0) ? s[t - 1] : 0;
  if (i0 < n) part[i0] = excl;
  if (i0 + 1 < n) part[i0 + 1] = excl + a;
  if (t == 255) bsum[b] = s[255];
}

__global__ void k_scan2(int* bsum, int nb) {
  if (threadIdx.x == 0) {
    int run = 0;
    for (int b = 0; b < nb; b++) { int t = bsum[b]; bsum[b] = run; run += t; }
  }
}

__global__ void k_scan3(int* rowptr, int* cursor, const int* __restrict__ bsum, int n, int E) {
  int i = blockIdx.x * blockDim.x + threadIdx.x;
  if (i < n) {
    int v = rowptr[i] + bsum[i >> 9];
    rowptr[i] = v;
    cursor[i] = v;
  }
  if (i == n) rowptr[n] = E;
}

// bucketed fill: only edges whose dest segment-start falls in this pass's 2MB
// position window write -> scattered stores stay L2-resident, killing the 14x
// write amplification of the single-pass version.
__global__ void k_fill_pass(Seg6 sg, int EE, const int* __restrict__ rowptr,
                            int* cursor, int* __restrict__ eidx, int pass, int shift) {
  int e = blockIdx.x * blockDim.x + threadIdx.x;
  if (e >= EE) return;
  int gi = 0;
  while (e >= sg.edgeoff[gi + 1]) gi++;
  int le = e - sg.edgeoff[gi];
  int gn = sg.nodeoff[gi] + sg.col[gi][le];
  if ((rowptr[gn] >> shift) != pass) return;
  int pos = atomicAdd(&cursor[gn], 1);
  int m = sg.mode[gi];
  int pay;
  if (m == 2) pay = le;
  else {
    pay = sg.row[gi][le];
    if (m == 1) pay |= sg.et0[le] << 16;
  }
  eidx[pos] = pay;
}

// ================= weight pre-pack: fp32 [K x 128] -> bf16 transposed [128 x Kdst] =====
struct PackD { const float* src; int Ksrc; int Kdst; };
struct Pack17 { PackD d[17]; int koff[18]; };

__global__ void k_pack(Pack17 p, unsigned short* __restrict__ Wt, int totalRows) {
  int t = blockIdx.x * blockDim.x + threadIdx.x;
  if (t >= totalRows * 128) return;
  int gk = t >> 7, n = t & 127;
  int w = 0;
  while (gk >= p.koff[w + 1]) w++;
  int k = gk - p.koff[w];
  float v = (k < p.d[w].Ksrc) ? p.d[w].src[(size_t)k * 128 + n] : 0.f;
  Wt[(size_t)p.koff[w] * 128 + (size_t)n * p.d[w].Kdst + k] = f2b(v);
}

// ================= gathers (bf16 src/dst, fp32 accumulate) =================
__global__ void k_gather_mean(const unsigned short* __restrict__ src, const int* __restrict__ eidx,
                              const int* __restrict__ rowptr, const int* __restrict__ remap,
                              unsigned short* __restrict__ out) {
  int c = blockIdx.x, h = threadIdx.x;
  int beg = rowptr[c], end = rowptr[c + 1];
  __shared__ int si[128];
  float acc = 0.f;
  for (int j0 = beg; j0 < end; j0 += 128) {
    int nn = min(128, end - j0);
    __syncthreads();
    if (h < nn) {
      int e = eidx[j0 + h];
      si[h] = remap ? remap[e] : e;
    }
    __syncthreads();
    int t = 0;
    for (; t + 4 <= nn; t += 4) {
      float a0 = b2f(src[(size_t)si[t] * H + h]);
      float a1 = b2f(src[(size_t)si[t + 1] * H + h]);
      float a2 = b2f(src[(size_t)si[t + 2] * H + h]);
      float a3 = b2f(src[(size_t)si[t + 3] * H + h]);
      acc += (a0 + a1) + (a2 + a3);
    }
    for (; t < nn; t++) acc += b2f(src[(size_t)si[t] * H + h]);
  }
  int cnt = end - beg;
  out[(size_t)c * H + h] = f2b(acc * (1.f / (float)(cnt > 0 ? cnt : 1)));
}

// single-pass 3-relation mean; writes concatenated [rel0|rel1|rel2] row of width 384
__global__ void k_gather_rel3(const unsigned short* __restrict__ src, const int* __restrict__ eidx,
                              const int* __restrict__ rowptr, unsigned short* __restrict__ G3) {
  int c = blockIdx.x, h = threadIdx.x;
  int beg = rowptr[c], end = rowptr[c + 1];
  __shared__ int si[128];
  float a0 = 0.f, a1 = 0.f, a2 = 0.f;
  int c0 = 0, c1 = 0, c2 = 0;
  for (int j0 = beg; j0 < end; j0 += 128) {
    int nn = min(128, end - j0);
    __syncthreads();
    if (h < nn) si[h] = eidx[j0 + h];
    __syncthreads();
    for (int t = 0; t < nn; t++) {
      int pk = si[t];
      int rel = pk >> 16;
      float val = b2f(src[(size_t)(pk & 0xFFFF) * H + h]);
      if (rel == 0) { a0 += val; c0++; }
      else if (rel == 1) { a1 += val; c1++; }
      else { a2 += val; c2++; }
    }
  }
  size_t base = (size_t)c * 384;
  G3[base + h] = f2b(a0 * (1.f / (float)(c0 > 0 ? c0 : 1)));
  G3[base + 128 + h] = f2b(a1 * (1.f / (float)(c1 > 0 ? c1 : 1)));
  G3[base + 256 + h] = f2b(a2 * (1.f / (float)(c2 > 0 ? c2 : 1)));
}

// symmetric-normalized gather (+ optional self + bias + relu), strided bf16 src/dst
__global__ void k_gather_norm(const unsigned short* __restrict__ src, int ldS, int offS,
                              const int* __restrict__ eidx, const int* __restrict__ rowptr,
                              const float* __restrict__ dinv, const unsigned short* __restrict__ selfX,
                              const float* __restrict__ bias, unsigned short* __restrict__ out,
                              int ldD, int offD, int relu) {
  int c = blockIdx.x, h = threadIdx.x;
  int beg = rowptr[c], end = rowptr[c + 1];
  __shared__ int si[128];
  __shared__ float sw[128];
  float acc = 0.f;
  for (int j0 = beg; j0 < end; j0 += 128) {
    int nn = min(128, end - j0);
    __syncthreads();
    if (h < nn) {
      int r = eidx[j0 + h];
      si[h] = r;
      sw[h] = dinv[r];
    }
    __syncthreads();
    int t = 0;
    for (; t + 4 <= nn; t += 4) {
      float a0 = sw[t] * b2f(src[(size_t)si[t] * ldS + offS + h]);
      float a1 = sw[t + 1] * b2f(src[(size_t)si[t + 1] * ldS + offS + h]);
      float a2 = sw[t + 2] * b2f(src[(size_t)si[t + 2] * ldS + offS + h]);
      float a3 = sw[t + 3] * b2f(src[(size_t)si[t + 3] * ldS + offS + h]);
      acc += (a0 + a1) + (a2 + a3);
    }
    for (; t < nn; t++) acc += sw[t] * b2f(src[(size_t)si[t] * ldS + offS + h]);
  }
  float dc = dinv[c];
  float o = acc * dc;
  if (selfX) o += dc * dc * b2f(selfX[(size_t)c * H + h]);
  if (bias) o += bias[h];
  if (relu) o = fmaxf(o, 0.f);
  out[(size_t)c * ldD + offD + h] = f2b(o);
}

// 7-dim symmetric-normalized gather over bf16 (payload masked for etype bits)
__global__ void k_gather_norm7(const unsigned short* __restrict__ src, int ldS, int offS,
                               const int* __restrict__ eidx, const int* __restrict__ rowptr,
                               const float* __restrict__ dinv, unsigned short* __restrict__ dst,
                               int ldD, int offD) {
  int c = blockIdx.x;
  int t = threadIdx.x;  // 64
  int f = t & 7, j = t >> 3;
  int beg = rowptr[c], end = rowptr[c + 1];
  __shared__ int si[64];
  __shared__ float sw[64];
  __shared__ float red[8][8];
  float acc = 0.f;
  for (int j0 = beg; j0 < end; j0 += 64) {
    int nn = min(64, end - j0);
    __syncthreads();
    if (t < nn) {
      int r = eidx[j0 + t] & 0xFFFF;
      si[t] = r;
      sw[t] = dinv[r];
    }
    __syncthreads();
    if (f < 7)
      for (int u = j; u < nn; u += 8) acc += sw[u] * b2f(src[(size_t)si[u] * ldS + offS + f]);
  }
  red[j][f] = acc;
  __syncthreads();
  if (j == 0 && f < 7) {
    float s = 0.f;
    for (int u = 0; u < 8; u++) s += red[u][f];
    dst[(size_t)c * ldD + offD + f] = f2b(s * dinv[c]);
  }
}

// ResGated gather + skip(K=6) + bias + relu; kk/q/v bf16
__global__ void k_resgated_gather(const unsigned short* __restrict__ kk,
                                  const unsigned short* __restrict__ q,
                                  const unsigned short* __restrict__ v,
                                  const float* __restrict__ ea,
                                  const float* __restrict__ We, const int* __restrict__ rh,
                                  const int* __restrict__ eidx, const int* __restrict__ rowptr,
                                  const float* __restrict__ sx, const float* __restrict__ Wsk,
                                  const float* __restrict__ rgb, unsigned short* __restrict__ out) {
  int c = blockIdx.x, h = threadIdx.x;
  int beg = rowptr[c], end = rowptr[c + 1];
  __shared__ int sr[64];
  __shared__ float se0[64], se1[64];
  float kload = b2f(kk[(size_t)c * H + h]);
  float we0 = We[h], we1 = We[H + h];
  float acc = 0.f;
  for (int j0 = beg; j0 < end; j0 += 64) {
    int nn = min(64, end - j0);
    __syncthreads();
    if (h < nn) {
      int e = eidx[j0 + h];
      sr[h] = rh[e];
      se0[h] = ea[2 * e];
      se1[h] = ea[2 * e + 1];
    }
    __syncthreads();
    for (int t = 0; t < nn; t++) {
      int r = sr[t];
      float x = kload + b2f(q[(size_t)r * H + h]) + se0[t] * we0 + se1[t] * we1;
      float eta = 1.f / (1.f + __expf(-x));
      acc += eta * b2f(v[(size_t)r * H + h]);
    }
  }
  float skip = rgb[h];
#pragma unroll
  for (int f = 0; f < 6; f++) skip = fmaf(sx[c * 6 + f], Wsk[f * H + h], skip);
  out[(size_t)c * H + h] = f2b(fmaxf(acc + skip, 0.f));
}

// ================= small utilities =================
__global__ void k_copy7b(const float* __restrict__ src, unsigned short* __restrict__ dst, int n) {
  long long t = (long long)blockIdx.x * blockDim.x + threadIdx.x;
  int i = (int)(t >> 3), f = (int)(t & 7);
  if (i < n && f < 7) dst[(size_t)i * 32 + f] = f2b(src[(size_t)i * 7 + f]);
}

// tiny-K dense gemm (K=5/6), bf16 out
__global__ void k_gemm128b(const float* __restrict__ X, const float* __restrict__ W,
                           const float* __restrict__ b, unsigned short* __restrict__ out,
                           int M, int K) {
  long long t = (long long)blockIdx.x * blockDim.x + threadIdx.x;
  if (t >= (long long)M * H) return;
  int i = (int)(t >> 7), h = (int)(t & 127);
  float acc = b ? b[h] : 0.f;
  const float* x = X + (long long)i * K;
  for (int k = 0; k < K; k++) acc = fmaf(x[k], W[k * H + h], acc);
  out[t] = f2b(acc);
}

// ================= MFMA bf16 GEMM: C[M x 128] = [X1|X2] @ [W1;W2] =================
// X bf16 (row-major, ld in elems), W pre-transposed bf16 [128 x K].
// BM=64, 4 waves; epilogue: bias, relu, row-L2-norm; out fp32 or bf16.
__global__ __launch_bounds__(256) void k_mgemm(const unsigned short* __restrict__ X1, int ldX1, int K1,
                                               const unsigned short* __restrict__ W1t,
                                               const unsigned short* __restrict__ X2, int ldX2, int K2,
                                               const unsigned short* __restrict__ W2t,
                                               const float* __restrict__ bias,
                                               void* __restrict__ Cv, long ldC,
                                               int M, int flags) {
  __shared__ unsigned short Als[64 * 40];
  __shared__ unsigned short Bls[128 * 40];
  __shared__ float rs[2][64];
  int tid = threadIdx.x;
  int lane = tid & 63, wv = tid >> 6;
  int m = lane & 15, q = lane >> 4;
  int rbase = (wv & 1) * 32;
  int cbase = (wv >> 1) * 64;
  int blockRow = blockIdx.x * 64;
  int sr = tid >> 2, skc = (tid & 3) * 8;
  f32x4 acc[2][4];
#pragma unroll
  for (int a = 0; a < 2; a++)
#pragma unroll
    for (int b = 0; b < 4; b++) acc[a][b] = (f32x4){0.f, 0.f, 0.f, 0.f};

  int Ktot = K1 + K2;
  for (int k0 = 0; k0 < Ktot; k0 += 32) {
    const unsigned short* Xb;
    const unsigned short* Wt_;
    int kr, ldx, Kw;
    if (k0 < K1) { Xb = X1; Wt_ = W1t; kr = k0; ldx = ldX1; Kw = K1; }
    else { Xb = X2; Wt_ = W2t; kr = k0 - K1; ldx = ldX2; Kw = K2; }
    __syncthreads();
    {
      int gr = blockRow + sr;
      bf16x8 xv = (bf16x8){0, 0, 0, 0, 0, 0, 0, 0};
      if (gr < M) xv = *(const bf16x8*)(Xb + (size_t)gr * ldx + kr + skc);
      *(bf16x8*)&Als[sr * 40 + skc] = xv;
    }
#pragma unroll
    for (int it = 0; it < 2; it++) {
      int fid = it * 256 + tid;
      int n = fid >> 2, kc = (fid & 3) * 8;
      *(bf16x8*)&Bls[n * 40 + kc] = *(const bf16x8*)(Wt_ + (size_t)n * Kw + kr + kc);
    }
    __syncthreads();
    bf16x8 a0 = *(const bf16x8*)&Als[(rbase + m) * 40 + q * 8];
    bf16x8 a1 = *(const bf16x8*)&Als[(rbase + 16 + m) * 40 + q * 8];
    bf16x8 b0 = *(const bf16x8*)&Bls[(cbase + m) * 40 + q * 8];
    bf16x8 b1 = *(const bf16x8*)&Bls[(cbase + 16 + m) * 40 + q * 8];
    bf16x8 b2 = *(const bf16x8*)&Bls[(cbase + 32 + m) * 40 + q * 8];
    bf16x8 b3 = *(const bf16x8*)&Bls[(cbase + 48 + m) * 40 + q * 8];
    acc[0][0] = __builtin_amdgcn_mfma_f32_16x16x32_bf16(a0, b0, acc[0][0], 0, 0, 0);
    acc[0][1] = __builtin_amdgcn_mfma_f32_16x16x32_bf16(a0, b1, acc[0][1], 0, 0, 0);
    acc[0][2] = __builtin_amdgcn_mfma_f32_16x16x32_bf16(a0, b2, acc[0][2], 0, 0, 0);
    acc[0][3] = __builtin_amdgcn_mfma_f32_16x16x32_bf16(a0, b3, acc[0][3], 0, 0, 0);
    acc[1][0] = __builtin_amdgcn_mfma_f32_16x16x32_bf16(a1, b0, acc[1][0], 0, 0, 0);
    acc[1][1] = __builtin_amdgcn_mfma_f32_16x16x32_bf16(a1, b1, acc[1][1], 0, 0, 0);
    acc[1][2] = __builtin_amdgcn_mfma_f32_16x16x32_bf16(a1, b2, acc[1][2], 0, 0, 0);
    acc[1][3] = __builtin_amdgcn_mfma_f32_16x16x32_bf16(a1, b3, acc[1][3], 0, 0, 0);
  }
  float ov[2][4][4];
  float bcol[4] = {0.f, 0.f, 0.f, 0.f};
  if (bias) {
#pragma unroll
    for (int j = 0; j < 4; j++) bcol[j] = bias[cbase + j * 16 + m];
  }
#pragma unroll
  for (int a = 0; a < 2; a++)
#pragma unroll
    for (int j = 0; j < 4; j++)
#pragma unroll
      for (int i = 0; i < 4; i++) ov[a][j][i] = acc[a][j][i] + bcol[j];

  if (flags & TG_NORM) {
#pragma unroll
    for (int a = 0; a < 2; a++)
#pragma unroll
      for (int i = 0; i < 4; i++) {
        float p = 0.f;
#pragma unroll
        for (int j = 0; j < 4; j++) p = fmaf(ov[a][j][i], ov[a][j][i], p);
        p += __shfl_xor(p, 1);
        p += __shfl_xor(p, 2);
        p += __shfl_xor(p, 4);
        p += __shfl_xor(p, 8);
        if (m == 0) rs[wv >> 1][rbase + a * 16 + q * 4 + i] = p;
      }
    __syncthreads();
#pragma unroll
    for (int a = 0; a < 2; a++)
#pragma unroll
      for (int i = 0; i < 4; i++) {
        int ridx = rbase + a * 16 + q * 4 + i;
        float s = rs[0][ridx] + rs[1][ridx];
        float f = 1.f / fmaxf(sqrtf(s), 1e-12f);
#pragma unroll
        for (int j = 0; j < 4; j++) ov[a][j][i] = fmaxf(ov[a][j][i] * f, 0.f);
      }
  } else if (flags & TG_RELU) {
#pragma unroll
    for (int a = 0; a < 2; a++)
#pragma unroll
      for (int j = 0; j < 4; j++)
#pragma unroll
        for (int i = 0; i < 4; i++) ov[a][j][i] = fmaxf(ov[a][j][i], 0.f);
  }
  if (flags & TG_OUTBF16) {
    unsigned short* C = (unsigned short*)Cv;
#pragma unroll
    for (int a = 0; a < 2; a++)
#pragma unroll
      for (int i = 0; i < 4; i++) {
        int row = blockRow + rbase + a * 16 + q * 4 + i;
        if (row < M) {
#pragma unroll
          for (int j = 0; j < 4; j++)
            C[(size_t)row * ldC + cbase + j * 16 + m] = f2b(ov[a][j][i]);
        }
      }
  } else {
    float* C = (float*)Cv;
#pragma unroll
    for (int a = 0; a < 2; a++)
#pragma unroll
      for (int i = 0; i < 4; i++) {
        int row = blockRow + rbase + a * 16 + q * 4 + i;
        if (row < M) {
#pragma unroll
          for (int j = 0; j < 4; j++)
            C[(size_t)row * ldC + cbase + j * 16 + m] = ov[a][j][i];
        }
      }
  }
}

static inline int mgb(int M) { return (M + 63) / 64; }

// ================= fused head: z = relu(X@lw + lb) @ lwl + lbl =================
__global__ __launch_bounds__(256) void k_head(const float* __restrict__ X,
                                              const float* __restrict__ lw,
                                              const float* __restrict__ lb,
                                              const float* __restrict__ lwl,
                                              const float* __restrict__ lbl,
                                              float* __restrict__ z, int M) {
  __shared__ float Wl[128 * 32];
  __shared__ float Xs[8][128];
  int tid = threadIdx.x;
  for (int i = tid * 4; i < 4096; i += 1024) *(float4*)&Wl[i] = *(const float4*)&lw[i];
  int rowBase = blockIdx.x * 8;
  {
    int idx = tid * 4;
    int xr = idx >> 7, xc = idx & 127;
    int grow = rowBase + xr;
    float4 v = make_float4(0.f, 0.f, 0.f, 0.f);
    if (grow < M) v = *(const float4*)(X + (size_t)grow * H + xc);
    *(float4*)&Xs[xr][xc] = v;
  }
  __syncthreads();
  int r = tid >> 5, o = tid & 31;
  float acc = lb[o];
  for (int k = 0; k < 128; k++) acc = fmaf(Xs[r][k], Wl[k * 32 + o], acc);
  acc = fmaxf(acc, 0.f) * lwl[o];
  for (int s = 16; s > 0; s >>= 1) acc += __shfl_down(acc, s, 32);
  int grow = rowBase + r;
  if (o == 0 && grow < M) z[grow] = acc + lbl[0];
}

// ================= log_softmax over axis 0 =================
__global__ void k_logsoftmax(const float* __restrict__ z, float* __restrict__ out, int n) {
  __shared__ float red[256];
  int tid = threadIdx.x;
  float m = -1e30f;
  for (int i = tid; i < n; i += 256) m = fmaxf(m, z[i]);
  red[tid] = m;
  __syncthreads();
  for (int s = 128; s > 0; s >>= 1) {
    if (tid < s) red[tid] = fmaxf(red[tid], red[tid + s]);
    __syncthreads();
  }
  float mx = red[0];
  __syncthreads();
  float sum = 0.f;
  for (int i = tid; i < n; i += 256) sum += __expf(z[i] - mx);
  red[tid] = sum;
  __syncthreads();
  for (int s = 128; s > 0; s >>= 1) {
    if (tid < s) red[tid] += red[tid + s];
    __syncthreads();
  }
  float lse = mx + logf(red[0]);
  for (int i = tid; i < n; i += 256) out[i] = z[i] - lse;
}

extern "C" void kernel_launch(void* const* d_in, const int* in_sizes, int n_in,
                              void* d_out, int out_size, void* d_ws, size_t ws_size,
                              hipStream_t stream) {
  const float* game_x = (const float*)d_in[0];
  const float* state_x = (const float*)d_in[1];
  const float* pc_x = (const float*)d_in[2];
  const int* ei_vv = (const int*)d_in[3];
  const int* et_vv = (const int*)d_in[4];
  const int* ei_hist = (const int*)d_in[5];
  const float* ea_hist = (const float*)d_in[6];
  const int* ei_in = (const int*)d_in[7];
  const int* ei_ss = (const int*)d_in[8];
  const int* ei_pp = (const int*)d_in[9];
  const int* ei_ps = (const int*)d_in[10];
  const float* tag10_w = (const float*)d_in[12];
  const float* tag10_b = (const float*)d_in[13];
  const float* rgcn_w = (const float*)d_in[14];
  const float* rgcn_root = (const float*)d_in[15];
  const float* rgcn_b = (const float*)d_in[16];
  const float* gcn1_w = (const float*)d_in[17];
  const float* gcn1_b = (const float*)d_in[18];
  const float* gcn2_w = (const float*)d_in[19];
  const float* gcn2_b = (const float*)d_in[20];
  const float* rg_key_w = (const float*)d_in[21];
  const float* rg_key_b = (const float*)d_in[22];
  const float* rg_query_w = (const float*)d_in[23];
  const float* rg_query_b = (const float*)d_in[24];
  const float* rg_value_w = (const float*)d_in[25];
  const float* rg_value_b = (const float*)d_in[26];
  const float* rg_edge_w = (const float*)d_in[27];
  const float* rg_skip_w = (const float*)d_in[28];
  const float* rg_b = (const float*)d_in[29];
  const float* sage32_lw = (const float*)d_in[30];
  const float* sage32_lb = (const float*)d_in[31];
  const float* sage32_rw = (const float*)d_in[32];
  const float* sage4_lw = (const float*)d_in[33];
  const float* sage4_lb = (const float*)d_in[34];
  const float* sage4_rw = (const float*)d_in[35];
  const float* sage42_lw = (const float*)d_in[36];
  const float* sage42_lb = (const float*)d_in[37];
  const float* sage42_rw = (const float*)d_in[38];
  const float* pcs_lw = (const float*)d_in[39];
  const float* pcs_lb = (const float*)d_in[40];
  const float* pcs_rw = (const float*)d_in[41];
  const float* tag2_w = (const float*)d_in[42];
  const float* tag2_b = (const float*)d_in[43];
  const float* sage5_lw = (const float*)d_in[44];
  const float* sage5_lb = (const float*)d_in[45];
  const float* sage5_rw = (const float*)d_in[46];
  const float* lin_w = (const float*)d_in[47];
  const float* lin_b = (const float*)d_in[48];
  const float* linl_w = (const float*)d_in[49];
  const float* linl_b = (const float*)d_in[50];

  const int Evv = in_sizes[3] / 2, Eh = in_sizes[5] / 2, Ein = in_sizes[7] / 2,
            Ess = in_sizes[8] / 2, Epp = in_sizes[9] / 2, Eps = in_sizes[10] / 2;
  const int EE = Evv + Epp + Eh + Ein + Eps + Ess;
  const int NN = NG + NP + 4 * NS;

  // ---- workspace layout (bytes). Peak ~113 MB. ----
  char* base = (char*)d_ws;
  const size_t B_NGH = (size_t)NG * H * 2;   // 12.8 MB
  const size_t B_NPH = (size_t)NP * H * 2;   // 7.68 MB
  const size_t B_NSH = (size_t)NS * H * 2;   // 5.12 MB
  unsigned short* g_tag_b = (unsigned short*)base;             // later q_b
  unsigned short* g_b = (unsigned short*)(base + B_NGH);
  char* C0 = base + 2 * B_NGH;                                  // 46 MB arena
  unsigned short* P_tag10_b = (unsigned short*)C0;              // NG*32
  unsigned short* G3_b = (unsigned short*)C0;                   // NG*384 = 38.4 MB
  unsigned short* xW_b = (unsigned short*)C0;                   // NP*128
  unsigned short* p1b_b = (unsigned short*)(C0 + B_NPH);
  unsigned short* p2b_b = (unsigned short*)(C0 + 2 * B_NPH);    // lives to phase 7
  unsigned short* v_b = (unsigned short*)C0;                    // phase 4 (12.8MB < 15.36)
  unsigned short* q_b = g_tag_b;                                // after phase 2
  unsigned short* P_tag2_b = (unsigned short*)C0;               // NS*384 = 15.36 MB (= 2*B_NPH)
  char* S0 = base + 2 * B_NGH + 46000000;
  unsigned short* S_a_b = (unsigned short*)S0;
  unsigned short* S_b_b = (unsigned short*)(S0 + B_NSH);
  unsigned short* m_buf_b = (unsigned short*)(S0 + 2 * B_NSH);
  unsigned short* kk_b = (unsigned short*)(S0 + 3 * B_NSH);
  float* Sfin = (float*)(S0 + 4 * B_NSH);                       // NS*128 fp32
  unsigned short* Wt = (unsigned short*)(S0 + 4 * B_NSH + (size_t)NS * H * 4);
  int* ip = (int*)(S0 + 4 * B_NSH + (size_t)NS * H * 4 + 700000);
  int* rp_all = ip; ip += NN + 1;
  int* cur_all = ip; ip += NN;
  int* cnt_all = ip; ip += NN;
  int* eidx_all = ip; ip += EE;
  int* bsum = ip; ip += 512;
  float* fp = (float*)ip;
  float* dinv_all = fp; fp += NN;
  float* z = fp; fp += NS;

  // graph order: 0=vv, 1=pp, 2=hh, 3=in, 4=ps, 5=ss
  Seg6 sg;
  sg.col[0] = ei_vv + Evv;  sg.row[0] = ei_vv;
  sg.col[1] = ei_pp + Epp;  sg.row[1] = ei_pp;
  sg.col[2] = ei_hist + Eh; sg.row[2] = ei_hist;
  sg.col[3] = ei_in + Ein;  sg.row[3] = ei_in;
  sg.col[4] = ei_ps + Eps;  sg.row[4] = ei_ps;
  sg.col[5] = ei_ss + Ess;  sg.row[5] = ei_ss;
  sg.et0 = et_vv;
  int no[7] = {0, NG, NG + NP, NG + NP + NS, NG + NP + 2 * NS, NG + NP + 3 * NS, NN};
  int eo[7] = {0, Evv, Evv + Epp, Evv + Epp + Eh, Evv + Epp + Eh + Ein,
               Evv + Epp + Eh + Ein + Eps, EE};
  for (int i = 0; i < 7; i++) { sg.nodeoff[i] = no[i]; sg.edgeoff[i] = eo[i]; }
  int md[6] = {1, 0, 2, 0, 0, 0};
  float as[6] = {0.f, 1.f, 0.f, 0.f, 0.f, 0.f};
  int hd[6] = {1, 1, 0, 0, 0, 1};
  for (int i = 0; i < 6; i++) { sg.mode[i] = md[i]; sg.addself[i] = as[i]; sg.hasdinv[i] = hd[i]; }

  const int* rp_vv = rp_all + no[0];
  const int* rp_pp = rp_all + no[1];
  const int* rp_hh = rp_all + no[2];
  const int* rp_in = rp_all + no[3];
  const int* rp_ps = rp_all + no[4];
  const int* rp_ss = rp_all + no[5];
  const float* dinvG = dinv_all + no[0];
  const float* dinvP = dinv_all + no[1];
  const float* dinvS = dinv_all + no[5];
  const int* rh = ei_hist;

  // ---- weight pre-pack (transposed bf16) ----
  Pack17 pk;
  const float* wsrc[17] = {tag10_w, rgcn_w, rgcn_root, gcn2_w, rg_query_w, rg_value_w,
                           sage32_lw, sage32_rw, sage4_lw, sage4_rw, sage42_lw, sage42_rw,
                           pcs_lw, pcs_rw, tag2_w, sage5_lw, sage5_rw};
  int ksrc[17] = {28, 384, 128, 128, 128, 128, 128, 128, 128, 128, 128, 128, 128, 128, 384, 128, 128};
  int kdst[17] = {32, 384, 128, 128, 128, 128, 128, 128, 128, 128, 128, 128, 128, 128, 384, 128, 128};
  int run = 0;
  for (int i = 0; i < 17; i++) {
    pk.d[i].src = wsrc[i]; pk.d[i].Ksrc = ksrc[i]; pk.d[i].Kdst = kdst[i];
    pk.koff[i] = run; run += kdst[i];
  }
  pk.koff[17] = run;  // 2592
  unsigned short* WT[17];
  for (int i = 0; i < 17; i++) WT[i] = Wt + (size_t)pk.koff[i] * 128;
  k_pack<<<nblk((long long)run * 128), 256, 0, stream>>>(pk, Wt, run);

  // ---- batched CSR build: count, scan, bucketed fill ----
  hipMemsetAsync(cnt_all, 0, (size_t)NN * 4, stream);
  k_count_all<<<nblk(EE), 256, 0, stream>>>(sg, EE, cnt_all);
  k_dinv_all<<<nblk(NN), 256, 0, stream>>>(sg, NN, cnt_all, dinv_all);
  int nb = (NN + 511) / 512;
  k_scan1<<<nb, 256, 0, stream>>>(cnt_all, NN, rp_all, bsum);
  k_scan2<<<1, 64, 0, stream>>>(bsum, nb);
  k_scan3<<<nblk(NN + 1), 256, 0, stream>>>(rp_all, cur_all, bsum, NN, EE);
  const int shift = 19;  // 512k-entry (2 MB) position windows
  int npass = ((EE - 1) >> shift) + 1;
  for (int p = 0; p < npass; p++)
    k_fill_pass<<<nblk(EE), 256, 0, stream>>>(sg, EE, rp_all, cur_all, eidx_all, p, shift);

  // ================= phase 1: TAGConv game (7-dim bf16 hops, K packed to 32) ==========
  hipMemsetAsync(P_tag10_b, 0, (size_t)NG * 32 * 2, stream);
  k_copy7b<<<nblk((long long)NG * 8), 256, 0, stream>>>(game_x, P_tag10_b, NG);
  k_gather_norm7<<<NG, 64, 0, stream>>>(P_tag10_b, 32, 0, eidx_all, rp_vv, dinvG, P_tag10_b, 32, 7);
  k_gather_norm7<<<NG, 64, 0, stream>>>(P_tag10_b, 32, 7, eidx_all, rp_vv, dinvG, P_tag10_b, 32, 14);
  k_gather_norm7<<<NG, 64, 0, stream>>>(P_tag10_b, 32, 14, eidx_all, rp_vv, dinvG, P_tag10_b, 32, 21);
  k_mgemm<<<mgb(NG), 256, 0, stream>>>(P_tag10_b, 32, 32, WT[0], nullptr, 0, 0, nullptr,
                                       tag10_b, g_tag_b, H, NG, TG_RELU | TG_OUTBF16);

  // ================= phase 2: RGCN — one dual-source GEMM (K=384 + root K=128) ========
  k_gather_rel3<<<NG, 128, 0, stream>>>(g_tag_b, eidx_all, rp_vv, G3_b);
  k_mgemm<<<mgb(NG), 256, 0, stream>>>(G3_b, 384, 384, WT[1], g_tag_b, H, H, WT[2],
                                       rgcn_b, g_b, H, NG, TG_RELU | TG_OUTBF16);

  // ================= phase 3: pc graph (2x GCN) =================
  k_gemm128b<<<nblk((long long)NP * H), 256, 0, stream>>>(pc_x, gcn1_w, nullptr, xW_b, NP, 5);
  k_gather_norm<<<NP, 128, 0, stream>>>(xW_b, H, 0, eidx_all, rp_pp, dinvP, xW_b, gcn1_b,
                                        p1b_b, H, 0, 1);
  k_mgemm<<<mgb(NP), 256, 0, stream>>>(p1b_b, H, H, WT[3], nullptr, 0, 0, nullptr,
                                       nullptr, xW_b, H, NP, TG_OUTBF16);
  k_gather_norm<<<NP, 128, 0, stream>>>(xW_b, H, 0, eidx_all, rp_pp, dinvP, xW_b, gcn2_b,
                                        p2b_b, H, 0, 1);

  // ================= phase 4: ResGated (game -> state) =================
  k_gemm128b<<<nblk((long long)NS * H), 256, 0, stream>>>(state_x, rg_key_w, rg_key_b, kk_b, NS, 6);
  k_mgemm<<<mgb(NG), 256, 0, stream>>>(g_b, H, H, WT[4], nullptr, 0, 0, nullptr,
                                       rg_query_b, q_b, H, NG, TG_OUTBF16);
  k_mgemm<<<mgb(NG), 256, 0, stream>>>(g_b, H, H, WT[5], nullptr, 0, 0, nullptr,
                                       rg_value_b, v_b, H, NG, TG_OUTBF16);
  k_resgated_gather<<<NS, 128, 0, stream>>>(kk_b, q_b, v_b, ea_hist, rg_edge_w, rh,
                                            eidx_all, rp_hh, state_x, rg_skip_w, rg_b, S_a_b);

  // ================= phase 5: sage32 (hist, xs=g) =================
  k_gather_mean<<<NS, 128, 0, stream>>>(g_b, eidx_all, rp_hh, rh, m_buf_b);
  k_mgemm<<<mgb(NS), 256, 0, stream>>>(m_buf_b, H, H, WT[6], S_a_b, H, H, WT[7],
                                       sage32_lb, S_b_b, H, NS, TG_NORM | TG_OUTBF16);

  // ================= phase 6: sage4 + sage42 (in, xs=g; shared mean) =================
  k_gather_mean<<<NS, 128, 0, stream>>>(g_b, eidx_all, rp_in, nullptr, m_buf_b);
  k_mgemm<<<mgb(NS), 256, 0, stream>>>(m_buf_b, H, H, WT[8], S_b_b, H, H, WT[9],
                                       sage4_lb, S_a_b, H, NS, TG_NORM | TG_OUTBF16);
  k_mgemm<<<mgb(NS), 256, 0, stream>>>(m_buf_b, H, H, WT[10], S_a_b, H, H, WT[11],
                                       sage42_lb, S_b_b, H, NS, TG_NORM | TG_OUTBF16);

  // ================= phase 7: pcs sage (pc->state) — writes tag2 operand col 0 ========
  k_gather_mean<<<NS, 128, 0, stream>>>(p2b_b, eidx_all, rp_ps, nullptr, m_buf_b);
  k_mgemm<<<mgb(NS), 256, 0, stream>>>(m_buf_b, H, H, WT[12], S_b_b, H, H, WT[13],
                                       pcs_lb, P_tag2_b, 384, NS, TG_NORM | TG_OUTBF16);

  // ================= phase 8: tag2 (2 hops into cols 128/256, K=384 GEMM) =============
  k_gather_norm<<<NS, 128, 0, stream>>>(P_tag2_b, 384, 0, eidx_all, rp_ss, dinvS, nullptr,
                                        nullptr, P_tag2_b, 384, 128, 0);
  k_gather_norm<<<NS, 128, 0, stream>>>(P_tag2_b, 384, 128, eidx_all, rp_ss, dinvS, nullptr,
                                        nullptr, P_tag2_b, 384, 256, 0);
  k_mgemm<<<mgb(NS), 256, 0, stream>>>(P_tag2_b, 384, 384, WT[14], nullptr, 0, 0, nullptr,
                                       tag2_b, S_b_b, H, NS, TG_RELU | TG_OUTBF16);

  // ================= phase 9: sage5 (state graph, xs=xd=s) — fp32 out for head ========
  k_gather_mean<<<NS, 128, 0, stream>>>(S_b_b, eidx_all, rp_ss, nullptr, m_buf_b);
  k_mgemm<<<mgb(NS), 256, 0, stream>>>(m_buf_b, H, H, WT[15], S_b_b, H, H, WT[16],
                                       sage5_lb, Sfin, H, NS, TG_NORM);

  // ================= head =================
  k_head<<<(NS + 7) / 8, 256, 0, stream>>>(Sfin, lin_w, lin_b, linl_w, linl_b, z, NS);
  k_logsoftmax<<<1, 256, 0, stream>>>(z, (float*)d_out, NS);
}

// Round 7
// 805.104 us; speedup vs baseline: 5.7187x; 1.1416x over previous
//
#include <hip/hip_runtime.h>
#include <cstdint>

#define H 128
static const int NG = 50000, NS = 20000, NP = 30000;

#define TG_RELU 2
#define TG_NORM 4
#define TG_OUTBF16 8

#define CSR_CHUNK 8192

typedef __attribute__((ext_vector_type(8))) short bf16x8;
typedef __attribute__((ext_vector_type(4))) float f32x4;

static inline int nblk(long long n) { return (int)((n + 255) / 256); }

__device__ inline unsigned short f2b(float f) {
  unsigned int u = __float_as_uint(f);
  u += 0x7FFFu + ((u >> 16) & 1u);
  return (unsigned short)(u >> 16);
}
__device__ inline float b2f(unsigned short u) {
  return __uint_as_float(((unsigned int)u) << 16);
}

// ================= atomic-free batched CSR build =================
struct Seg6 {
  const int* col[6];
  const int* row[6];
  const int* et0;
  int nodeoff[7];
  int edgeoff[7];
  int mode[6];         // 0=row, 1=row|(et<<16), 2=edge id (local)
  float addself[6];
  int hasdinv[6];
};

// per-8192-edge-block 512-bin coarse histogram (bucket = gn>>9), no global atomics
__global__ __launch_bounds__(256) void k_hist(Seg6 sg, int EE, int* __restrict__ table) {
  __shared__ int h[512];
  int tid = threadIdx.x, blk = blockIdx.x;
  h[tid] = 0; h[tid + 256] = 0;
  __syncthreads();
  int e0 = blk * CSR_CHUNK, e1 = min(EE, e0 + CSR_CHUNK);
  for (int e = e0 + tid; e < e1; e += 256) {
    int gi = 0;
    while (e >= sg.edgeoff[gi + 1]) gi++;
    int le = e - sg.edgeoff[gi];
    int gn = sg.nodeoff[gi] + sg.col[gi][le];
    atomicAdd(&h[gn >> 9], 1);  // LDS atomic
  }
  __syncthreads();
  table[blk * 512 + tid] = h[tid];
  table[blk * 512 + tid + 256] = h[tid + 256];
}

// one block, 512 threads: column-scan table -> per-(block,bucket) bases + coarseOff
__global__ void k_scanT(int* __restrict__ table, int nblkA, int* __restrict__ coarseOff) {
  int b = threadIdx.x;  // 0..511
  int s = 0;
  for (int k = 0; k < nblkA; k++) s += table[k * 512 + b];
  __shared__ int cs[512];
  cs[b] = s;
  __syncthreads();
  for (int off = 1; off < 512; off <<= 1) {
    int v = cs[b];
    int u = (b >= off) ? cs[b - off] : 0;
    __syncthreads();
    cs[b] = v + u;
    __syncthreads();
  }
  int excl = (b > 0) ? cs[b - 1] : 0;
  coarseOff[b] = excl;
  if (b == 511) coarseOff[512] = cs[511];
  int run = excl;
  for (int k = 0; k < nblkA; k++) {
    int t = table[k * 512 + b];
    table[k * 512 + b] = run;
    run += t;
  }
}

// scatter (gn, payload) pairs into per-bucket spans using LDS cursors from table
__global__ __launch_bounds__(256) void k_scatterA(Seg6 sg, int EE, const int* __restrict__ table,
                                                  uint2* __restrict__ tmp) {
  __shared__ int cur[512];
  int tid = threadIdx.x, blk = blockIdx.x;
  cur[tid] = table[blk * 512 + tid];
  cur[tid + 256] = table[blk * 512 + tid + 256];
  __syncthreads();
  int e0 = blk * CSR_CHUNK, e1 = min(EE, e0 + CSR_CHUNK);
  for (int e = e0 + tid; e < e1; e += 256) {
    int gi = 0;
    while (e >= sg.edgeoff[gi + 1]) gi++;
    int le = e - sg.edgeoff[gi];
    int gn = sg.nodeoff[gi] + sg.col[gi][le];
    int m = sg.mode[gi];
    int pay;
    if (m == 2) pay = le;
    else {
      pay = sg.row[gi][le];
      if (m == 1) pay |= sg.et0[le] << 16;
    }
    int pos = atomicAdd(&cur[gn >> 9], 1);  // LDS atomic; spans disjoint per (blk,bucket)
    tmp[pos] = make_uint2((unsigned)gn, (unsigned)pay);
  }
}

// per-bucket (512 nodes): count -> rowptr + dinv, then scatter payloads into L2-hot window
__global__ __launch_bounds__(256) void k_localCSR(const uint2* __restrict__ tmp,
                                                  const int* __restrict__ coarseOff,
                                                  Seg6 sg, int NN, int EE, int B,
                                                  int* __restrict__ rowptr,
                                                  int* __restrict__ eidx,
                                                  float* __restrict__ dinv) {
  int b = blockIdx.x, tid = threadIdx.x;
  int base = b * 512;
  int nNodes = min(512, NN - base);
  int beg = coarseOff[b], end = coarseOff[b + 1];
  __shared__ int cnt[512];
  __shared__ int off[512];
  __shared__ int ps[256];
  cnt[tid] = 0; cnt[tid + 256] = 0;
  __syncthreads();
  for (int j = beg + tid; j < end; j += 256)
    atomicAdd(&cnt[tmp[j].x - base], 1);
  __syncthreads();
  // exclusive scan of cnt[512] (pair-per-thread + Hillis-Steele over 256 pair-sums)
  int a = cnt[2 * tid], bb = cnt[2 * tid + 1];
  ps[tid] = a + bb;
  __syncthreads();
  for (int o = 1; o < 256; o <<= 1) {
    int v = ps[tid];
    int u = (tid >= o) ? ps[tid - o] : 0;
    __syncthreads();
    ps[tid] = v + u;
    __syncthreads();
  }
  int excl = (tid > 0) ? ps[tid - 1] : 0;
  off[2 * tid] = excl;
  off[2 * tid + 1] = excl + a;
  __syncthreads();
  // rowptr + dinv
  for (int i = tid; i < nNodes; i += 256) {
    int gid = base + i;
    rowptr[gid] = beg + off[i];
    int gi = 0;
    while (gid >= sg.nodeoff[gi + 1]) gi++;
    if (sg.hasdinv[gi]) {
      float d = (float)cnt[i] + sg.addself[gi];
      dinv[gid] = (d > 0.f) ? rsqrtf(d) : 0.f;
    }
  }
  if (b == B - 1 && tid == 0) rowptr[NN] = EE;
  __syncthreads();
  // scatter payloads (off doubles as cursor)
  for (int j = beg + tid; j < end; j += 256) {
    uint2 p = tmp[j];
    int pos = beg + atomicAdd(&off[p.x - base], 1);
    eidx[pos] = (int)p.y;
  }
}

// ================= weight pre-pack: fp32 [K x 128] -> bf16 transposed [128 x Kdst] =====
struct PackD { const float* src; int Ksrc; int Kdst; };
struct Pack17 { PackD d[17]; int koff[18]; };

__global__ void k_pack(Pack17 p, unsigned short* __restrict__ Wt, int totalRows) {
  int t = blockIdx.x * blockDim.x + threadIdx.x;
  if (t >= totalRows * 128) return;
  int gk = t >> 7, n = t & 127;
  int w = 0;
  while (gk >= p.koff[w + 1]) w++;
  int k = gk - p.koff[w];
  float v = (k < p.d[w].Ksrc) ? p.d[w].src[(size_t)k * 128 + n] : 0.f;
  Wt[(size_t)p.koff[w] * 128 + (size_t)n * p.d[w].Kdst + k] = f2b(v);
}

// ================= gathers (bf16 src/dst, fp32 accumulate) =================
__global__ void k_gather_mean(const unsigned short* __restrict__ src, const int* __restrict__ eidx,
                              const int* __restrict__ rowptr, const int* __restrict__ remap,
                              unsigned short* __restrict__ out) {
  int c = blockIdx.x, h = threadIdx.x;
  int beg = rowptr[c], end = rowptr[c + 1];
  __shared__ int si[128];
  float acc = 0.f;
  for (int j0 = beg; j0 < end; j0 += 128) {
    int nn = min(128, end - j0);
    __syncthreads();
    if (h < nn) {
      int e = eidx[j0 + h];
      si[h] = remap ? remap[e] : e;
    }
    __syncthreads();
    int t = 0;
    for (; t + 4 <= nn; t += 4) {
      float a0 = b2f(src[(size_t)si[t] * H + h]);
      float a1 = b2f(src[(size_t)si[t + 1] * H + h]);
      float a2 = b2f(src[(size_t)si[t + 2] * H + h]);
      float a3 = b2f(src[(size_t)si[t + 3] * H + h]);
      acc += (a0 + a1) + (a2 + a3);
    }
    for (; t < nn; t++) acc += b2f(src[(size_t)si[t] * H + h]);
  }
  int cnt = end - beg;
  out[(size_t)c * H + h] = f2b(acc * (1.f / (float)(cnt > 0 ? cnt : 1)));
}

// single-pass 3-relation mean; writes concatenated [rel0|rel1|rel2] row of width 384
__global__ void k_gather_rel3(const unsigned short* __restrict__ src, const int* __restrict__ eidx,
                              const int* __restrict__ rowptr, unsigned short* __restrict__ G3) {
  int c = blockIdx.x, h = threadIdx.x;
  int beg = rowptr[c], end = rowptr[c + 1];
  __shared__ int si[128];
  float a0 = 0.f, a1 = 0.f, a2 = 0.f;
  int c0 = 0, c1 = 0, c2 = 0;
  for (int j0 = beg; j0 < end; j0 += 128) {
    int nn = min(128, end - j0);
    __syncthreads();
    if (h < nn) si[h] = eidx[j0 + h];
    __syncthreads();
    for (int t = 0; t < nn; t++) {
      int pk = si[t];
      int rel = pk >> 16;
      float val = b2f(src[(size_t)(pk & 0xFFFF) * H + h]);
      if (rel == 0) { a0 += val; c0++; }
      else if (rel == 1) { a1 += val; c1++; }
      else { a2 += val; c2++; }
    }
  }
  size_t base = (size_t)c * 384;
  G3[base + h] = f2b(a0 * (1.f / (float)(c0 > 0 ? c0 : 1)));
  G3[base + 128 + h] = f2b(a1 * (1.f / (float)(c1 > 0 ? c1 : 1)));
  G3[base + 256 + h] = f2b(a2 * (1.f / (float)(c2 > 0 ? c2 : 1)));
}

// symmetric-normalized gather (+ optional self + bias + relu), strided bf16 src/dst
__global__ void k_gather_norm(const unsigned short* __restrict__ src, int ldS, int offS,
                              const int* __restrict__ eidx, const int* __restrict__ rowptr,
                              const float* __restrict__ dinv, const unsigned short* __restrict__ selfX,
                              const float* __restrict__ bias, unsigned short* __restrict__ out,
                              int ldD, int offD, int relu) {
  int c = blockIdx.x, h = threadIdx.x;
  int beg = rowptr[c], end = rowptr[c + 1];
  __shared__ int si[128];
  __shared__ float sw[128];
  float acc = 0.f;
  for (int j0 = beg; j0 < end; j0 += 128) {
    int nn = min(128, end - j0);
    __syncthreads();
    if (h < nn) {
      int r = eidx[j0 + h];
      si[h] = r;
      sw[h] = dinv[r];
    }
    __syncthreads();
    int t = 0;
    for (; t + 4 <= nn; t += 4) {
      float a0 = sw[t] * b2f(src[(size_t)si[t] * ldS + offS + h]);
      float a1 = sw[t + 1] * b2f(src[(size_t)si[t + 1] * ldS + offS + h]);
      float a2 = sw[t + 2] * b2f(src[(size_t)si[t + 2] * ldS + offS + h]);
      float a3 = sw[t + 3] * b2f(src[(size_t)si[t + 3] * ldS + offS + h]);
      acc += (a0 + a1) + (a2 + a3);
    }
    for (; t < nn; t++) acc += sw[t] * b2f(src[(size_t)si[t] * ldS + offS + h]);
  }
  float dc = dinv[c];
  float o = acc * dc;
  if (selfX) o += dc * dc * b2f(selfX[(size_t)c * H + h]);
  if (bias) o += bias[h];
  if (relu) o = fmaxf(o, 0.f);
  out[(size_t)c * ldD + offD + h] = f2b(o);
}

// 7-dim symmetric-normalized gather over bf16 (payload masked for etype bits)
__global__ void k_gather_norm7(const unsigned short* __restrict__ src, int ldS, int offS,
                               const int* __restrict__ eidx, const int* __restrict__ rowptr,
                               const float* __restrict__ dinv, unsigned short* __restrict__ dst,
                               int ldD, int offD) {
  int c = blockIdx.x;
  int t = threadIdx.x;  // 64
  int f = t & 7, j = t >> 3;
  int beg = rowptr[c], end = rowptr[c + 1];
  __shared__ int si[64];
  __shared__ float sw[64];
  __shared__ float red[8][8];
  float acc = 0.f;
  for (int j0 = beg; j0 < end; j0 += 64) {
    int nn = min(64, end - j0);
    __syncthreads();
    if (t < nn) {
      int r = eidx[j0 + t] & 0xFFFF;
      si[t] = r;
      sw[t] = dinv[r];
    }
    __syncthreads();
    if (f < 7)
      for (int u = j; u < nn; u += 8) acc += sw[u] * b2f(src[(size_t)si[u] * ldS + offS + f]);
  }
  red[j][f] = acc;
  __syncthreads();
  if (j == 0 && f < 7) {
    float s = 0.f;
    for (int u = 0; u < 8; u++) s += red[u][f];
    dst[(size_t)c * ldD + offD + f] = f2b(s * dinv[c]);
  }
}

// ResGated gather + skip(K=6) + bias + relu; kk/q/v bf16
__global__ void k_resgated_gather(const unsigned short* __restrict__ kk,
                                  const unsigned short* __restrict__ q,
                                  const unsigned short* __restrict__ v,
                                  const float* __restrict__ ea,
                                  const float* __restrict__ We, const int* __restrict__ rh,
                                  const int* __restrict__ eidx, const int* __restrict__ rowptr,
                                  const float* __restrict__ sx, const float* __restrict__ Wsk,
                                  const float* __restrict__ rgb, unsigned short* __restrict__ out) {
  int c = blockIdx.x, h = threadIdx.x;
  int beg = rowptr[c], end = rowptr[c + 1];
  __shared__ int sr[64];
  __shared__ float se0[64], se1[64];
  float kload = b2f(kk[(size_t)c * H + h]);
  float we0 = We[h], we1 = We[H + h];
  float acc = 0.f;
  for (int j0 = beg; j0 < end; j0 += 64) {
    int nn = min(64, end - j0);
    __syncthreads();
    if (h < nn) {
      int e = eidx[j0 + h];
      sr[h] = rh[e];
      se0[h] = ea[2 * e];
      se1[h] = ea[2 * e + 1];
    }
    __syncthreads();
    for (int t = 0; t < nn; t++) {
      int r = sr[t];
      float x = kload + b2f(q[(size_t)r * H + h]) + se0[t] * we0 + se1[t] * we1;
      float eta = 1.f / (1.f + __expf(-x));
      acc += eta * b2f(v[(size_t)r * H + h]);
    }
  }
  float skip = rgb[h];
#pragma unroll
  for (int f = 0; f < 6; f++) skip = fmaf(sx[c * 6 + f], Wsk[f * H + h], skip);
  out[(size_t)c * H + h] = f2b(fmaxf(acc + skip, 0.f));
}

// ================= small utilities =================
__global__ void k_copy7b(const float* __restrict__ src, unsigned short* __restrict__ dst, int n) {
  long long t = (long long)blockIdx.x * blockDim.x + threadIdx.x;
  int i = (int)(t >> 3), f = (int)(t & 7);
  if (i < n && f < 7) dst[(size_t)i * 32 + f] = f2b(src[(size_t)i * 7 + f]);
}

// tiny-K dense gemm (K=5/6), bf16 out
__global__ void k_gemm128b(const float* __restrict__ X, const float* __restrict__ W,
                           const float* __restrict__ b, unsigned short* __restrict__ out,
                           int M, int K) {
  long long t = (long long)blockIdx.x * blockDim.x + threadIdx.x;
  if (t >= (long long)M * H) return;
  int i = (int)(t >> 7), h = (int)(t & 127);
  float acc = b ? b[h] : 0.f;
  const float* x = X + (long long)i * K;
  for (int k = 0; k < K; k++) acc = fmaf(x[k], W[k * H + h], acc);
  out[t] = f2b(acc);
}

// ================= MFMA bf16 GEMM: C[M x 128] = [X1|X2] @ [W1;W2] =================
__global__ __launch_bounds__(256) void k_mgemm(const unsigned short* __restrict__ X1, int ldX1, int K1,
                                               const unsigned short* __restrict__ W1t,
                                               const unsigned short* __restrict__ X2, int ldX2, int K2,
                                               const unsigned short* __restrict__ W2t,
                                               const float* __restrict__ bias,
                                               void* __restrict__ Cv, long ldC,
                                               int M, int flags) {
  __shared__ unsigned short Als[64 * 40];
  __shared__ unsigned short Bls[128 * 40];
  __shared__ float rs[2][64];
  int tid = threadIdx.x;
  int lane = tid & 63, wv = tid >> 6;
  int m = lane & 15, q = lane >> 4;
  int rbase = (wv & 1) * 32;
  int cbase = (wv >> 1) * 64;
  int blockRow = blockIdx.x * 64;
  int sr = tid >> 2, skc = (tid & 3) * 8;
  f32x4 acc[2][4];
#pragma unroll
  for (int a = 0; a < 2; a++)
#pragma unroll
    for (int b = 0; b < 4; b++) acc[a][b] = (f32x4){0.f, 0.f, 0.f, 0.f};

  int Ktot = K1 + K2;
  for (int k0 = 0; k0 < Ktot; k0 += 32) {
    const unsigned short* Xb;
    const unsigned short* Wt_;
    int kr, ldx, Kw;
    if (k0 < K1) { Xb = X1; Wt_ = W1t; kr = k0; ldx = ldX1; Kw = K1; }
    else { Xb = X2; Wt_ = W2t; kr = k0 - K1; ldx = ldX2; Kw = K2; }
    __syncthreads();
    {
      int gr = blockRow + sr;
      bf16x8 xv = (bf16x8){0, 0, 0, 0, 0, 0, 0, 0};
      if (gr < M) xv = *(const bf16x8*)(Xb + (size_t)gr * ldx + kr + skc);
      *(bf16x8*)&Als[sr * 40 + skc] = xv;
    }
#pragma unroll
    for (int it = 0; it < 2; it++) {
      int fid = it * 256 + tid;
      int n = fid >> 2, kc = (fid & 3) * 8;
      *(bf16x8*)&Bls[n * 40 + kc] = *(const bf16x8*)(Wt_ + (size_t)n * Kw + kr + kc);
    }
    __syncthreads();
    bf16x8 a0 = *(const bf16x8*)&Als[(rbase + m) * 40 + q * 8];
    bf16x8 a1 = *(const bf16x8*)&Als[(rbase + 16 + m) * 40 + q * 8];
    bf16x8 b0 = *(const bf16x8*)&Bls[(cbase + m) * 40 + q * 8];
    bf16x8 b1 = *(const bf16x8*)&Bls[(cbase + 16 + m) * 40 + q * 8];
    bf16x8 b2 = *(const bf16x8*)&Bls[(cbase + 32 + m) * 40 + q * 8];
    bf16x8 b3 = *(const bf16x8*)&Bls[(cbase + 48 + m) * 40 + q * 8];
    acc[0][0] = __builtin_amdgcn_mfma_f32_16x16x32_bf16(a0, b0, acc[0][0], 0, 0, 0);
    acc[0][1] = __builtin_amdgcn_mfma_f32_16x16x32_bf16(a0, b1, acc[0][1], 0, 0, 0);
    acc[0][2] = __builtin_amdgcn_mfma_f32_16x16x32_bf16(a0, b2, acc[0][2], 0, 0, 0);
    acc[0][3] = __builtin_amdgcn_mfma_f32_16x16x32_bf16(a0, b3, acc[0][3], 0, 0, 0);
    acc[1][0] = __builtin_amdgcn_mfma_f32_16x16x32_bf16(a1, b0, acc[1][0], 0, 0, 0);
    acc[1][1] = __builtin_amdgcn_mfma_f32_16x16x32_bf16(a1, b1, acc[1][1], 0, 0, 0);
    acc[1][2] = __builtin_amdgcn_mfma_f32_16x16x32_bf16(a1, b2, acc[1][2], 0, 0, 0);
    acc[1][3] = __builtin_amdgcn_mfma_f32_16x16x32_bf16(a1, b3, acc[1][3], 0, 0, 0);
  }
  float ov[2][4][4];
  float bcol[4] = {0.f, 0.f, 0.f, 0.f};
  if (bias) {
#pragma unroll
    for (int j = 0; j < 4; j++) bcol[j] = bias[cbase + j * 16 + m];
  }
#pragma unroll
  for (int a = 0; a < 2; a++)
#pragma unroll
    for (int j = 0; j < 4; j++)
#pragma unroll
      for (int i = 0; i < 4; i++) ov[a][j][i] = acc[a][j][i] + bcol[j];

  if (flags & TG_NORM) {
#pragma unroll
    for (int a = 0; a < 2; a++)
#pragma unroll
      for (int i = 0; i < 4; i++) {
        float p = 0.f;
#pragma unroll
        for (int j = 0; j < 4; j++) p = fmaf(ov[a][j][i], ov[a][j][i], p);
        p += __shfl_xor(p, 1);
        p += __shfl_xor(p, 2);
        p += __shfl_xor(p, 4);
        p += __shfl_xor(p, 8);
        if (m == 0) rs[wv >> 1][rbase + a * 16 + q * 4 + i] = p;
      }
    __syncthreads();
#pragma unroll
    for (int a = 0; a < 2; a++)
#pragma unroll
      for (int i = 0; i < 4; i++) {
        int ridx = rbase + a * 16 + q * 4 + i;
        float s = rs[0][ridx] + rs[1][ridx];
        float f = 1.f / fmaxf(sqrtf(s), 1e-12f);
#pragma unroll
        for (int j = 0; j < 4; j++) ov[a][j][i] = fmaxf(ov[a][j][i] * f, 0.f);
      }
  } else if (flags & TG_RELU) {
#pragma unroll
    for (int a = 0; a < 2; a++)
#pragma unroll
      for (int j = 0; j < 4; j++)
#pragma unroll
        for (int i = 0; i < 4; i++) ov[a][j][i] = fmaxf(ov[a][j][i], 0.f);
  }
  if (flags & TG_OUTBF16) {
    unsigned short* C = (unsigned short*)Cv;
#pragma unroll
    for (int a = 0; a < 2; a++)
#pragma unroll
      for (int i = 0; i < 4; i++) {
        int row = blockRow + rbase + a * 16 + q * 4 + i;
        if (row < M) {
#pragma unroll
          for (int j = 0; j < 4; j++)
            C[(size_t)row * ldC + cbase + j * 16 + m] = f2b(ov[a][j][i]);
        }
      }
  } else {
    float* C = (float*)Cv;
#pragma unroll
    for (int a = 0; a < 2; a++)
#pragma unroll
      for (int i = 0; i < 4; i++) {
        int row = blockRow + rbase + a * 16 + q * 4 + i;
        if (row < M) {
#pragma unroll
          for (int j = 0; j < 4; j++)
            C[(size_t)row * ldC + cbase + j * 16 + m] = ov[a][j][i];
        }
      }
  }
}

static inline int mgb(int M) { return (M + 63) / 64; }

// ================= fused head: z = relu(X@lw + lb) @ lwl + lbl =================
__global__ __launch_bounds__(256) void k_head(const float* __restrict__ X,
                                              const float* __restrict__ lw,
                                              const float* __restrict__ lb,
                                              const float* __restrict__ lwl,
                                              const float* __restrict__ lbl,
                                              float* __restrict__ z, int M) {
  __shared__ float Wl[128 * 32];
  __shared__ float Xs[8][128];
  int tid = threadIdx.x;
  for (int i = tid * 4; i < 4096; i += 1024) *(float4*)&Wl[i] = *(const float4*)&lw[i];
  int rowBase = blockIdx.x * 8;
  {
    int idx = tid * 4;
    int xr = idx >> 7, xc = idx & 127;
    int grow = rowBase + xr;
    float4 v = make_float4(0.f, 0.f, 0.f, 0.f);
    if (grow < M) v = *(const float4*)(X + (size_t)grow * H + xc);
    *(float4*)&Xs[xr][xc] = v;
  }
  __syncthreads();
  int r = tid >> 5, o = tid & 31;
  float acc = lb[o];
  for (int k = 0; k < 128; k++) acc = fmaf(Xs[r][k], Wl[k * 32 + o], acc);
  acc = fmaxf(acc, 0.f) * lwl[o];
  for (int s = 16; s > 0; s >>= 1) acc += __shfl_down(acc, s, 32);
  int grow = rowBase + r;
  if (o == 0 && grow < M) z[grow] = acc + lbl[0];
}

// ================= log_softmax over axis 0 =================
__global__ void k_logsoftmax(const float* __restrict__ z, float* __restrict__ out, int n) {
  __shared__ float red[256];
  int tid = threadIdx.x;
  float m = -1e30f;
  for (int i = tid; i < n; i += 256) m = fmaxf(m, z[i]);
  red[tid] = m;
  __syncthreads();
  for (int s = 128; s > 0; s >>= 1) {
    if (tid < s) red[tid] = fmaxf(red[tid], red[tid + s]);
    __syncthreads();
  }
  float mx = red[0];
  __syncthreads();
  float sum = 0.f;
  for (int i = tid; i < n; i += 256) sum += __expf(z[i] - mx);
  red[tid] = sum;
  __syncthreads();
  for (int s = 128; s > 0; s >>= 1) {
    if (tid < s) red[tid] += red[tid + s];
    __syncthreads();
  }
  float lse = mx + logf(red[0]);
  for (int i = tid; i < n; i += 256) out[i] = z[i] - lse;
}

extern "C" void kernel_launch(void* const* d_in, const int* in_sizes, int n_in,
                              void* d_out, int out_size, void* d_ws, size_t ws_size,
                              hipStream_t stream) {
  const float* game_x = (const float*)d_in[0];
  const float* state_x = (const float*)d_in[1];
  const float* pc_x = (const float*)d_in[2];
  const int* ei_vv = (const int*)d_in[3];
  const int* et_vv = (const int*)d_in[4];
  const int* ei_hist = (const int*)d_in[5];
  const float* ea_hist = (const float*)d_in[6];
  const int* ei_in = (const int*)d_in[7];
  const int* ei_ss = (const int*)d_in[8];
  const int* ei_pp = (const int*)d_in[9];
  const int* ei_ps = (const int*)d_in[10];
  const float* tag10_w = (const float*)d_in[12];
  const float* tag10_b = (const float*)d_in[13];
  const float* rgcn_w = (const float*)d_in[14];
  const float* rgcn_root = (const float*)d_in[15];
  const float* rgcn_b = (const float*)d_in[16];
  const float* gcn1_w = (const float*)d_in[17];
  const float* gcn1_b = (const float*)d_in[18];
  const float* gcn2_w = (const float*)d_in[19];
  const float* gcn2_b = (const float*)d_in[20];
  const float* rg_key_w = (const float*)d_in[21];
  const float* rg_key_b = (const float*)d_in[22];
  const float* rg_query_w = (const float*)d_in[23];
  const float* rg_query_b = (const float*)d_in[24];
  const float* rg_value_w = (const float*)d_in[25];
  const float* rg_value_b = (const float*)d_in[26];
  const float* rg_edge_w = (const float*)d_in[27];
  const float* rg_skip_w = (const float*)d_in[28];
  const float* rg_b = (const float*)d_in[29];
  const float* sage32_lw = (const float*)d_in[30];
  const float* sage32_lb = (const float*)d_in[31];
  const float* sage32_rw = (const float*)d_in[32];
  const float* sage4_lw = (const float*)d_in[33];
  const float* sage4_lb = (const float*)d_in[34];
  const float* sage4_rw = (const float*)d_in[35];
  const float* sage42_lw = (const float*)d_in[36];
  const float* sage42_lb = (const float*)d_in[37];
  const float* sage42_rw = (const float*)d_in[38];
  const float* pcs_lw = (const float*)d_in[39];
  const float* pcs_lb = (const float*)d_in[40];
  const float* pcs_rw = (const float*)d_in[41];
  const float* tag2_w = (const float*)d_in[42];
  const float* tag2_b = (const float*)d_in[43];
  const float* sage5_lw = (const float*)d_in[44];
  const float* sage5_lb = (const float*)d_in[45];
  const float* sage5_rw = (const float*)d_in[46];
  const float* lin_w = (const float*)d_in[47];
  const float* lin_b = (const float*)d_in[48];
  const float* linl_w = (const float*)d_in[49];
  const float* linl_b = (const float*)d_in[50];

  const int Evv = in_sizes[3] / 2, Eh = in_sizes[5] / 2, Ein = in_sizes[7] / 2,
            Ess = in_sizes[8] / 2, Epp = in_sizes[9] / 2, Eps = in_sizes[10] / 2;
  const int EE = Evv + Epp + Eh + Ein + Eps + Ess;
  const int NN = NG + NP + 4 * NS;

  // ---- workspace layout (bytes). ----
  char* base = (char*)d_ws;
  const size_t B_NGH = (size_t)NG * H * 2;   // 12.8 MB
  const size_t B_NPH = (size_t)NP * H * 2;   // 7.68 MB
  const size_t B_NSH = (size_t)NS * H * 2;   // 5.12 MB
  unsigned short* g_tag_b = (unsigned short*)base;             // later q_b
  unsigned short* g_b = (unsigned short*)(base + B_NGH);
  char* C0 = base + 2 * B_NGH;                                  // 46 MB arena
  uint2* tmp_pairs = (uint2*)C0;                                // EE*8 = 14.4 MB (CSR phase only)
  unsigned short* P_tag10_b = (unsigned short*)C0;              // NG*32
  unsigned short* G3_b = (unsigned short*)C0;                   // NG*384 = 38.4 MB
  unsigned short* xW_b = (unsigned short*)C0;                   // NP*128
  unsigned short* p1b_b = (unsigned short*)(C0 + B_NPH);
  unsigned short* p2b_b = (unsigned short*)(C0 + 2 * B_NPH);    // lives to phase 7
  unsigned short* v_b = (unsigned short*)C0;                    // phase 4
  unsigned short* q_b = g_tag_b;                                // after phase 2
  unsigned short* P_tag2_b = (unsigned short*)C0;               // NS*384 = 15.36 MB
  char* S0 = base + 2 * B_NGH + 46000000;
  unsigned short* S_a_b = (unsigned short*)S0;
  unsigned short* S_b_b = (unsigned short*)(S0 + B_NSH);
  unsigned short* m_buf_b = (unsigned short*)(S0 + 2 * B_NSH);
  unsigned short* kk_b = (unsigned short*)(S0 + 3 * B_NSH);
  float* Sfin = (float*)(S0 + 4 * B_NSH);                       // NS*128 fp32
  unsigned short* Wt = (unsigned short*)(S0 + 4 * B_NSH + (size_t)NS * H * 4);
  int* ip = (int*)(S0 + 4 * B_NSH + (size_t)NS * H * 4 + 700000);
  int* rp_all = ip; ip += NN + 1;
  int* eidx_all = ip; ip += EE;
  int* table = ip; ip += 512 * 240;   // per-(block,bucket) offsets (nblkA <= 240)
  int* coarseOff = ip; ip += 520;
  float* fp = (float*)ip;
  float* dinv_all = fp; fp += NN;
  float* z = fp; fp += NS;

  // graph order: 0=vv, 1=pp, 2=hh, 3=in, 4=ps, 5=ss
  Seg6 sg;
  sg.col[0] = ei_vv + Evv;  sg.row[0] = ei_vv;
  sg.col[1] = ei_pp + Epp;  sg.row[1] = ei_pp;
  sg.col[2] = ei_hist + Eh; sg.row[2] = ei_hist;
  sg.col[3] = ei_in + Ein;  sg.row[3] = ei_in;
  sg.col[4] = ei_ps + Eps;  sg.row[4] = ei_ps;
  sg.col[5] = ei_ss + Ess;  sg.row[5] = ei_ss;
  sg.et0 = et_vv;
  int no[7] = {0, NG, NG + NP, NG + NP + NS, NG + NP + 2 * NS, NG + NP + 3 * NS, NN};
  int eo[7] = {0, Evv, Evv + Epp, Evv + Epp + Eh, Evv + Epp + Eh + Ein,
               Evv + Epp + Eh + Ein + Eps, EE};
  for (int i = 0; i < 7; i++) { sg.nodeoff[i] = no[i]; sg.edgeoff[i] = eo[i]; }
  int md[6] = {1, 0, 2, 0, 0, 0};
  float as[6] = {0.f, 1.f, 0.f, 0.f, 0.f, 0.f};
  int hd[6] = {1, 1, 0, 0, 0, 1};
  for (int i = 0; i < 6; i++) { sg.mode[i] = md[i]; sg.addself[i] = as[i]; sg.hasdinv[i] = hd[i]; }

  const int* rp_vv = rp_all + no[0];
  const int* rp_pp = rp_all + no[1];
  const int* rp_hh = rp_all + no[2];
  const int* rp_in = rp_all + no[3];
  const int* rp_ps = rp_all + no[4];
  const int* rp_ss = rp_all + no[5];
  const float* dinvG = dinv_all + no[0];
  const float* dinvP = dinv_all + no[1];
  const float* dinvS = dinv_all + no[5];
  const int* rh = ei_hist;

  // ---- weight pre-pack (transposed bf16) ----
  Pack17 pk;
  const float* wsrc[17] = {tag10_w, rgcn_w, rgcn_root, gcn2_w, rg_query_w, rg_value_w,
                           sage32_lw, sage32_rw, sage4_lw, sage4_rw, sage42_lw, sage42_rw,
                           pcs_lw, pcs_rw, tag2_w, sage5_lw, sage5_rw};
  int ksrc[17] = {28, 384, 128, 128, 128, 128, 128, 128, 128, 128, 128, 128, 128, 128, 384, 128, 128};
  int kdst[17] = {32, 384, 128, 128, 128, 128, 128, 128, 128, 128, 128, 128, 128, 128, 384, 128, 128};
  int run = 0;
  for (int i = 0; i < 17; i++) {
    pk.d[i].src = wsrc[i]; pk.d[i].Ksrc = ksrc[i]; pk.d[i].Kdst = kdst[i];
    pk.koff[i] = run; run += kdst[i];
  }
  pk.koff[17] = run;  // 2592
  unsigned short* WT[17];
  for (int i = 0; i < 17; i++) WT[i] = Wt + (size_t)pk.koff[i] * 128;
  k_pack<<<nblk((long long)run * 128), 256, 0, stream>>>(pk, Wt, run);

  // ---- atomic-free CSR build (4 dispatches) ----
  int nblkA = (EE + CSR_CHUNK - 1) / CSR_CHUNK;
  int B = (NN + 511) / 512;
  k_hist<<<nblkA, 256, 0, stream>>>(sg, EE, table);
  k_scanT<<<1, 512, 0, stream>>>(table, nblkA, coarseOff);
  k_scatterA<<<nblkA, 256, 0, stream>>>(sg, EE, table, tmp_pairs);
  k_localCSR<<<B, 256, 0, stream>>>(tmp_pairs, coarseOff, sg, NN, EE, B,
                                    rp_all, eidx_all, dinv_all);

  // ================= phase 1: TAGConv game (7-dim bf16 hops, K packed to 32) ==========
  hipMemsetAsync(P_tag10_b, 0, (size_t)NG * 32 * 2, stream);
  k_copy7b<<<nblk((long long)NG * 8), 256, 0, stream>>>(game_x, P_tag10_b, NG);
  k_gather_norm7<<<NG, 64, 0, stream>>>(P_tag10_b, 32, 0, eidx_all, rp_vv, dinvG, P_tag10_b, 32, 7);
  k_gather_norm7<<<NG, 64, 0, stream>>>(P_tag10_b, 32, 7, eidx_all, rp_vv, dinvG, P_tag10_b, 32, 14);
  k_gather_norm7<<<NG, 64, 0, stream>>>(P_tag10_b, 32, 14, eidx_all, rp_vv, dinvG, P_tag10_b, 32, 21);
  k_mgemm<<<mgb(NG), 256, 0, stream>>>(P_tag10_b, 32, 32, WT[0], nullptr, 0, 0, nullptr,
                                       tag10_b, g_tag_b, H, NG, TG_RELU | TG_OUTBF16);

  // ================= phase 2: RGCN — one dual-source GEMM (K=384 + root K=128) ========
  k_gather_rel3<<<NG, 128, 0, stream>>>(g_tag_b, eidx_all, rp_vv, G3_b);
  k_mgemm<<<mgb(NG), 256, 0, stream>>>(G3_b, 384, 384, WT[1], g_tag_b, H, H, WT[2],
                                       rgcn_b, g_b, H, NG, TG_RELU | TG_OUTBF16);

  // ================= phase 3: pc graph (2x GCN) =================
  k_gemm128b<<<nblk((long long)NP * H), 256, 0, stream>>>(pc_x, gcn1_w, nullptr, xW_b, NP, 5);
  k_gather_norm<<<NP, 128, 0, stream>>>(xW_b, H, 0, eidx_all, rp_pp, dinvP, xW_b, gcn1_b,
                                        p1b_b, H, 0, 1);
  k_mgemm<<<mgb(NP), 256, 0, stream>>>(p1b_b, H, H, WT[3], nullptr, 0, 0, nullptr,
                                       nullptr, xW_b, H, NP, TG_OUTBF16);
  k_gather_norm<<<NP, 128, 0, stream>>>(xW_b, H, 0, eidx_all, rp_pp, dinvP, xW_b, gcn2_b,
                                        p2b_b, H, 0, 1);

  // ================= phase 4: ResGated (game -> state) =================
  k_gemm128b<<<nblk((long long)NS * H), 256, 0, stream>>>(state_x, rg_key_w, rg_key_b, kk_b, NS, 6);
  k_mgemm<<<mgb(NG), 256, 0, stream>>>(g_b, H, H, WT[4], nullptr, 0, 0, nullptr,
                                       rg_query_b, q_b, H, NG, TG_OUTBF16);
  k_mgemm<<<mgb(NG), 256, 0, stream>>>(g_b, H, H, WT[5], nullptr, 0, 0, nullptr,
                                       rg_value_b, v_b, H, NG, TG_OUTBF16);
  k_resgated_gather<<<NS, 128, 0, stream>>>(kk_b, q_b, v_b, ea_hist, rg_edge_w, rh,
                                            eidx_all, rp_hh, state_x, rg_skip_w, rg_b, S_a_b);

  // ================= phase 5: sage32 (hist, xs=g) =================
  k_gather_mean<<<NS, 128, 0, stream>>>(g_b, eidx_all, rp_hh, rh, m_buf_b);
  k_mgemm<<<mgb(NS), 256, 0, stream>>>(m_buf_b, H, H, WT[6], S_a_b, H, H, WT[7],
                                       sage32_lb, S_b_b, H, NS, TG_NORM | TG_OUTBF16);

  // ================= phase 6: sage4 + sage42 (in, xs=g; shared mean) =================
  k_gather_mean<<<NS, 128, 0, stream>>>(g_b, eidx_all, rp_in, nullptr, m_buf_b);
  k_mgemm<<<mgb(NS), 256, 0, stream>>>(m_buf_b, H, H, WT[8], S_b_b, H, H, WT[9],
                                       sage4_lb, S_a_b, H, NS, TG_NORM | TG_OUTBF16);
  k_mgemm<<<mgb(NS), 256, 0, stream>>>(m_buf_b, H, H, WT[10], S_a_b, H, H, WT[11],
                                       sage42_lb, S_b_b, H, NS, TG_NORM | TG_OUTBF16);

  // ================= phase 7: pcs sage (pc->state) — writes tag2 operand col 0 ========
  k_gather_mean<<<NS, 128, 0, stream>>>(p2b_b, eidx_all, rp_ps, nullptr, m_buf_b);
  k_mgemm<<<mgb(NS), 256, 0, stream>>>(m_buf_b, H, H, WT[12], S_b_b, H, H, WT[13],
                                       pcs_lb, P_tag2_b, 384, NS, TG_NORM | TG_OUTBF16);

  // ================= phase 8: tag2 (2 hops into cols 128/256, K=384 GEMM) =============
  k_gather_norm<<<NS, 128, 0, stream>>>(P_tag2_b, 384, 0, eidx_all, rp_ss, dinvS, nullptr,
                                        nullptr, P_tag2_b, 384, 128, 0);
  k_gather_norm<<<NS, 128, 0, stream>>>(P_tag2_b, 384, 128, eidx_all, rp_ss, dinvS, nullptr,
                                        nullptr, P_tag2_b, 384, 256, 0);
  k_mgemm<<<mgb(NS), 256, 0, stream>>>(P_tag2_b, 384, 384, WT[14], nullptr, 0, 0, nullptr,
                                       tag2_b, S_b_b, H, NS, TG_RELU | TG_OUTBF16);

  // ================= phase 9: sage5 (state graph, xs=xd=s) — fp32 out for head ========
  k_gather_mean<<<NS, 128, 0, stream>>>(S_b_b, eidx_all, rp_ss, nullptr, m_buf_b);
  k_mgemm<<<mgb(NS), 256, 0, stream>>>(m_buf_b, H, H, WT[15], S_b_b, H, H, WT[16],
                                       sage5_lb, Sfin, H, NS, TG_NORM);

  // ================= head =================
  k_head<<<(NS + 7) / 8, 256, 0, stream>>>(Sfin, lin_w, lin_b, linl_w, linl_b, z, NS);
  k_logsoftmax<<<1, 256, 0, stream>>>(z, (float*)d_out, NS);
}

// Round 8
// 800.229 us; speedup vs baseline: 5.7535x; 1.0061x over previous
//
#include <hip/hip_runtime.h>
#include <cstdint>

#define H 128
static const int NG = 50000, NS = 20000, NP = 30000;

#define TG_RELU 2
#define TG_NORM 4
#define TG_OUTBF16 8

#define CSR_CHUNK 8192

typedef __attribute__((ext_vector_type(8))) short bf16x8;
typedef __attribute__((ext_vector_type(4))) float f32x4;

static inline int nblk(long long n) { return (int)((n + 255) / 256); }

__device__ inline unsigned short f2b(float f) {
  unsigned int u = __float_as_uint(f);
  u += 0x7FFFu + ((u >> 16) & 1u);
  return (unsigned short)(u >> 16);
}
__device__ inline float b2f(unsigned short u) {
  return __uint_as_float(((unsigned int)u) << 16);
}
__device__ inline float2 bfp2(unsigned int u) {
  return make_float2(__uint_as_float(u << 16), __uint_as_float(u & 0xFFFF0000u));
}
__device__ inline unsigned int f2bfp(float x, float y) {
  return ((unsigned int)f2b(y) << 16) | (unsigned int)f2b(x);
}

// ================= atomic-free batched CSR build =================
struct Seg6 {
  const int* col[6];
  const int* row[6];
  const int* et0;
  int nodeoff[7];
  int edgeoff[7];
  int mode[6];         // 0=row, 1=row|(et<<16), 2=edge id (local)
  float addself[6];
  int hasdinv[6];
};

__global__ __launch_bounds__(256) void k_hist(Seg6 sg, int EE, int* __restrict__ table) {
  __shared__ int h[512];
  int tid = threadIdx.x, blk = blockIdx.x;
  h[tid] = 0; h[tid + 256] = 0;
  __syncthreads();
  int e0 = blk * CSR_CHUNK, e1 = min(EE, e0 + CSR_CHUNK);
  for (int e = e0 + tid; e < e1; e += 256) {
    int gi = 0;
    while (e >= sg.edgeoff[gi + 1]) gi++;
    int le = e - sg.edgeoff[gi];
    int gn = sg.nodeoff[gi] + sg.col[gi][le];
    atomicAdd(&h[gn >> 9], 1);  // LDS atomic
  }
  __syncthreads();
  table[blk * 512 + tid] = h[tid];
  table[blk * 512 + tid + 256] = h[tid + 256];
}

__global__ void k_scanT(int* __restrict__ table, int nblkA, int* __restrict__ coarseOff) {
  int b = threadIdx.x;  // 0..511
  int s = 0;
  for (int k = 0; k < nblkA; k++) s += table[k * 512 + b];
  __shared__ int cs[512];
  cs[b] = s;
  __syncthreads();
  for (int off = 1; off < 512; off <<= 1) {
    int v = cs[b];
    int u = (b >= off) ? cs[b - off] : 0;
    __syncthreads();
    cs[b] = v + u;
    __syncthreads();
  }
  int excl = (b > 0) ? cs[b - 1] : 0;
  coarseOff[b] = excl;
  if (b == 511) coarseOff[512] = cs[511];
  int run = excl;
  for (int k = 0; k < nblkA; k++) {
    int t = table[k * 512 + b];
    table[k * 512 + b] = run;
    run += t;
  }
}

__global__ __launch_bounds__(256) void k_scatterA(Seg6 sg, int EE, const int* __restrict__ table,
                                                  uint2* __restrict__ tmp) {
  __shared__ int cur[512];
  int tid = threadIdx.x, blk = blockIdx.x;
  cur[tid] = table[blk * 512 + tid];
  cur[tid + 256] = table[blk * 512 + tid + 256];
  __syncthreads();
  int e0 = blk * CSR_CHUNK, e1 = min(EE, e0 + CSR_CHUNK);
  for (int e = e0 + tid; e < e1; e += 256) {
    int gi = 0;
    while (e >= sg.edgeoff[gi + 1]) gi++;
    int le = e - sg.edgeoff[gi];
    int gn = sg.nodeoff[gi] + sg.col[gi][le];
    int m = sg.mode[gi];
    int pay;
    if (m == 2) pay = le;
    else {
      pay = sg.row[gi][le];
      if (m == 1) pay |= sg.et0[le] << 16;
    }
    int pos = atomicAdd(&cur[gn >> 9], 1);
    tmp[pos] = make_uint2((unsigned)gn, (unsigned)pay);
  }
}

__global__ __launch_bounds__(256) void k_localCSR(const uint2* __restrict__ tmp,
                                                  const int* __restrict__ coarseOff,
                                                  Seg6 sg, int NN, int EE, int B,
                                                  int* __restrict__ rowptr,
                                                  int* __restrict__ eidx,
                                                  float* __restrict__ dinv) {
  int b = blockIdx.x, tid = threadIdx.x;
  int base = b * 512;
  int nNodes = min(512, NN - base);
  int beg = coarseOff[b], end = coarseOff[b + 1];
  __shared__ int cnt[512];
  __shared__ int off[512];
  __shared__ int ps[256];
  cnt[tid] = 0; cnt[tid + 256] = 0;
  __syncthreads();
  for (int j = beg + tid; j < end; j += 256)
    atomicAdd(&cnt[tmp[j].x - base], 1);
  __syncthreads();
  int a = cnt[2 * tid], bb = cnt[2 * tid + 1];
  ps[tid] = a + bb;
  __syncthreads();
  for (int o = 1; o < 256; o <<= 1) {
    int v = ps[tid];
    int u = (tid >= o) ? ps[tid - o] : 0;
    __syncthreads();
    ps[tid] = v + u;
    __syncthreads();
  }
  int excl = (tid > 0) ? ps[tid - 1] : 0;
  off[2 * tid] = excl;
  off[2 * tid + 1] = excl + a;
  __syncthreads();
  for (int i = tid; i < nNodes; i += 256) {
    int gid = base + i;
    rowptr[gid] = beg + off[i];
    int gi = 0;
    while (gid >= sg.nodeoff[gi + 1]) gi++;
    if (sg.hasdinv[gi]) {
      float d = (float)cnt[i] + sg.addself[gi];
      dinv[gid] = (d > 0.f) ? rsqrtf(d) : 0.f;
    }
  }
  if (b == B - 1 && tid == 0) rowptr[NN] = EE;
  __syncthreads();
  for (int j = beg + tid; j < end; j += 256) {
    uint2 p = tmp[j];
    int pos = beg + atomicAdd(&off[p.x - base], 1);
    eidx[pos] = (int)p.y;
  }
}

// ================= weight pre-pack =================
struct PackD { const float* src; int Ksrc; int Kdst; };
struct Pack17 { PackD d[17]; int koff[18]; };

__global__ void k_pack(Pack17 p, unsigned short* __restrict__ Wt, int totalRows) {
  int t = blockIdx.x * blockDim.x + threadIdx.x;
  if (t >= totalRows * 128) return;
  int gk = t >> 7, n = t & 127;
  int w = 0;
  while (gk >= p.koff[w + 1]) w++;
  int k = gk - p.koff[w];
  float v = (k < p.d[w].Ksrc) ? p.d[w].src[(size_t)k * 128 + n] : 0.f;
  Wt[(size_t)p.koff[w] * 128 + (size_t)n * p.d[w].Kdst + k] = f2b(v);
}

// ================= wave-per-node gathers (bf16, no LDS, no syncs) =================
// mean: one 64-lane wave per node, ushort2 per lane, 4-edge unroll
__global__ __launch_bounds__(256) void k_gmean(const unsigned short* __restrict__ src,
                                               const int* __restrict__ eidx,
                                               const int* __restrict__ rowptr,
                                               unsigned short* __restrict__ out, int N) {
  int c = blockIdx.x * 4 + (threadIdx.x >> 6);
  if (c >= N) return;
  int lane = threadIdx.x & 63;
  int beg = rowptr[c], end = rowptr[c + 1];
  float2 A0 = {0.f, 0.f}, A1 = {0.f, 0.f}, A2 = {0.f, 0.f}, A3 = {0.f, 0.f};
  int j = beg;
  for (; j + 4 <= end; j += 4) {
    int e0 = eidx[j], e1 = eidx[j + 1], e2 = eidx[j + 2], e3 = eidx[j + 3];
    unsigned int r0 = *(const unsigned int*)(src + (size_t)e0 * H + lane * 2);
    unsigned int r1 = *(const unsigned int*)(src + (size_t)e1 * H + lane * 2);
    unsigned int r2 = *(const unsigned int*)(src + (size_t)e2 * H + lane * 2);
    unsigned int r3 = *(const unsigned int*)(src + (size_t)e3 * H + lane * 2);
    float2 v0 = bfp2(r0), v1 = bfp2(r1), v2 = bfp2(r2), v3 = bfp2(r3);
    A0.x += v0.x; A0.y += v0.y;
    A1.x += v1.x; A1.y += v1.y;
    A2.x += v2.x; A2.y += v2.y;
    A3.x += v3.x; A3.y += v3.y;
  }
  for (; j < end; j++) {
    float2 v = bfp2(*(const unsigned int*)(src + (size_t)eidx[j] * H + lane * 2));
    A0.x += v.x; A0.y += v.y;
  }
  int cnt = end - beg;
  float s = 1.f / (float)(cnt > 0 ? cnt : 1);
  float ox = (A0.x + A1.x + A2.x + A3.x) * s;
  float oy = (A0.y + A1.y + A2.y + A3.y) * s;
  *(unsigned int*)(out + (size_t)c * H + lane * 2) = f2bfp(ox, oy);
}

// 3-relation mean -> concatenated 384-wide row (payload = r | et<<16)
__global__ __launch_bounds__(256) void k_grel3(const unsigned short* __restrict__ src,
                                               const int* __restrict__ eidx,
                                               const int* __restrict__ rowptr,
                                               unsigned short* __restrict__ G3, int N) {
  int c = blockIdx.x * 4 + (threadIdx.x >> 6);
  if (c >= N) return;
  int lane = threadIdx.x & 63;
  int beg = rowptr[c], end = rowptr[c + 1];
  float2 a0 = {0.f, 0.f}, a1 = {0.f, 0.f}, a2 = {0.f, 0.f};
  int c0 = 0, c1 = 0, c2 = 0;
  for (int j = beg; j < end; j++) {
    int pk = eidx[j];
    int rel = pk >> 16;
    float2 v = bfp2(*(const unsigned int*)(src + (size_t)(pk & 0xFFFF) * H + lane * 2));
    if (rel == 0) { a0.x += v.x; a0.y += v.y; c0++; }
    else if (rel == 1) { a1.x += v.x; a1.y += v.y; c1++; }
    else { a2.x += v.x; a2.y += v.y; c2++; }
  }
  float s0 = 1.f / (float)(c0 > 0 ? c0 : 1);
  float s1 = 1.f / (float)(c1 > 0 ? c1 : 1);
  float s2 = 1.f / (float)(c2 > 0 ? c2 : 1);
  size_t base = (size_t)c * 384 + lane * 2;
  *(unsigned int*)(G3 + base) = f2bfp(a0.x * s0, a0.y * s0);
  *(unsigned int*)(G3 + base + 128) = f2bfp(a1.x * s1, a1.y * s1);
  *(unsigned int*)(G3 + base + 256) = f2bfp(a2.x * s2, a2.y * s2);
}

// symmetric-normalized gather (+ optional self + bias + relu), strided
__global__ __launch_bounds__(256) void k_gnorm(const unsigned short* __restrict__ src,
                                               long ldS, int offS,
                                               const int* __restrict__ eidx,
                                               const int* __restrict__ rowptr,
                                               const float* __restrict__ dinv,
                                               const unsigned short* __restrict__ selfX,
                                               const float* __restrict__ bias,
                                               unsigned short* __restrict__ out,
                                               long ldD, int offD, int relu, int N) {
  int c = blockIdx.x * 4 + (threadIdx.x >> 6);
  if (c >= N) return;
  int lane = threadIdx.x & 63;
  int beg = rowptr[c], end = rowptr[c + 1];
  float2 A0 = {0.f, 0.f}, A1 = {0.f, 0.f}, A2 = {0.f, 0.f}, A3 = {0.f, 0.f};
  int j = beg;
  for (; j + 4 <= end; j += 4) {
    int e0 = eidx[j], e1 = eidx[j + 1], e2 = eidx[j + 2], e3 = eidx[j + 3];
    float w0 = dinv[e0], w1 = dinv[e1], w2 = dinv[e2], w3 = dinv[e3];
    float2 v0 = bfp2(*(const unsigned int*)(src + (size_t)e0 * ldS + offS + lane * 2));
    float2 v1 = bfp2(*(const unsigned int*)(src + (size_t)e1 * ldS + offS + lane * 2));
    float2 v2 = bfp2(*(const unsigned int*)(src + (size_t)e2 * ldS + offS + lane * 2));
    float2 v3 = bfp2(*(const unsigned int*)(src + (size_t)e3 * ldS + offS + lane * 2));
    A0.x = fmaf(w0, v0.x, A0.x); A0.y = fmaf(w0, v0.y, A0.y);
    A1.x = fmaf(w1, v1.x, A1.x); A1.y = fmaf(w1, v1.y, A1.y);
    A2.x = fmaf(w2, v2.x, A2.x); A2.y = fmaf(w2, v2.y, A2.y);
    A3.x = fmaf(w3, v3.x, A3.x); A3.y = fmaf(w3, v3.y, A3.y);
  }
  for (; j < end; j++) {
    int e = eidx[j];
    float w = dinv[e];
    float2 v = bfp2(*(const unsigned int*)(src + (size_t)e * ldS + offS + lane * 2));
    A0.x = fmaf(w, v.x, A0.x); A0.y = fmaf(w, v.y, A0.y);
  }
  float dc = dinv[c];
  float ox = (A0.x + A1.x + A2.x + A3.x) * dc;
  float oy = (A0.y + A1.y + A2.y + A3.y) * dc;
  if (selfX) {
    float2 sv = bfp2(*(const unsigned int*)(selfX + (size_t)c * H + lane * 2));
    ox += dc * dc * sv.x;
    oy += dc * dc * sv.y;
  }
  if (bias) {
    float2 bv = *(const float2*)(bias + lane * 2);
    ox += bv.x; oy += bv.y;
  }
  if (relu) { ox = fmaxf(ox, 0.f); oy = fmaxf(oy, 0.f); }
  *(unsigned int*)(out + (size_t)c * ldD + offD + lane * 2) = f2bfp(ox, oy);
}

// fused ResGated + hh-mean: per edge reads q,v,g rows; emits S_a and m_buf
__global__ __launch_bounds__(256) void k_resgated_mean(const unsigned short* __restrict__ kk,
                                                       const unsigned short* __restrict__ q,
                                                       const unsigned short* __restrict__ v,
                                                       const unsigned short* __restrict__ g,
                                                       const float* __restrict__ ea,
                                                       const float* __restrict__ We,
                                                       const int* __restrict__ rh,
                                                       const int* __restrict__ eidx,
                                                       const int* __restrict__ rowptr,
                                                       const float* __restrict__ sx,
                                                       const float* __restrict__ Wsk,
                                                       const float* __restrict__ rgb,
                                                       unsigned short* __restrict__ outS,
                                                       unsigned short* __restrict__ outM, int N) {
  int c = blockIdx.x * 4 + (threadIdx.x >> 6);
  if (c >= N) return;
  int lane = threadIdx.x & 63;
  int d0 = lane * 2;
  int beg = rowptr[c], end = rowptr[c + 1];
  float2 kload = bfp2(*(const unsigned int*)(kk + (size_t)c * H + d0));
  float2 we0 = make_float2(We[d0], We[d0 + 1]);
  float2 we1 = make_float2(We[H + d0], We[H + d0 + 1]);
  float2 accS = {0.f, 0.f}, accM = {0.f, 0.f};
  for (int j = beg; j < end; j++) {
    int e = eidx[j];
    int r = rh[e];
    float a0 = ea[2 * e], a1 = ea[2 * e + 1];
    float2 qv = bfp2(*(const unsigned int*)(q + (size_t)r * H + d0));
    float2 vv = bfp2(*(const unsigned int*)(v + (size_t)r * H + d0));
    float2 gv = bfp2(*(const unsigned int*)(g + (size_t)r * H + d0));
    float x0 = kload.x + qv.x + a0 * we0.x + a1 * we1.x;
    float x1 = kload.y + qv.y + a0 * we0.y + a1 * we1.y;
    float eta0 = 1.f / (1.f + __expf(-x0));
    float eta1 = 1.f / (1.f + __expf(-x1));
    accS.x = fmaf(eta0, vv.x, accS.x);
    accS.y = fmaf(eta1, vv.y, accS.y);
    accM.x += gv.x; accM.y += gv.y;
  }
  float sk0 = rgb[d0], sk1 = rgb[d0 + 1];
#pragma unroll
  for (int f = 0; f < 6; f++) {
    float xf = sx[c * 6 + f];
    sk0 = fmaf(xf, Wsk[f * H + d0], sk0);
    sk1 = fmaf(xf, Wsk[f * H + d0 + 1], sk1);
  }
  *(unsigned int*)(outS + (size_t)c * H + d0) =
      f2bfp(fmaxf(accS.x + sk0, 0.f), fmaxf(accS.y + sk1, 0.f));
  int cnt = end - beg;
  float s = 1.f / (float)(cnt > 0 ? cnt : 1);
  *(unsigned int*)(outM + (size_t)c * H + d0) = f2bfp(accM.x * s, accM.y * s);
}

// 7-dim symmetric-normalized gather over bf16 (payload masked for etype bits)
__global__ void k_gather_norm7(const unsigned short* __restrict__ src, int ldS, int offS,
                               const int* __restrict__ eidx, const int* __restrict__ rowptr,
                               const float* __restrict__ dinv, unsigned short* __restrict__ dst,
                               int ldD, int offD) {
  int c = blockIdx.x;
  int t = threadIdx.x;  // 64
  int f = t & 7, j = t >> 3;
  int beg = rowptr[c], end = rowptr[c + 1];
  __shared__ int si[64];
  __shared__ float sw[64];
  __shared__ float red[8][8];
  float acc = 0.f;
  for (int j0 = beg; j0 < end; j0 += 64) {
    int nn = min(64, end - j0);
    __syncthreads();
    if (t < nn) {
      int r = eidx[j0 + t] & 0xFFFF;
      si[t] = r;
      sw[t] = dinv[r];
    }
    __syncthreads();
    if (f < 7)
      for (int u = j; u < nn; u += 8) acc += sw[u] * b2f(src[(size_t)si[u] * ldS + offS + f]);
  }
  red[j][f] = acc;
  __syncthreads();
  if (j == 0 && f < 7) {
    float s = 0.f;
    for (int u = 0; u < 8; u++) s += red[u][f];
    dst[(size_t)c * ldD + offD + f] = f2b(s * dinv[c]);
  }
}

// ================= small utilities =================
__global__ void k_copy7b(const float* __restrict__ src, unsigned short* __restrict__ dst, int n) {
  long long t = (long long)blockIdx.x * blockDim.x + threadIdx.x;
  int i = (int)(t >> 3), f = (int)(t & 7);
  if (i < n && f < 7) dst[(size_t)i * 32 + f] = f2b(src[(size_t)i * 7 + f]);
}

__global__ void k_gemm128b(const float* __restrict__ X, const float* __restrict__ W,
                           const float* __restrict__ b, unsigned short* __restrict__ out,
                           int M, int K) {
  long long t = (long long)blockIdx.x * blockDim.x + threadIdx.x;
  if (t >= (long long)M * H) return;
  int i = (int)(t >> 7), h = (int)(t & 127);
  float acc = b ? b[h] : 0.f;
  const float* x = X + (long long)i * K;
  for (int k = 0; k < K; k++) acc = fmaf(x[k], W[k * H + h], acc);
  out[t] = f2b(acc);
}

// ================= MFMA bf16 GEMM: C[M x 128] = [X1|X2] @ [W1;W2] =================
__global__ __launch_bounds__(256) void k_mgemm(const unsigned short* __restrict__ X1, int ldX1, int K1,
                                               const unsigned short* __restrict__ W1t,
                                               const unsigned short* __restrict__ X2, int ldX2, int K2,
                                               const unsigned short* __restrict__ W2t,
                                               const float* __restrict__ bias,
                                               void* __restrict__ Cv, long ldC,
                                               int M, int flags) {
  __shared__ unsigned short Als[64 * 40];
  __shared__ unsigned short Bls[128 * 40];
  __shared__ float rs[2][64];
  int tid = threadIdx.x;
  int lane = tid & 63, wv = tid >> 6;
  int m = lane & 15, q = lane >> 4;
  int rbase = (wv & 1) * 32;
  int cbase = (wv >> 1) * 64;
  int blockRow = blockIdx.x * 64;
  int sr = tid >> 2, skc = (tid & 3) * 8;
  f32x4 acc[2][4];
#pragma unroll
  for (int a = 0; a < 2; a++)
#pragma unroll
    for (int b = 0; b < 4; b++) acc[a][b] = (f32x4){0.f, 0.f, 0.f, 0.f};

  int Ktot = K1 + K2;
  for (int k0 = 0; k0 < Ktot; k0 += 32) {
    const unsigned short* Xb;
    const unsigned short* Wt_;
    int kr, ldx, Kw;
    if (k0 < K1) { Xb = X1; Wt_ = W1t; kr = k0; ldx = ldX1; Kw = K1; }
    else { Xb = X2; Wt_ = W2t; kr = k0 - K1; ldx = ldX2; Kw = K2; }
    __syncthreads();
    {
      int gr = blockRow + sr;
      bf16x8 xv = (bf16x8){0, 0, 0, 0, 0, 0, 0, 0};
      if (gr < M) xv = *(const bf16x8*)(Xb + (size_t)gr * ldx + kr + skc);
      *(bf16x8*)&Als[sr * 40 + skc] = xv;
    }
#pragma unroll
    for (int it = 0; it < 2; it++) {
      int fid = it * 256 + tid;
      int n = fid >> 2, kc = (fid & 3) * 8;
      *(bf16x8*)&Bls[n * 40 + kc] = *(const bf16x8*)(Wt_ + (size_t)n * Kw + kr + kc);
    }
    __syncthreads();
    bf16x8 a0 = *(const bf16x8*)&Als[(rbase + m) * 40 + q * 8];
    bf16x8 a1 = *(const bf16x8*)&Als[(rbase + 16 + m) * 40 + q * 8];
    bf16x8 b0 = *(const bf16x8*)&Bls[(cbase + m) * 40 + q * 8];
    bf16x8 b1 = *(const bf16x8*)&Bls[(cbase + 16 + m) * 40 + q * 8];
    bf16x8 b2 = *(const bf16x8*)&Bls[(cbase + 32 + m) * 40 + q * 8];
    bf16x8 b3 = *(const bf16x8*)&Bls[(cbase + 48 + m) * 40 + q * 8];
    acc[0][0] = __builtin_amdgcn_mfma_f32_16x16x32_bf16(a0, b0, acc[0][0], 0, 0, 0);
    acc[0][1] = __builtin_amdgcn_mfma_f32_16x16x32_bf16(a0, b1, acc[0][1], 0, 0, 0);
    acc[0][2] = __builtin_amdgcn_mfma_f32_16x16x32_bf16(a0, b2, acc[0][2], 0, 0, 0);
    acc[0][3] = __builtin_amdgcn_mfma_f32_16x16x32_bf16(a0, b3, acc[0][3], 0, 0, 0);
    acc[1][0] = __builtin_amdgcn_mfma_f32_16x16x32_bf16(a1, b0, acc[1][0], 0, 0, 0);
    acc[1][1] = __builtin_amdgcn_mfma_f32_16x16x32_bf16(a1, b1, acc[1][1], 0, 0, 0);
    acc[1][2] = __builtin_amdgcn_mfma_f32_16x16x32_bf16(a1, b2, acc[1][2], 0, 0, 0);
    acc[1][3] = __builtin_amdgcn_mfma_f32_16x16x32_bf16(a1, b3, acc[1][3], 0, 0, 0);
  }
  float ov[2][4][4];
  float bcol[4] = {0.f, 0.f, 0.f, 0.f};
  if (bias) {
#pragma unroll
    for (int j = 0; j < 4; j++) bcol[j] = bias[cbase + j * 16 + m];
  }
#pragma unroll
  for (int a = 0; a < 2; a++)
#pragma unroll
    for (int j = 0; j < 4; j++)
#pragma unroll
      for (int i = 0; i < 4; i++) ov[a][j][i] = acc[a][j][i] + bcol[j];

  if (flags & TG_NORM) {
#pragma unroll
    for (int a = 0; a < 2; a++)
#pragma unroll
      for (int i = 0; i < 4; i++) {
        float p = 0.f;
#pragma unroll
        for (int j = 0; j < 4; j++) p = fmaf(ov[a][j][i], ov[a][j][i], p);
        p += __shfl_xor(p, 1);
        p += __shfl_xor(p, 2);
        p += __shfl_xor(p, 4);
        p += __shfl_xor(p, 8);
        if (m == 0) rs[wv >> 1][rbase + a * 16 + q * 4 + i] = p;
      }
    __syncthreads();
#pragma unroll
    for (int a = 0; a < 2; a++)
#pragma unroll
      for (int i = 0; i < 4; i++) {
        int ridx = rbase + a * 16 + q * 4 + i;
        float s = rs[0][ridx] + rs[1][ridx];
        float f = 1.f / fmaxf(sqrtf(s), 1e-12f);
#pragma unroll
        for (int j = 0; j < 4; j++) ov[a][j][i] = fmaxf(ov[a][j][i] * f, 0.f);
      }
  } else if (flags & TG_RELU) {
#pragma unroll
    for (int a = 0; a < 2; a++)
#pragma unroll
      for (int j = 0; j < 4; j++)
#pragma unroll
        for (int i = 0; i < 4; i++) ov[a][j][i] = fmaxf(ov[a][j][i], 0.f);
  }
  if (flags & TG_OUTBF16) {
    unsigned short* C = (unsigned short*)Cv;
#pragma unroll
    for (int a = 0; a < 2; a++)
#pragma unroll
      for (int i = 0; i < 4; i++) {
        int row = blockRow + rbase + a * 16 + q * 4 + i;
        if (row < M) {
#pragma unroll
          for (int j = 0; j < 4; j++)
            C[(size_t)row * ldC + cbase + j * 16 + m] = f2b(ov[a][j][i]);
        }
      }
  } else {
    float* C = (float*)Cv;
#pragma unroll
    for (int a = 0; a < 2; a++)
#pragma unroll
      for (int i = 0; i < 4; i++) {
        int row = blockRow + rbase + a * 16 + q * 4 + i;
        if (row < M) {
#pragma unroll
          for (int j = 0; j < 4; j++)
            C[(size_t)row * ldC + cbase + j * 16 + m] = ov[a][j][i];
        }
      }
  }
}

static inline int mgb(int M) { return (M + 63) / 64; }

// ================= fused head =================
__global__ __launch_bounds__(256) void k_head(const float* __restrict__ X,
                                              const float* __restrict__ lw,
                                              const float* __restrict__ lb,
                                              const float* __restrict__ lwl,
                                              const float* __restrict__ lbl,
                                              float* __restrict__ z, int M) {
  __shared__ float Wl[128 * 32];
  __shared__ float Xs[8][128];
  int tid = threadIdx.x;
  for (int i = tid * 4; i < 4096; i += 1024) *(float4*)&Wl[i] = *(const float4*)&lw[i];
  int rowBase = blockIdx.x * 8;
  {
    int idx = tid * 4;
    int xr = idx >> 7, xc = idx & 127;
    int grow = rowBase + xr;
    float4 v = make_float4(0.f, 0.f, 0.f, 0.f);
    if (grow < M) v = *(const float4*)(X + (size_t)grow * H + xc);
    *(float4*)&Xs[xr][xc] = v;
  }
  __syncthreads();
  int r = tid >> 5, o = tid & 31;
  float acc = lb[o];
  for (int k = 0; k < 128; k++) acc = fmaf(Xs[r][k], Wl[k * 32 + o], acc);
  acc = fmaxf(acc, 0.f) * lwl[o];
  for (int s = 16; s > 0; s >>= 1) acc += __shfl_down(acc, s, 32);
  int grow = rowBase + r;
  if (o == 0 && grow < M) z[grow] = acc + lbl[0];
}

// ================= log_softmax =================
__global__ void k_logsoftmax(const float* __restrict__ z, float* __restrict__ out, int n) {
  __shared__ float red[256];
  int tid = threadIdx.x;
  float m = -1e30f;
  for (int i = tid; i < n; i += 256) m = fmaxf(m, z[i]);
  red[tid] = m;
  __syncthreads();
  for (int s = 128; s > 0; s >>= 1) {
    if (tid < s) red[tid] = fmaxf(red[tid], red[tid + s]);
    __syncthreads();
  }
  float mx = red[0];
  __syncthreads();
  float sum = 0.f;
  for (int i = tid; i < n; i += 256) sum += __expf(z[i] - mx);
  red[tid] = sum;
  __syncthreads();
  for (int s = 128; s > 0; s >>= 1) {
    if (tid < s) red[tid] += red[tid + s];
    __syncthreads();
  }
  float lse = mx + logf(red[0]);
  for (int i = tid; i < n; i += 256) out[i] = z[i] - lse;
}

extern "C" void kernel_launch(void* const* d_in, const int* in_sizes, int n_in,
                              void* d_out, int out_size, void* d_ws, size_t ws_size,
                              hipStream_t stream) {
  const float* game_x = (const float*)d_in[0];
  const float* state_x = (const float*)d_in[1];
  const float* pc_x = (const float*)d_in[2];
  const int* ei_vv = (const int*)d_in[3];
  const int* et_vv = (const int*)d_in[4];
  const int* ei_hist = (const int*)d_in[5];
  const float* ea_hist = (const float*)d_in[6];
  const int* ei_in = (const int*)d_in[7];
  const int* ei_ss = (const int*)d_in[8];
  const int* ei_pp = (const int*)d_in[9];
  const int* ei_ps = (const int*)d_in[10];
  const float* tag10_w = (const float*)d_in[12];
  const float* tag10_b = (const float*)d_in[13];
  const float* rgcn_w = (const float*)d_in[14];
  const float* rgcn_root = (const float*)d_in[15];
  const float* rgcn_b = (const float*)d_in[16];
  const float* gcn1_w = (const float*)d_in[17];
  const float* gcn1_b = (const float*)d_in[18];
  const float* gcn2_w = (const float*)d_in[19];
  const float* gcn2_b = (const float*)d_in[20];
  const float* rg_key_w = (const float*)d_in[21];
  const float* rg_key_b = (const float*)d_in[22];
  const float* rg_query_w = (const float*)d_in[23];
  const float* rg_query_b = (const float*)d_in[24];
  const float* rg_value_w = (const float*)d_in[25];
  const float* rg_value_b = (const float*)d_in[26];
  const float* rg_edge_w = (const float*)d_in[27];
  const float* rg_skip_w = (const float*)d_in[28];
  const float* rg_b = (const float*)d_in[29];
  const float* sage32_lw = (const float*)d_in[30];
  const float* sage32_lb = (const float*)d_in[31];
  const float* sage32_rw = (const float*)d_in[32];
  const float* sage4_lw = (const float*)d_in[33];
  const float* sage4_lb = (const float*)d_in[34];
  const float* sage4_rw = (const float*)d_in[35];
  const float* sage42_lw = (const float*)d_in[36];
  const float* sage42_lb = (const float*)d_in[37];
  const float* sage42_rw = (const float*)d_in[38];
  const float* pcs_lw = (const float*)d_in[39];
  const float* pcs_lb = (const float*)d_in[40];
  const float* pcs_rw = (const float*)d_in[41];
  const float* tag2_w = (const float*)d_in[42];
  const float* tag2_b = (const float*)d_in[43];
  const float* sage5_lw = (const float*)d_in[44];
  const float* sage5_lb = (const float*)d_in[45];
  const float* sage5_rw = (const float*)d_in[46];
  const float* lin_w = (const float*)d_in[47];
  const float* lin_b = (const float*)d_in[48];
  const float* linl_w = (const float*)d_in[49];
  const float* linl_b = (const float*)d_in[50];

  const int Evv = in_sizes[3] / 2, Eh = in_sizes[5] / 2, Ein = in_sizes[7] / 2,
            Ess = in_sizes[8] / 2, Epp = in_sizes[9] / 2, Eps = in_sizes[10] / 2;
  const int EE = Evv + Epp + Eh + Ein + Eps + Ess;
  const int NN = NG + NP + 4 * NS;

  // ---- workspace layout (bytes). ----
  char* base = (char*)d_ws;
  const size_t B_NGH = (size_t)NG * H * 2;
  const size_t B_NPH = (size_t)NP * H * 2;
  const size_t B_NSH = (size_t)NS * H * 2;
  unsigned short* g_tag_b = (unsigned short*)base;             // later q_b
  unsigned short* g_b = (unsigned short*)(base + B_NGH);
  char* C0 = base + 2 * B_NGH;
  uint2* tmp_pairs = (uint2*)C0;
  unsigned short* P_tag10_b = (unsigned short*)C0;
  unsigned short* G3_b = (unsigned short*)C0;
  unsigned short* xW_b = (unsigned short*)C0;
  unsigned short* p1b_b = (unsigned short*)(C0 + B_NPH);
  unsigned short* p2b_b = (unsigned short*)(C0 + 2 * B_NPH);
  unsigned short* v_b = (unsigned short*)C0;
  unsigned short* q_b = g_tag_b;
  unsigned short* P_tag2_b = (unsigned short*)C0;
  char* S0 = base + 2 * B_NGH + 46000000;
  unsigned short* S_a_b = (unsigned short*)S0;
  unsigned short* S_b_b = (unsigned short*)(S0 + B_NSH);
  unsigned short* m_buf_b = (unsigned short*)(S0 + 2 * B_NSH);
  unsigned short* kk_b = (unsigned short*)(S0 + 3 * B_NSH);
  float* Sfin = (float*)(S0 + 4 * B_NSH);
  unsigned short* Wt = (unsigned short*)(S0 + 4 * B_NSH + (size_t)NS * H * 4);
  int* ip = (int*)(S0 + 4 * B_NSH + (size_t)NS * H * 4 + 700000);
  int* rp_all = ip; ip += NN + 1;
  int* eidx_all = ip; ip += EE;
  int* table = ip; ip += 512 * 240;
  int* coarseOff = ip; ip += 520;
  float* fp = (float*)ip;
  float* dinv_all = fp; fp += NN;
  float* z = fp; fp += NS;

  // graph order: 0=vv, 1=pp, 2=hh, 3=in, 4=ps, 5=ss
  Seg6 sg;
  sg.col[0] = ei_vv + Evv;  sg.row[0] = ei_vv;
  sg.col[1] = ei_pp + Epp;  sg.row[1] = ei_pp;
  sg.col[2] = ei_hist + Eh; sg.row[2] = ei_hist;
  sg.col[3] = ei_in + Ein;  sg.row[3] = ei_in;
  sg.col[4] = ei_ps + Eps;  sg.row[4] = ei_ps;
  sg.col[5] = ei_ss + Ess;  sg.row[5] = ei_ss;
  sg.et0 = et_vv;
  int no[7] = {0, NG, NG + NP, NG + NP + NS, NG + NP + 2 * NS, NG + NP + 3 * NS, NN};
  int eo[7] = {0, Evv, Evv + Epp, Evv + Epp + Eh, Evv + Epp + Eh + Ein,
               Evv + Epp + Eh + Ein + Eps, EE};
  for (int i = 0; i < 7; i++) { sg.nodeoff[i] = no[i]; sg.edgeoff[i] = eo[i]; }
  int md[6] = {1, 0, 2, 0, 0, 0};
  float as[6] = {0.f, 1.f, 0.f, 0.f, 0.f, 0.f};
  int hd[6] = {1, 1, 0, 0, 0, 1};
  for (int i = 0; i < 6; i++) { sg.mode[i] = md[i]; sg.addself[i] = as[i]; sg.hasdinv[i] = hd[i]; }

  const int* rp_vv = rp_all + no[0];
  const int* rp_pp = rp_all + no[1];
  const int* rp_hh = rp_all + no[2];
  const int* rp_in = rp_all + no[3];
  const int* rp_ps = rp_all + no[4];
  const int* rp_ss = rp_all + no[5];
  const float* dinvG = dinv_all + no[0];
  const float* dinvP = dinv_all + no[1];
  const float* dinvS = dinv_all + no[5];
  const int* rh = ei_hist;

  // ---- weight pre-pack (transposed bf16) ----
  Pack17 pk;
  const float* wsrc[17] = {tag10_w, rgcn_w, rgcn_root, gcn2_w, rg_query_w, rg_value_w,
                           sage32_lw, sage32_rw, sage4_lw, sage4_rw, sage42_lw, sage42_rw,
                           pcs_lw, pcs_rw, tag2_w, sage5_lw, sage5_rw};
  int ksrc[17] = {28, 384, 128, 128, 128, 128, 128, 128, 128, 128, 128, 128, 128, 128, 384, 128, 128};
  int kdst[17] = {32, 384, 128, 128, 128, 128, 128, 128, 128, 128, 128, 128, 128, 128, 384, 128, 128};
  int run = 0;
  for (int i = 0; i < 17; i++) {
    pk.d[i].src = wsrc[i]; pk.d[i].Ksrc = ksrc[i]; pk.d[i].Kdst = kdst[i];
    pk.koff[i] = run; run += kdst[i];
  }
  pk.koff[17] = run;
  unsigned short* WT[17];
  for (int i = 0; i < 17; i++) WT[i] = Wt + (size_t)pk.koff[i] * 128;
  k_pack<<<nblk((long long)run * 128), 256, 0, stream>>>(pk, Wt, run);

  // ---- atomic-free CSR build (4 dispatches) ----
  int nblkA = (EE + CSR_CHUNK - 1) / CSR_CHUNK;
  int B = (NN + 511) / 512;
  k_hist<<<nblkA, 256, 0, stream>>>(sg, EE, table);
  k_scanT<<<1, 512, 0, stream>>>(table, nblkA, coarseOff);
  k_scatterA<<<nblkA, 256, 0, stream>>>(sg, EE, table, tmp_pairs);
  k_localCSR<<<B, 256, 0, stream>>>(tmp_pairs, coarseOff, sg, NN, EE, B,
                                    rp_all, eidx_all, dinv_all);

  // ================= phase 1: TAGConv game =================
  hipMemsetAsync(P_tag10_b, 0, (size_t)NG * 32 * 2, stream);
  k_copy7b<<<nblk((long long)NG * 8), 256, 0, stream>>>(game_x, P_tag10_b, NG);
  k_gather_norm7<<<NG, 64, 0, stream>>>(P_tag10_b, 32, 0, eidx_all, rp_vv, dinvG, P_tag10_b, 32, 7);
  k_gather_norm7<<<NG, 64, 0, stream>>>(P_tag10_b, 32, 7, eidx_all, rp_vv, dinvG, P_tag10_b, 32, 14);
  k_gather_norm7<<<NG, 64, 0, stream>>>(P_tag10_b, 32, 14, eidx_all, rp_vv, dinvG, P_tag10_b, 32, 21);
  k_mgemm<<<mgb(NG), 256, 0, stream>>>(P_tag10_b, 32, 32, WT[0], nullptr, 0, 0, nullptr,
                                       tag10_b, g_tag_b, H, NG, TG_RELU | TG_OUTBF16);

  // ================= phase 2: RGCN =================
  k_grel3<<<(NG + 3) / 4, 256, 0, stream>>>(g_tag_b, eidx_all, rp_vv, G3_b, NG);
  k_mgemm<<<mgb(NG), 256, 0, stream>>>(G3_b, 384, 384, WT[1], g_tag_b, H, H, WT[2],
                                       rgcn_b, g_b, H, NG, TG_RELU | TG_OUTBF16);

  // ================= phase 3: pc graph (2x GCN) =================
  k_gemm128b<<<nblk((long long)NP * H), 256, 0, stream>>>(pc_x, gcn1_w, nullptr, xW_b, NP, 5);
  k_gnorm<<<(NP + 3) / 4, 256, 0, stream>>>(xW_b, H, 0, eidx_all, rp_pp, dinvP, xW_b, gcn1_b,
                                            p1b_b, H, 0, 1, NP);
  k_mgemm<<<mgb(NP), 256, 0, stream>>>(p1b_b, H, H, WT[3], nullptr, 0, 0, nullptr,
                                       nullptr, xW_b, H, NP, TG_OUTBF16);
  k_gnorm<<<(NP + 3) / 4, 256, 0, stream>>>(xW_b, H, 0, eidx_all, rp_pp, dinvP, xW_b, gcn2_b,
                                            p2b_b, H, 0, 1, NP);

  // ================= phase 4: ResGated + hh-mean (fused) =================
  k_gemm128b<<<nblk((long long)NS * H), 256, 0, stream>>>(state_x, rg_key_w, rg_key_b, kk_b, NS, 6);
  k_mgemm<<<mgb(NG), 256, 0, stream>>>(g_b, H, H, WT[4], nullptr, 0, 0, nullptr,
                                       rg_query_b, q_b, H, NG, TG_OUTBF16);
  k_mgemm<<<mgb(NG), 256, 0, stream>>>(g_b, H, H, WT[5], nullptr, 0, 0, nullptr,
                                       rg_value_b, v_b, H, NG, TG_OUTBF16);
  k_resgated_mean<<<(NS + 3) / 4, 256, 0, stream>>>(kk_b, q_b, v_b, g_b, ea_hist, rg_edge_w, rh,
                                                    eidx_all, rp_hh, state_x, rg_skip_w, rg_b,
                                                    S_a_b, m_buf_b, NS);

  // ================= phase 5: sage32 (m_buf from fused kernel) =================
  k_mgemm<<<mgb(NS), 256, 0, stream>>>(m_buf_b, H, H, WT[6], S_a_b, H, H, WT[7],
                                       sage32_lb, S_b_b, H, NS, TG_NORM | TG_OUTBF16);

  // ================= phase 6: sage4 + sage42 (in, shared mean) =================
  k_gmean<<<(NS + 3) / 4, 256, 0, stream>>>(g_b, eidx_all, rp_in, m_buf_b, NS);
  k_mgemm<<<mgb(NS), 256, 0, stream>>>(m_buf_b, H, H, WT[8], S_b_b, H, H, WT[9],
                                       sage4_lb, S_a_b, H, NS, TG_NORM | TG_OUTBF16);
  k_mgemm<<<mgb(NS), 256, 0, stream>>>(m_buf_b, H, H, WT[10], S_a_b, H, H, WT[11],
                                       sage42_lb, S_b_b, H, NS, TG_NORM | TG_OUTBF16);

  // ================= phase 7: pcs sage =================
  k_gmean<<<(NS + 3) / 4, 256, 0, stream>>>(p2b_b, eidx_all, rp_ps, m_buf_b, NS);
  k_mgemm<<<mgb(NS), 256, 0, stream>>>(m_buf_b, H, H, WT[12], S_b_b, H, H, WT[13],
                                       pcs_lb, P_tag2_b, 384, NS, TG_NORM | TG_OUTBF16);

  // ================= phase 8: tag2 =================
  k_gnorm<<<(NS + 3) / 4, 256, 0, stream>>>(P_tag2_b, 384, 0, eidx_all, rp_ss, dinvS, nullptr,
                                            nullptr, P_tag2_b, 384, 128, 0, NS);
  k_gnorm<<<(NS + 3) / 4, 256, 0, stream>>>(P_tag2_b, 384, 128, eidx_all, rp_ss, dinvS, nullptr,
                                            nullptr, P_tag2_b, 384, 256, 0, NS);
  k_mgemm<<<mgb(NS), 256, 0, stream>>>(P_tag2_b, 384, 384, WT[14], nullptr, 0, 0, nullptr,
                                       tag2_b, S_b_b, H, NS, TG_RELU | TG_OUTBF16);

  // ================= phase 9: sage5 =================
  k_gmean<<<(NS + 3) / 4, 256, 0, stream>>>(S_b_b, eidx_all, rp_ss, m_buf_b, NS);
  k_mgemm<<<mgb(NS), 256, 0, stream>>>(m_buf_b, H, H, WT[15], S_b_b, H, H, WT[16],
                                       sage5_lb, Sfin, H, NS, TG_NORM);

  // ================= head =================
  k_head<<<(NS + 7) / 8, 256, 0, stream>>>(Sfin, lin_w, lin_b, linl_w, linl_b, z, NS);
  k_logsoftmax<<<1, 256, 0, stream>>>(z, (float*)d_out, NS);
}